// Round 3
// baseline (1005.812 us; speedup 1.0000x reference)
//
#include <hip/hip_runtime.h>

#define N_NODES 50000
#define E_RAW_N 800000
#define E_TOT   850000
#define F_IN_K  500
#define HID     160

using short8 = __attribute__((ext_vector_type(8))) short;
using f32x4  = __attribute__((ext_vector_type(4))) float;

__device__ __forceinline__ float b2f(unsigned short u) {
  union { unsigned int i; float f; } v; v.i = ((unsigned int)u) << 16; return v.f;
}
__device__ __forceinline__ unsigned short f2b(float f) {
  union { float f; unsigned int i; } v; v.f = f;
  unsigned int i = v.i;
  unsigned int lsb = (i >> 16) & 1u;
  i += 0x7fffu + lsb;
  return (unsigned short)(i >> 16);
}

__device__ __forceinline__ float wsum(float x) {
  #pragma unroll
  for (int o = 32; o; o >>= 1) x += __shfl_xor(x, o, 64);
  return x;
}
__device__ __forceinline__ float wmax(float x) {
  #pragma unroll
  for (int o = 32; o; o >>= 1) x = fmaxf(x, __shfl_xor(x, o, 64));
  return x;
}

// ---------------- edge dtype detection ---------------------------------------
// int64 edges: odd 32-bit words (high halves) of src row are all 0 (ids<50000).
// int32 edges: those words are random node ids -> ~never all zero.
__global__ void detect_kernel(const int* __restrict__ ei, int* __restrict__ flag) {
  if (threadIdx.x == 0 && blockIdx.x == 0) {
    int allz = 1;
    for (int i = 1; i < 128; i += 2) if (ei[i] != 0) { allz = 0; break; }
    *flag = allz;  // 1 => int64 layout
  }
}

__device__ __forceinline__ int edge_src(const int* ei, int wide, int e) {
  return wide ? ei[2 * e] : ei[e];
}
__device__ __forceinline__ int edge_dst(const int* ei, int wide, int e) {
  return wide ? ei[2 * (E_RAW_N + e)] : ei[E_RAW_N + e];
}

// ---------------- GEMM: C[M,160] = A[M,K] @ B[K,160], f32 in/out -------------
// block = 256 threads (4 waves), block tile 16 rows x 160 cols, 16x16x32 MFMA.
// SPLIT=1: split-bf16 (hi/lo) -> ~f32 accuracy, 3 MFMAs per tile.
// EPI 0: plain store.  EPI 1: +bias, leaky_relu(0.01).
template<int K, int EPI, int SPLIT>
__global__ __launch_bounds__(256) void gemm_f32(
    const float* __restrict__ A, const float* __restrict__ B,
    float* __restrict__ C, const float* __restrict__ bias)
{
  constexpr int NS = SPLIT ? 2 : 1;
  __shared__ __align__(16) unsigned short As[NS][16 * 32];
  __shared__ __align__(16) unsigned short Bs[NS][160 * 40];  // BT[c][kl], stride 40
  const int t = threadIdx.x;
  const int l = t & 63;
  const int w = t >> 6;
  const int r0 = blockIdx.x * 16;
  f32x4 acc0 = {0.f,0.f,0.f,0.f}, acc1 = {0.f,0.f,0.f,0.f}, acc2 = {0.f,0.f,0.f,0.f};
  constexpr int KSTEPS = (K + 31) / 32;
  for (int ks = 0; ks < KSTEPS; ++ks) {
    const int k0 = ks * 32;
    { // stage A tile 16x32 (2 elems per thread)
      const int i0 = t * 2;
      const int row = i0 >> 5;
      const int kl = i0 & 31;
      const long g = (long)(r0 + row) * K + (k0 + kl);
      #pragma unroll
      for (int j = 0; j < 2; ++j) {
        float a = (k0 + kl + j < K) ? A[g + j] : 0.f;
        const unsigned short hi = f2b(a);
        As[0][row * 32 + kl + j] = hi;
        if (SPLIT) As[1][row * 32 + kl + j] = f2b(a - b2f(hi));
      }
    }
    // stage B tile transposed 32x160 -> BT[160][40]
    for (int i = t; i < 5120; i += 256) {
      const int kl = i / 160;
      const int c = i - kl * 160;
      float b = (k0 + kl < K) ? B[(long)(k0 + kl) * HID + c] : 0.f;
      const unsigned short hi = f2b(b);
      Bs[0][c * 40 + kl] = hi;
      if (SPLIT) Bs[1][c * 40 + kl] = f2b(b - b2f(hi));
    }
    __syncthreads();
    const int aoff = (l & 15) * 32 + (l >> 4) * 8;
    const short8 afh = *(const short8*)&As[0][aoff];
    short8 afl;
    if (SPLIT) afl = *(const short8*)&As[SPLIT][aoff];
    #pragma unroll
    for (int j = 0; j < 3; ++j) {
      const int ct = w + j * 4;
      if (j == 2 && w >= 2) break;
      const int boff = (ct * 16 + (l & 15)) * 40 + (l >> 4) * 8;
      const short8 bfh = *(const short8*)&Bs[0][boff];
      f32x4 acc = (j == 0) ? acc0 : (j == 1) ? acc1 : acc2;
      acc = __builtin_amdgcn_mfma_f32_16x16x32_bf16(afh, bfh, acc, 0, 0, 0);
      if (SPLIT) {
        const short8 bfl = *(const short8*)&Bs[SPLIT][boff];
        acc = __builtin_amdgcn_mfma_f32_16x16x32_bf16(afh, bfl, acc, 0, 0, 0);
        acc = __builtin_amdgcn_mfma_f32_16x16x32_bf16(afl, bfh, acc, 0, 0, 0);
      }
      if (j == 0) acc0 = acc; else if (j == 1) acc1 = acc; else acc2 = acc;
    }
    __syncthreads();
  }
  const int rbase = r0 + (l >> 4) * 4;
  #pragma unroll
  for (int j = 0; j < 3; ++j) {
    const int ct = w + j * 4;
    if (ct < 10) {
      const f32x4 a = (j == 0) ? acc0 : (j == 1) ? acc1 : acc2;
      const int col = ct * 16 + (l & 15);
      float bv = 0.f;
      if (EPI == 1) bv = bias[col];
      #pragma unroll
      for (int r = 0; r < 4; ++r) {
        float v = a[r];
        if (EPI == 1) { v += bv; v = v > 0.f ? v : 0.01f * v; }
        C[(long)(rbase + r) * HID + col] = v;
      }
    }
  }
}

// ---------------- attention dots: a_s[n,h] = xl[n,h,:]·att_s[h,:] -------------
__global__ __launch_bounds__(256) void att_kernel(
    const float* __restrict__ xl,
    const float* __restrict__ att_s, const float* __restrict__ att_d,
    float* __restrict__ a_s, float* __restrict__ a_d)
{
  const int i = blockIdx.x * 256 + threadIdx.x;
  if (i >= N_NODES * 5) return;
  const int h = i % 5;
  const int n = i / 5;
  const float* xr = xl + (long)n * HID + h * 32;
  float s = 0.f, d = 0.f;
  #pragma unroll
  for (int c = 0; c < 32; ++c) {
    const float xv = xr[c];
    s += xv * att_s[h * 32 + c];
    d += xv * att_d[h * 32 + c];
  }
  a_s[i] = s;
  a_d[i] = d;
}

// ---------------- CSR build ---------------------------------------------------
__global__ __launch_bounds__(256) void count_kernel(const int* __restrict__ ei,
    const int* __restrict__ flag, int* __restrict__ deg) {
  const int e = blockIdx.x * 256 + threadIdx.x;
  if (e >= E_TOT) return;
  const int wide = *flag;
  const int d = (e < E_RAW_N) ? edge_dst(ei, wide, e) : (e - E_RAW_N);
  atomicAdd(&deg[d], 1);
}

__global__ __launch_bounds__(1024) void scan_kernel(const int* __restrict__ deg, int* __restrict__ off) {
  __shared__ int buf[1024];
  const int t = threadIdx.x;
  int carry = 0;
  for (int base = 0; base < N_NODES; base += 1024) {
    const int idx = base + t;
    const int v = (idx < N_NODES) ? deg[idx] : 0;
    buf[t] = v;
    __syncthreads();
    int x = v;
    for (int o = 1; o < 1024; o <<= 1) {
      const int y = (t >= o) ? buf[t - o] : 0;
      __syncthreads();
      x += y;
      buf[t] = x;
      __syncthreads();
    }
    if (idx < N_NODES) off[idx] = carry + x - v;
    const int tot = buf[1023];
    __syncthreads();
    carry += tot;
  }
  if (t == 0) off[N_NODES] = carry;
}

__global__ __launch_bounds__(256) void fill_kernel(const int* __restrict__ ei,
    const int* __restrict__ flag, const int* __restrict__ off,
    int* __restrict__ fillc, int* __restrict__ csr_src, int* __restrict__ csr_eid) {
  const int e = blockIdx.x * 256 + threadIdx.x;
  if (e >= E_TOT) return;
  const int wide = *flag;
  int s, d;
  if (e < E_RAW_N) { s = edge_src(ei, wide, e); d = edge_dst(ei, wide, e); }
  else { s = e - E_RAW_N; d = s; }
  const int p = off[d] + atomicAdd(&fillc[d], 1);
  csr_src[p] = s;
  csr_eid[p] = e;
}

// ---------------- fused per-node segment-softmax + aggregation ---------------
// one wave per dst node; lanes own columns {l, l+64, l+128}.
// DO_LN=1: + bias, leaky(0.01), LayerNorm -> hout.  DO_LN=0: + bias, leaky -> hout.
template<int DO_LN>
__global__ __launch_bounds__(256) void node_kernel(
    const int* __restrict__ off_, const int* __restrict__ csr_src, const int* __restrict__ csr_eid,
    const float* __restrict__ xl,
    const float* __restrict__ a_s, const float* __restrict__ a_d,
    float* __restrict__ alpha_out,
    const float* __restrict__ bias,
    const float* __restrict__ gamma_, const float* __restrict__ beta_,
    float* __restrict__ hout)
{
  const int w = threadIdx.x >> 6;
  const int l = threadIdx.x & 63;
  const int n = blockIdx.x * 4 + w;
  if (n >= N_NODES) return;
  const int off = off_[n];
  const int deg = off_[n + 1] - off;

  const float ad0 = a_d[n*5+0], ad1 = a_d[n*5+1], ad2 = a_d[n*5+2], ad3 = a_d[n*5+3], ad4 = a_d[n*5+4];

  // phase A: per-head max logit
  float m0 = -1e30f, m1 = -1e30f, m2 = -1e30f, m3 = -1e30f, m4 = -1e30f;
  for (int s = l; s < deg; s += 64) {
    const int src = csr_src[off + s];
    const float* ap = a_s + src * 5;
    float lg;
    lg = ap[0] + ad0; lg = lg > 0.f ? lg : 0.2f * lg; m0 = fmaxf(m0, lg);
    lg = ap[1] + ad1; lg = lg > 0.f ? lg : 0.2f * lg; m1 = fmaxf(m1, lg);
    lg = ap[2] + ad2; lg = lg > 0.f ? lg : 0.2f * lg; m2 = fmaxf(m2, lg);
    lg = ap[3] + ad3; lg = lg > 0.f ? lg : 0.2f * lg; m3 = fmaxf(m3, lg);
    lg = ap[4] + ad4; lg = lg > 0.f ? lg : 0.2f * lg; m4 = fmaxf(m4, lg);
  }
  m0 = wmax(m0); m1 = wmax(m1); m2 = wmax(m2); m3 = wmax(m3); m4 = wmax(m4);

  // phase B: per-head sum of exp
  float s0 = 0.f, s1 = 0.f, s2 = 0.f, s3 = 0.f, s4 = 0.f;
  for (int s = l; s < deg; s += 64) {
    const int src = csr_src[off + s];
    const float* ap = a_s + src * 5;
    float lg;
    lg = ap[0] + ad0; lg = lg > 0.f ? lg : 0.2f * lg; s0 += __expf(lg - m0);
    lg = ap[1] + ad1; lg = lg > 0.f ? lg : 0.2f * lg; s1 += __expf(lg - m1);
    lg = ap[2] + ad2; lg = lg > 0.f ? lg : 0.2f * lg; s2 += __expf(lg - m2);
    lg = ap[3] + ad3; lg = lg > 0.f ? lg : 0.2f * lg; s3 += __expf(lg - m3);
    lg = ap[4] + ad4; lg = lg > 0.f ? lg : 0.2f * lg; s4 += __expf(lg - m4);
  }
  s0 = wsum(s0); s1 = wsum(s1); s2 = wsum(s2); s3 = wsum(s3); s4 = wsum(s4);
  const float i0 = 1.f / (s0 + 1e-16f), i1 = 1.f / (s1 + 1e-16f), i2 = 1.f / (s2 + 1e-16f),
              i3 = 1.f / (s3 + 1e-16f), i4 = 1.f / (s4 + 1e-16f);

  const bool lo = (l < 32);
  const float adA = lo ? ad0 : ad1, mA = lo ? m0 : m1, iA = lo ? i0 : i1;
  const float adB = lo ? ad2 : ad3, mB = lo ? m2 : m3, iB = lo ? i2 : i3;
  float adw = 0.f, mw = 0.f, iw = 0.f;
  if (l < 5) {
    adw = l == 0 ? ad0 : l == 1 ? ad1 : l == 2 ? ad2 : l == 3 ? ad3 : ad4;
    mw  = l == 0 ? m0  : l == 1 ? m1  : l == 2 ? m2  : l == 3 ? m3  : m4;
    iw  = l == 0 ? i0  : l == 1 ? i1  : l == 2 ? i2  : l == 3 ? i3  : i4;
  }

  const int c0 = l, c1 = l + 64, c2 = l + 128;
  const int hA = lo ? 0 : 1;
  float acc0 = 0.f, acc1 = 0.f, acc2 = 0.f;

  // phase C: aggregate messages + emit normalized alphas
  for (int s = 0; s < deg; ++s) {
    const int p = off + s;
    const int src = csr_src[p];
    const float* ap = a_s + src * 5;
    const long xb = (long)src * HID;
    float lgA = ap[hA] + adA;     lgA = lgA > 0.f ? lgA : 0.2f * lgA;
    float lgB = ap[2 + hA] + adB; lgB = lgB > 0.f ? lgB : 0.2f * lgB;
    const float aA = __expf(lgA - mA) * iA;
    const float aB = __expf(lgB - mB) * iB;
    acc0 += xl[xb + c0] * aA;
    acc1 += xl[xb + c1] * aB;
    if (lo) {
      float lgC = ap[4] + ad4; lgC = lgC > 0.f ? lgC : 0.2f * lgC;
      const float aC = __expf(lgC - m4) * i4;
      acc2 += xl[xb + c2] * aC;
    }
    if (l < 5) {
      float lg = ap[l] + adw; lg = lg > 0.f ? lg : 0.2f * lg;
      const float av = __expf(lg - mw) * iw;
      alpha_out[(long)csr_eid[p] * 5 + l] = av;
    }
  }

  // epilogue
  float v0 = acc0 + bias[c0]; v0 = v0 > 0.f ? v0 : 0.01f * v0;
  float v1 = acc1 + bias[c1]; v1 = v1 > 0.f ? v1 : 0.01f * v1;
  float v2 = 0.f;
  if (lo) { v2 = acc2 + bias[c2]; v2 = v2 > 0.f ? v2 : 0.01f * v2; }

  const long hb = (long)n * HID;
  if (DO_LN) {
    const float tot = wsum(v0 + v1 + v2);
    const float mean = tot * (1.f / 160.f);
    const float d0 = v0 - mean, d1 = v1 - mean;
    float sq = d0 * d0 + d1 * d1;
    float d2 = 0.f;
    if (lo) { d2 = v2 - mean; sq += d2 * d2; }
    const float var = wsum(sq) * (1.f / 160.f);
    const float rstd = rsqrtf(var + 1e-5f);
    hout[hb + c0] = d0 * rstd * gamma_[c0] + beta_[c0];
    hout[hb + c1] = d1 * rstd * gamma_[c1] + beta_[c1];
    if (lo) hout[hb + c2] = d2 * rstd * gamma_[c2] + beta_[c2];
  } else {
    hout[hb + c0] = v0;
    hout[hb + c1] = v1;
    if (lo) hout[hb + c2] = v2;
  }
}

extern "C" void kernel_launch(void* const* d_in, const int* in_sizes, int n_in,
                              void* d_out, int out_size, void* d_ws, size_t ws_size,
                              hipStream_t stream)
{
  const float* x     = (const float*)d_in[0];
  const int*   ei    = (const int*)d_in[1];
  const float* W1    = (const float*)d_in[2];
  const float* att1s = (const float*)d_in[3];
  const float* att1d = (const float*)d_in[4];
  const float* b1    = (const float*)d_in[5];
  const float* g1    = (const float*)d_in[6];
  const float* be1   = (const float*)d_in[7];
  const float* W2    = (const float*)d_in[8];
  const float* att2s = (const float*)d_in[9];
  const float* att2d = (const float*)d_in[10];
  const float* b2    = (const float*)d_in[11];
  const float* Wm    = (const float*)d_in[12];
  const float* bm    = (const float*)d_in[13];

  float* out    = (float*)d_out;                      // [N,160]
  float* alpha1 = out + (long)N_NODES * HID;          // [E,5]
  float* alpha2 = alpha1 + (long)E_TOT * 5;           // [E,5]

  char* p = (char*)d_ws;
  auto alloc = [&](size_t bytes) { void* r = (void*)p; p += (bytes + 255) & ~(size_t)255; return r; };
  float* xl   = (float*)alloc((size_t)N_NODES * HID * 4);
  float* hbuf = (float*)alloc((size_t)N_NODES * HID * 4);
  float* as_  = (float*)alloc((size_t)N_NODES * 5 * 4);
  float* ad_  = (float*)alloc((size_t)N_NODES * 5 * 4);
  int* deg    = (int*)alloc((size_t)N_NODES * 4);
  int* fillc  = (int*)alloc((size_t)N_NODES * 4);
  int* off    = (int*)alloc((size_t)(N_NODES + 1) * 4);
  int* csrS   = (int*)alloc((size_t)E_TOT * 4);
  int* csrE   = (int*)alloc((size_t)E_TOT * 4);
  int* flag   = (int*)alloc(256);

  hipMemsetAsync(deg, 0, (size_t)N_NODES * 4, stream);
  hipMemsetAsync(fillc, 0, (size_t)N_NODES * 4, stream);

  detect_kernel<<<1, 64, 0, stream>>>(ei, flag);
  const int EB = (E_TOT + 255) / 256;
  count_kernel<<<EB, 256, 0, stream>>>(ei, flag, deg);
  scan_kernel<<<1, 1024, 0, stream>>>(deg, off);
  fill_kernel<<<EB, 256, 0, stream>>>(ei, flag, off, fillc, csrS, csrE);

  // layer 1 (split-bf16 GEMM: ~f32 accuracy, feeds LN which amplifies abs error)
  gemm_f32<F_IN_K, 0, 1><<<N_NODES / 16, 256, 0, stream>>>(x, W1, xl, nullptr);
  att_kernel<<<(N_NODES * 5 + 255) / 256, 256, 0, stream>>>(xl, att1s, att1d, as_, ad_);
  node_kernel<1><<<N_NODES / 4, 256, 0, stream>>>(off, csrS, csrE, xl, as_, ad_, alpha1, b1, g1, be1, hbuf);

  // layer 2
  gemm_f32<HID, 0, 0><<<N_NODES / 16, 256, 0, stream>>>(hbuf, W2, xl, nullptr);
  att_kernel<<<(N_NODES * 5 + 255) / 256, 256, 0, stream>>>(xl, att2s, att2d, as_, ad_);
  node_kernel<0><<<N_NODES / 4, 256, 0, stream>>>(off, csrS, csrE, xl, as_, ad_, alpha2, b2, nullptr, nullptr, hbuf);

  // final MLP: out = leaky(h2 @ Wm + bm)
  gemm_f32<HID, 1, 0><<<N_NODES / 16, 256, 0, stream>>>(hbuf, Wm, out, bm);
}

// Round 4
// 809.936 us; speedup vs baseline: 1.2418x; 1.2418x over previous
//
#include <hip/hip_runtime.h>

#define N_NODES 50000
#define E_RAW_N 800000
#define E_TOT   850000
#define F_IN_K  500
#define HID     160
#define KPAD    512

using short8 = __attribute__((ext_vector_type(8))) short;
using f32x4  = __attribute__((ext_vector_type(4))) float;

__device__ __forceinline__ float b2f(unsigned short u) {
  union { unsigned int i; float f; } v; v.i = ((unsigned int)u) << 16; return v.f;
}
__device__ __forceinline__ unsigned short f2b(float f) {
  union { float f; unsigned int i; } v; v.f = f;
  unsigned int i = v.i;
  unsigned int lsb = (i >> 16) & 1u;
  i += 0x7fffu + lsb;
  return (unsigned short)(i >> 16);
}

__device__ __forceinline__ float wsum(float x) {
  #pragma unroll
  for (int o = 32; o; o >>= 1) x += __shfl_xor(x, o, 64);
  return x;
}
__device__ __forceinline__ float wmax(float x) {
  #pragma unroll
  for (int o = 32; o; o >>= 1) x = fmaxf(x, __shfl_xor(x, o, 64));
  return x;
}

// ---------------- edge dtype detection (int64 vs int32 hedge) ----------------
__global__ void detect_kernel(const int* __restrict__ ei, int* __restrict__ flag) {
  if (threadIdx.x == 0 && blockIdx.x == 0) {
    int allz = 1;
    for (int i = 1; i < 128; i += 2) if (ei[i] != 0) { allz = 0; break; }
    *flag = allz;  // 1 => int64 layout
  }
}
__device__ __forceinline__ int edge_src(const int* ei, int wide, int e) {
  return wide ? ei[2 * e] : ei[e];
}
__device__ __forceinline__ int edge_dst(const int* ei, int wide, int e) {
  return wide ? ei[2 * (E_RAW_N + e)] : ei[E_RAW_N + e];
}

// ---------------- weight pre-convert: B[K][160] f32 -> Bt hi/lo [160][KPAD] ---
__global__ __launch_bounds__(256) void convert_B(const float* __restrict__ B,
                                                 unsigned short* __restrict__ Bt, int K) {
  const int i = blockIdx.x * 256 + threadIdx.x;
  if (i >= HID * KPAD) return;
  const int c = i / KPAD, k = i % KPAD;
  const float b = (k < K) ? B[(long)k * HID + c] : 0.f;
  const unsigned short hi = f2b(b);
  Bt[i] = hi;
  Bt[HID * KPAD + i] = f2b(b - b2f(hi));
}

// ---------------- GEMM: C[M,160] = A[M,K] @ B, LDS-free ----------------------
// block = 4 waves; wave = 16 rows x 160 cols (10 col-tiles, 16x16x32 MFMA).
// A: f32, converted to bf16 hi/lo in-register. B: pre-converted Bt (hi, then lo).
// SPLIT=1: 3-MFMA split-bf16 (~f32 accuracy). EPI 1: +bias, leaky(0.01).
template<int K, int EPI, int SPLIT>
__global__ __launch_bounds__(256) void gemm_direct(
    const float* __restrict__ A, const unsigned short* __restrict__ Bt,
    float* __restrict__ C, const float* __restrict__ bias)
{
  const int l = threadIdx.x & 63;
  const int w = threadIdx.x >> 6;
  const int m = l & 15;
  const int kgrp = (l >> 4) * 8;
  const int rbase = blockIdx.x * 64 + w * 16;
  const int arow = (rbase + m < N_NODES) ? rbase + m : N_NODES - 1;
  const float* Arow = A + (long)arow * K;

  f32x4 acc[10];
  #pragma unroll
  for (int i = 0; i < 10; ++i) acc[i] = (f32x4){0.f, 0.f, 0.f, 0.f};

  constexpr int KSTEPS = (K + 31) / 32;
  for (int ks = 0; ks < KSTEPS; ++ks) {
    const int kb = ks * 32 + kgrp;
    float a[8];
    if ((K % 32 == 0) || ks < KSTEPS - 1) {
      const float4 a0 = *(const float4*)(Arow + kb);
      const float4 a1 = *(const float4*)(Arow + kb + 4);
      a[0]=a0.x; a[1]=a0.y; a[2]=a0.z; a[3]=a0.w;
      a[4]=a1.x; a[5]=a1.y; a[6]=a1.z; a[7]=a1.w;
    } else {
      #pragma unroll
      for (int j = 0; j < 8; ++j) a[j] = (kb + j < K) ? Arow[kb + j] : 0.f;
    }
    short8 ah, al;
    #pragma unroll
    for (int j = 0; j < 8; ++j) {
      const unsigned short h = f2b(a[j]);
      ah[j] = (short)h;
      if (SPLIT) al[j] = (short)f2b(a[j] - b2f(h));
    }
    #pragma unroll
    for (int ct = 0; ct < 10; ++ct) {
      const long bo = (long)(ct * 16 + m) * KPAD + ks * 32 + kgrp;
      const short8 bh = *(const short8*)(Bt + bo);
      acc[ct] = __builtin_amdgcn_mfma_f32_16x16x32_bf16(ah, bh, acc[ct], 0, 0, 0);
      if (SPLIT) {
        const short8 bl = *(const short8*)(Bt + (long)HID * KPAD + bo);
        acc[ct] = __builtin_amdgcn_mfma_f32_16x16x32_bf16(ah, bl, acc[ct], 0, 0, 0);
        acc[ct] = __builtin_amdgcn_mfma_f32_16x16x32_bf16(al, bh, acc[ct], 0, 0, 0);
      }
    }
  }

  const int crow0 = rbase + (l >> 4) * 4;
  #pragma unroll
  for (int r = 0; r < 4; ++r) {
    const int crow = crow0 + r;
    if (crow < N_NODES) {
      #pragma unroll
      for (int ct = 0; ct < 10; ++ct) {
        const int col = ct * 16 + m;
        float v = acc[ct][r];
        if (EPI == 1) { v += bias[col]; v = v > 0.f ? v : 0.01f * v; }
        C[(long)crow * HID + col] = v;
      }
    }
  }
}

// ---------------- attention dots: a_s[n,h] = xl[n,h,:]·att_s[h,:] -------------
__global__ __launch_bounds__(256) void att_kernel(
    const float* __restrict__ xl,
    const float* __restrict__ att_s, const float* __restrict__ att_d,
    float* __restrict__ a_s, float* __restrict__ a_d)
{
  const int i = blockIdx.x * 256 + threadIdx.x;
  if (i >= N_NODES * 5) return;
  const int h = i % 5;
  const int n = i / 5;
  const float4* xr = (const float4*)(xl + (long)n * HID + h * 32);
  const float4* sv4 = (const float4*)(att_s + h * 32);
  const float4* dv4 = (const float4*)(att_d + h * 32);
  float s = 0.f, d = 0.f;
  #pragma unroll
  for (int j = 0; j < 8; ++j) {
    const float4 xv = xr[j], sv = sv4[j], dv = dv4[j];
    s += xv.x * sv.x + xv.y * sv.y + xv.z * sv.z + xv.w * sv.w;
    d += xv.x * dv.x + xv.y * dv.y + xv.z * dv.z + xv.w * dv.w;
  }
  a_s[i] = s;
  a_d[i] = d;
}

// ---------------- CSR build ---------------------------------------------------
__global__ __launch_bounds__(256) void count_kernel(const int* __restrict__ ei,
    const int* __restrict__ flag, int* __restrict__ deg) {
  const int e = blockIdx.x * 256 + threadIdx.x;
  if (e >= E_TOT) return;
  const int wide = *flag;
  const int d = (e < E_RAW_N) ? edge_dst(ei, wide, e) : (e - E_RAW_N);
  atomicAdd(&deg[d], 1);
}

#define SCAN_CHUNK 49  // 1024*49 = 50176 >= 50000
__global__ __launch_bounds__(1024) void scan_kernel(const int* __restrict__ deg, int* __restrict__ off) {
  __shared__ int wtot[16];
  const int t = threadIdx.x;
  const int lane = t & 63, wid = t >> 6;
  const int base = t * SCAN_CHUNK;
  int local[SCAN_CHUNK];
  int sum = 0;
  #pragma unroll
  for (int i = 0; i < SCAN_CHUNK; ++i) {
    const int idx = base + i;
    const int v = (idx < N_NODES) ? deg[idx] : 0;
    local[i] = sum;
    sum += v;
  }
  int inc = sum;
  #pragma unroll
  for (int o = 1; o < 64; o <<= 1) {
    const int y = __shfl_up(inc, o, 64);
    if (lane >= o) inc += y;
  }
  if (lane == 63) wtot[wid] = inc;
  __syncthreads();
  if (wid == 0 && lane < 16) {
    const int v = wtot[lane];
    int inc2 = v;
    #pragma unroll
    for (int o = 1; o < 16; o <<= 1) {
      const int y = __shfl_up(inc2, o, 64);
      if (lane >= o) inc2 += y;
    }
    wtot[lane] = inc2 - v;  // exclusive
  }
  __syncthreads();
  const int pre = wtot[wid] + (inc - sum);
  #pragma unroll
  for (int i = 0; i < SCAN_CHUNK; ++i) {
    const int idx = base + i;
    if (idx < N_NODES) off[idx] = pre + local[i];
  }
  if (t == 1023) off[N_NODES] = E_TOT;
}

__global__ __launch_bounds__(256) void fill_kernel(const int* __restrict__ ei,
    const int* __restrict__ flag, const int* __restrict__ off,
    int* __restrict__ fillc, int* __restrict__ csr_src, int* __restrict__ csr_eid) {
  const int e = blockIdx.x * 256 + threadIdx.x;
  if (e >= E_TOT) return;
  const int wide = *flag;
  int s, d;
  if (e < E_RAW_N) { s = edge_src(ei, wide, e); d = edge_dst(ei, wide, e); }
  else { s = e - E_RAW_N; d = s; }
  const int p = off[d] + atomicAdd(&fillc[d], 1);
  csr_src[p] = s;
  csr_eid[p] = e;
}

// ---------------- fused per-node segment-softmax + aggregation ---------------
// one wave per dst node; lane l owns cols {2l, 2l+1} (head l>>4) and, for
// l<32, col 128+l (head 4).
template<int DO_LN>
__global__ __launch_bounds__(256) void node_kernel(
    const int* __restrict__ off_, const int* __restrict__ csr_src, const int* __restrict__ csr_eid,
    const float* __restrict__ xl,
    const float* __restrict__ a_s, const float* __restrict__ a_d,
    float* __restrict__ alpha_out,
    const float* __restrict__ bias,
    const float* __restrict__ gamma_, const float* __restrict__ beta_,
    float* __restrict__ hout)
{
  const int w = threadIdx.x >> 6;
  const int l = threadIdx.x & 63;
  const int n = blockIdx.x * 4 + w;
  if (n >= N_NODES) return;
  const int off = off_[n];
  const int deg = off_[n + 1] - off;

  const float ad0 = a_d[n*5+0], ad1 = a_d[n*5+1], ad2 = a_d[n*5+2], ad3 = a_d[n*5+3], ad4 = a_d[n*5+4];

  // phase A: per-head max logit
  float m0 = -1e30f, m1 = -1e30f, m2 = -1e30f, m3 = -1e30f, m4 = -1e30f;
  for (int s = l; s < deg; s += 64) {
    const int src = csr_src[off + s];
    const float* ap = a_s + src * 5;
    float lg;
    lg = ap[0] + ad0; lg = lg > 0.f ? lg : 0.2f * lg; m0 = fmaxf(m0, lg);
    lg = ap[1] + ad1; lg = lg > 0.f ? lg : 0.2f * lg; m1 = fmaxf(m1, lg);
    lg = ap[2] + ad2; lg = lg > 0.f ? lg : 0.2f * lg; m2 = fmaxf(m2, lg);
    lg = ap[3] + ad3; lg = lg > 0.f ? lg : 0.2f * lg; m3 = fmaxf(m3, lg);
    lg = ap[4] + ad4; lg = lg > 0.f ? lg : 0.2f * lg; m4 = fmaxf(m4, lg);
  }
  m0 = wmax(m0); m1 = wmax(m1); m2 = wmax(m2); m3 = wmax(m3); m4 = wmax(m4);

  // phase B: per-head sum of exp
  float s0 = 0.f, s1 = 0.f, s2 = 0.f, s3 = 0.f, s4 = 0.f;
  for (int s = l; s < deg; s += 64) {
    const int src = csr_src[off + s];
    const float* ap = a_s + src * 5;
    float lg;
    lg = ap[0] + ad0; lg = lg > 0.f ? lg : 0.2f * lg; s0 += __expf(lg - m0);
    lg = ap[1] + ad1; lg = lg > 0.f ? lg : 0.2f * lg; s1 += __expf(lg - m1);
    lg = ap[2] + ad2; lg = lg > 0.f ? lg : 0.2f * lg; s2 += __expf(lg - m2);
    lg = ap[3] + ad3; lg = lg > 0.f ? lg : 0.2f * lg; s3 += __expf(lg - m3);
    lg = ap[4] + ad4; lg = lg > 0.f ? lg : 0.2f * lg; s4 += __expf(lg - m4);
  }
  s0 = wsum(s0); s1 = wsum(s1); s2 = wsum(s2); s3 = wsum(s3); s4 = wsum(s4);
  const float i0 = 1.f / (s0 + 1e-16f), i1 = 1.f / (s1 + 1e-16f), i2 = 1.f / (s2 + 1e-16f),
              i3 = 1.f / (s3 + 1e-16f), i4 = 1.f / (s4 + 1e-16f);

  const int hA = l >> 4;  // head for cols 2l, 2l+1
  const float adA = hA == 0 ? ad0 : hA == 1 ? ad1 : hA == 2 ? ad2 : ad3;
  const float mA  = hA == 0 ? m0  : hA == 1 ? m1  : hA == 2 ? m2  : m3;
  const float iA  = hA == 0 ? i0  : hA == 1 ? i1  : hA == 2 ? i2  : i3;
  float adw = 0.f, mw = 0.f, iw = 0.f;
  if (l < 5) {
    adw = l == 0 ? ad0 : l == 1 ? ad1 : l == 2 ? ad2 : l == 3 ? ad3 : ad4;
    mw  = l == 0 ? m0  : l == 1 ? m1  : l == 2 ? m2  : l == 3 ? m3  : m4;
    iw  = l == 0 ? i0  : l == 1 ? i1  : l == 2 ? i2  : l == 3 ? i3  : i4;
  }

  float accx = 0.f, accy = 0.f, accz = 0.f;

  // phase C: aggregate messages + emit normalized alphas
  for (int s = 0; s < deg; ++s) {
    const int p = off + s;
    const int src = csr_src[p];
    const float* ap = a_s + src * 5;
    const long xb = (long)src * HID;
    float lgA = ap[hA] + adA; lgA = lgA > 0.f ? lgA : 0.2f * lgA;
    const float aA = __expf(lgA - mA) * iA;
    const float2 x2 = *(const float2*)(xl + xb + 2 * l);
    accx += x2.x * aA;
    accy += x2.y * aA;
    if (l < 32) {
      float lgC = ap[4] + ad4; lgC = lgC > 0.f ? lgC : 0.2f * lgC;
      const float aC = __expf(lgC - m4) * i4;
      accz += xl[xb + 128 + l] * aC;
    }
    if (l < 5) {
      float lg = ap[l] + adw; lg = lg > 0.f ? lg : 0.2f * lg;
      alpha_out[(long)csr_eid[p] * 5 + l] = __expf(lg - mw) * iw;
    }
  }

  // epilogue
  const int c0 = 2 * l, c2 = 128 + l;
  float v0 = accx + bias[c0];     v0 = v0 > 0.f ? v0 : 0.01f * v0;
  float v1 = accy + bias[c0 + 1]; v1 = v1 > 0.f ? v1 : 0.01f * v1;
  float v2 = 0.f;
  if (l < 32) { v2 = accz + bias[c2]; v2 = v2 > 0.f ? v2 : 0.01f * v2; }

  const long hb = (long)n * HID;
  if (DO_LN) {
    const float tot = wsum(v0 + v1 + v2);
    const float mean = tot * (1.f / 160.f);
    const float d0 = v0 - mean, d1 = v1 - mean;
    float sq = d0 * d0 + d1 * d1;
    float d2 = 0.f;
    if (l < 32) { d2 = v2 - mean; sq += d2 * d2; }
    const float var = wsum(sq) * (1.f / 160.f);
    const float rstd = rsqrtf(var + 1e-5f);
    hout[hb + c0]     = d0 * rstd * gamma_[c0]     + beta_[c0];
    hout[hb + c0 + 1] = d1 * rstd * gamma_[c0 + 1] + beta_[c0 + 1];
    if (l < 32) hout[hb + c2] = d2 * rstd * gamma_[c2] + beta_[c2];
  } else {
    hout[hb + c0]     = v0;
    hout[hb + c0 + 1] = v1;
    if (l < 32) hout[hb + c2] = v2;
  }
}

extern "C" void kernel_launch(void* const* d_in, const int* in_sizes, int n_in,
                              void* d_out, int out_size, void* d_ws, size_t ws_size,
                              hipStream_t stream)
{
  const float* x     = (const float*)d_in[0];
  const int*   ei    = (const int*)d_in[1];
  const float* W1    = (const float*)d_in[2];
  const float* att1s = (const float*)d_in[3];
  const float* att1d = (const float*)d_in[4];
  const float* b1    = (const float*)d_in[5];
  const float* g1    = (const float*)d_in[6];
  const float* be1   = (const float*)d_in[7];
  const float* W2    = (const float*)d_in[8];
  const float* att2s = (const float*)d_in[9];
  const float* att2d = (const float*)d_in[10];
  const float* b2    = (const float*)d_in[11];
  const float* Wm    = (const float*)d_in[12];
  const float* bm    = (const float*)d_in[13];

  float* out    = (float*)d_out;                      // [N,160]
  float* alpha1 = out + (long)N_NODES * HID;          // [E,5]
  float* alpha2 = alpha1 + (long)E_TOT * 5;           // [E,5]

  char* p = (char*)d_ws;
  auto alloc = [&](size_t bytes) { void* r = (void*)p; p += (bytes + 255) & ~(size_t)255; return r; };
  float* xl   = (float*)alloc((size_t)N_NODES * HID * 4);
  float* hbuf = (float*)alloc((size_t)N_NODES * HID * 4);
  float* as_  = (float*)alloc((size_t)N_NODES * 5 * 4);
  float* ad_  = (float*)alloc((size_t)N_NODES * 5 * 4);
  int* deg    = (int*)alloc((size_t)N_NODES * 4);
  int* fillc  = (int*)alloc((size_t)N_NODES * 4);
  int* off    = (int*)alloc((size_t)(N_NODES + 1) * 4);
  int* csrS   = (int*)alloc((size_t)E_TOT * 4);
  int* csrE   = (int*)alloc((size_t)E_TOT * 4);
  int* flag   = (int*)alloc(256);
  unsigned short* Bt1 = (unsigned short*)alloc((size_t)2 * HID * KPAD * 2);
  unsigned short* Bt2 = (unsigned short*)alloc((size_t)2 * HID * KPAD * 2);
  unsigned short* Btm = (unsigned short*)alloc((size_t)2 * HID * KPAD * 2);

  hipMemsetAsync(deg, 0, (size_t)N_NODES * 4, stream);
  hipMemsetAsync(fillc, 0, (size_t)N_NODES * 4, stream);

  detect_kernel<<<1, 64, 0, stream>>>(ei, flag);
  const int EB = (E_TOT + 255) / 256;
  count_kernel<<<EB, 256, 0, stream>>>(ei, flag, deg);
  scan_kernel<<<1, 1024, 0, stream>>>(deg, off);
  fill_kernel<<<EB, 256, 0, stream>>>(ei, flag, off, fillc, csrS, csrE);

  const int CB = (HID * KPAD + 255) / 256;
  convert_B<<<CB, 256, 0, stream>>>(W1, Bt1, F_IN_K);
  convert_B<<<CB, 256, 0, stream>>>(W2, Bt2, HID);
  convert_B<<<CB, 256, 0, stream>>>(Wm, Btm, HID);

  const int GB = (N_NODES + 63) / 64;

  // layer 1 (split-bf16: ~f32 accuracy, feeds LN which amplifies abs error)
  gemm_direct<F_IN_K, 0, 1><<<GB, 256, 0, stream>>>(x, Bt1, xl, nullptr);
  att_kernel<<<(N_NODES * 5 + 255) / 256, 256, 0, stream>>>(xl, att1s, att1d, as_, ad_);
  node_kernel<1><<<N_NODES / 4, 256, 0, stream>>>(off, csrS, csrE, xl, as_, ad_, alpha1, b1, g1, be1, hbuf);

  // layer 2
  gemm_direct<HID, 0, 0><<<GB, 256, 0, stream>>>(hbuf, Bt2, xl, nullptr);
  att_kernel<<<(N_NODES * 5 + 255) / 256, 256, 0, stream>>>(xl, att2s, att2d, as_, ad_);
  node_kernel<0><<<N_NODES / 4, 256, 0, stream>>>(off, csrS, csrE, xl, as_, ad_, alpha2, b2, nullptr, nullptr, hbuf);

  // final MLP: out = leaky(h2 @ Wm + bm)
  gemm_direct<HID, 1, 0><<<GB, 256, 0, stream>>>(hbuf, Btm, out, bm);
}

// Round 5
// 616.717 us; speedup vs baseline: 1.6309x; 1.3133x over previous
//
#include <hip/hip_runtime.h>

#define N_NODES 50000
#define E_RAW_N 800000
#define E_TOT   850000
#define F_IN_K  500
#define HID     160
#define KPAD    512

using short8 = __attribute__((ext_vector_type(8))) short;
using f32x4  = __attribute__((ext_vector_type(4))) float;

__device__ __forceinline__ float b2f(unsigned short u) {
  union { unsigned int i; float f; } v; v.i = ((unsigned int)u) << 16; return v.f;
}
__device__ __forceinline__ unsigned short f2b(float f) {
  union { float f; unsigned int i; } v; v.f = f;
  unsigned int i = v.i;
  unsigned int lsb = (i >> 16) & 1u;
  i += 0x7fffu + lsb;
  return (unsigned short)(i >> 16);
}

__device__ __forceinline__ float wsum(float x) {
  #pragma unroll
  for (int o = 32; o; o >>= 1) x += __shfl_xor(x, o, 64);
  return x;
}
__device__ __forceinline__ float wmax(float x) {
  #pragma unroll
  for (int o = 32; o; o >>= 1) x = fmaxf(x, __shfl_xor(x, o, 64));
  return x;
}
__device__ __forceinline__ float lrelu2(float x) { return x > 0.f ? x : 0.2f * x; }

// ---------------- edge dtype detection (int64 vs int32 hedge) ----------------
__global__ void detect_kernel(const int* __restrict__ ei, int* __restrict__ flag) {
  if (threadIdx.x == 0 && blockIdx.x == 0) {
    int allz = 1;
    for (int i = 1; i < 128; i += 2) if (ei[i] != 0) { allz = 0; break; }
    *flag = allz;  // 1 => int64 layout
  }
}
__device__ __forceinline__ int edge_src(const int* ei, int wide, int e) {
  return wide ? ei[2 * e] : ei[e];
}
__device__ __forceinline__ int edge_dst(const int* ei, int wide, int e) {
  return wide ? ei[2 * (E_RAW_N + e)] : ei[E_RAW_N + e];
}

// ---------------- weight pre-convert: B[K][160] f32 -> Bt hi/lo [160][KPAD] ---
__global__ __launch_bounds__(256) void convert_B(const float* __restrict__ B,
                                                 unsigned short* __restrict__ Bt, int K) {
  const int i = blockIdx.x * 256 + threadIdx.x;
  if (i >= HID * KPAD) return;
  const int c = i / KPAD, k = i % KPAD;
  const float b = (k < K) ? B[(long)k * HID + c] : 0.f;
  const unsigned short hi = f2b(b);
  Bt[i] = hi;
  Bt[HID * KPAD + i] = f2b(b - b2f(hi));
}

// ---------------- GEMM: C[M,160] = A[M,K] @ B, LDS-free ----------------------
// block = 4 waves; wave = 16 rows x 160 cols (10 col-tiles, 16x16x32 MFMA).
// SPLIT=1: 3-MFMA split-bf16 (~f32 accuracy). EPI 1: +bias, leaky(0.01).
// WH=1: also write bf16 copy to Ch (message-gather buffer).
template<int K, int EPI, int SPLIT, int WH>
__global__ __launch_bounds__(256) void gemm_direct(
    const float* __restrict__ A, const unsigned short* __restrict__ Bt,
    float* __restrict__ C, unsigned short* __restrict__ Ch,
    const float* __restrict__ bias)
{
  const int l = threadIdx.x & 63;
  const int w = threadIdx.x >> 6;
  const int m = l & 15;
  const int kgrp = (l >> 4) * 8;
  const int rbase = blockIdx.x * 64 + w * 16;
  const int arow = (rbase + m < N_NODES) ? rbase + m : N_NODES - 1;
  const float* Arow = A + (long)arow * K;

  f32x4 acc[10];
  #pragma unroll
  for (int i = 0; i < 10; ++i) acc[i] = (f32x4){0.f, 0.f, 0.f, 0.f};

  constexpr int KSTEPS = (K + 31) / 32;
  for (int ks = 0; ks < KSTEPS; ++ks) {
    const int kb = ks * 32 + kgrp;
    float a[8];
    if ((K % 32 == 0) || ks < KSTEPS - 1) {
      const float4 a0 = *(const float4*)(Arow + kb);
      const float4 a1 = *(const float4*)(Arow + kb + 4);
      a[0]=a0.x; a[1]=a0.y; a[2]=a0.z; a[3]=a0.w;
      a[4]=a1.x; a[5]=a1.y; a[6]=a1.z; a[7]=a1.w;
    } else {
      #pragma unroll
      for (int j = 0; j < 8; ++j) a[j] = (kb + j < K) ? Arow[kb + j] : 0.f;
    }
    short8 ah, al;
    #pragma unroll
    for (int j = 0; j < 8; ++j) {
      const unsigned short h = f2b(a[j]);
      ah[j] = (short)h;
      if (SPLIT) al[j] = (short)f2b(a[j] - b2f(h));
    }
    #pragma unroll
    for (int ct = 0; ct < 10; ++ct) {
      const long bo = (long)(ct * 16 + m) * KPAD + ks * 32 + kgrp;
      const short8 bh = *(const short8*)(Bt + bo);
      acc[ct] = __builtin_amdgcn_mfma_f32_16x16x32_bf16(ah, bh, acc[ct], 0, 0, 0);
      if (SPLIT) {
        const short8 bl = *(const short8*)(Bt + (long)HID * KPAD + bo);
        acc[ct] = __builtin_amdgcn_mfma_f32_16x16x32_bf16(ah, bl, acc[ct], 0, 0, 0);
        acc[ct] = __builtin_amdgcn_mfma_f32_16x16x32_bf16(al, bh, acc[ct], 0, 0, 0);
      }
    }
  }

  const int crow0 = rbase + (l >> 4) * 4;
  #pragma unroll
  for (int r = 0; r < 4; ++r) {
    const int crow = crow0 + r;
    if (crow < N_NODES) {
      #pragma unroll
      for (int ct = 0; ct < 10; ++ct) {
        const int col = ct * 16 + m;
        float v = acc[ct][r];
        if (EPI == 1) { v += bias[col]; v = v > 0.f ? v : 0.01f * v; }
        C[(long)crow * HID + col] = v;
        if (WH) Ch[(long)crow * HID + col] = f2b(v);
      }
    }
  }
}

// ---------------- attention dots: a_s[n,h] = xl[n,h,:]·att_s[h,:] -------------
__global__ __launch_bounds__(256) void att_kernel(
    const float* __restrict__ xl,
    const float* __restrict__ att_s, const float* __restrict__ att_d,
    float* __restrict__ a_s, float* __restrict__ a_d)
{
  const int i = blockIdx.x * 256 + threadIdx.x;
  if (i >= N_NODES * 5) return;
  const int h = i % 5;
  const int n = i / 5;
  const float4* xr = (const float4*)(xl + (long)n * HID + h * 32);
  const float4* sv4 = (const float4*)(att_s + h * 32);
  const float4* dv4 = (const float4*)(att_d + h * 32);
  float s = 0.f, d = 0.f;
  #pragma unroll
  for (int j = 0; j < 8; ++j) {
    const float4 xv = xr[j], sv = sv4[j], dv = dv4[j];
    s += xv.x * sv.x + xv.y * sv.y + xv.z * sv.z + xv.w * sv.w;
    d += xv.x * dv.x + xv.y * dv.y + xv.z * dv.z + xv.w * dv.w;
  }
  a_s[i] = s;
  a_d[i] = d;
}

// ---------------- CSR build ---------------------------------------------------
__global__ __launch_bounds__(256) void count_kernel(const int* __restrict__ ei,
    const int* __restrict__ flag, int* __restrict__ deg) {
  const int e = blockIdx.x * 256 + threadIdx.x;
  if (e >= E_TOT) return;
  const int wide = *flag;
  const int d = (e < E_RAW_N) ? edge_dst(ei, wide, e) : (e - E_RAW_N);
  atomicAdd(&deg[d], 1);
}

#define SCAN_CHUNK 49  // 1024*49 = 50176 >= 50000
__global__ __launch_bounds__(1024) void scan_kernel(const int* __restrict__ deg, int* __restrict__ off) {
  __shared__ int wtot[16];
  const int t = threadIdx.x;
  const int lane = t & 63, wid = t >> 6;
  const int base = t * SCAN_CHUNK;
  int local[SCAN_CHUNK];
  int sum = 0;
  #pragma unroll
  for (int i = 0; i < SCAN_CHUNK; ++i) {
    const int idx = base + i;
    const int v = (idx < N_NODES) ? deg[idx] : 0;
    local[i] = sum;
    sum += v;
  }
  int inc = sum;
  #pragma unroll
  for (int o = 1; o < 64; o <<= 1) {
    const int y = __shfl_up(inc, o, 64);
    if (lane >= o) inc += y;
  }
  if (lane == 63) wtot[wid] = inc;
  __syncthreads();
  if (wid == 0 && lane < 16) {
    const int v = wtot[lane];
    int inc2 = v;
    #pragma unroll
    for (int o = 1; o < 16; o <<= 1) {
      const int y = __shfl_up(inc2, o, 64);
      if (lane >= o) inc2 += y;
    }
    wtot[lane] = inc2 - v;  // exclusive
  }
  __syncthreads();
  const int pre = wtot[wid] + (inc - sum);
  #pragma unroll
  for (int i = 0; i < SCAN_CHUNK; ++i) {
    const int idx = base + i;
    if (idx < N_NODES) off[idx] = pre + local[i];
  }
  if (t == 1023) off[N_NODES] = E_TOT;
}

__global__ __launch_bounds__(256) void fill_kernel(const int* __restrict__ ei,
    const int* __restrict__ flag, const int* __restrict__ off,
    int* __restrict__ fillc, int* __restrict__ csr_src, int* __restrict__ csr_eid) {
  const int e = blockIdx.x * 256 + threadIdx.x;
  if (e >= E_TOT) return;
  const int wide = *flag;
  int s, d;
  if (e < E_RAW_N) { s = edge_src(ei, wide, e); d = edge_dst(ei, wide, e); }
  else { s = e - E_RAW_N; d = s; }
  const int p = off[d] + atomicAdd(&fillc[d], 1);
  csr_src[p] = s;
  csr_eid[p] = e;
}

// ---------------- fused per-node segment-softmax + aggregation ---------------
// one wave per dst node. Fast path (deg<=64): lane e owns edge e; a_s gathered
// ONCE; softmax + all-5 alphas in registers; coalesced 20B alpha store per
// lane; phase C gets alpha/src via shfl. Messages gathered from bf16 xlh
// (lane l owns cols {2l,2l+1}: head l>>4; l<32 also col 128+l: head 4).
template<int DO_LN>
__global__ __launch_bounds__(256) void node_kernel(
    const int* __restrict__ off_, const int* __restrict__ csr_src, const int* __restrict__ csr_eid,
    const unsigned short* __restrict__ xlh,
    const float* __restrict__ a_s, const float* __restrict__ a_d,
    float* __restrict__ alpha_out,
    const float* __restrict__ bias,
    const float* __restrict__ gamma_, const float* __restrict__ beta_,
    float* __restrict__ hout)
{
  const int w = threadIdx.x >> 6;
  const int l = threadIdx.x & 63;
  const int n = blockIdx.x * 4 + w;
  if (n >= N_NODES) return;
  const int off = off_[n];
  const int deg = off_[n + 1] - off;

  const float ad0 = a_d[n*5+0], ad1 = a_d[n*5+1], ad2 = a_d[n*5+2], ad3 = a_d[n*5+3], ad4 = a_d[n*5+4];
  const int hA = l >> 4;  // head for cols 2l, 2l+1
  float accx = 0.f, accy = 0.f, accz = 0.f;

  if (deg <= 64) {
    // ---- fast path: one lane per edge ----
    int src = 0, eid = 0;
    float v0 = -1e30f, v1 = -1e30f, v2 = -1e30f, v3 = -1e30f, v4 = -1e30f;
    if (l < deg) {
      src = csr_src[off + l];
      eid = csr_eid[off + l];
      const float* ap = a_s + src * 5;
      v0 = lrelu2(ap[0] + ad0);
      v1 = lrelu2(ap[1] + ad1);
      v2 = lrelu2(ap[2] + ad2);
      v3 = lrelu2(ap[3] + ad3);
      v4 = lrelu2(ap[4] + ad4);
    }
    const float m0 = wmax(v0), m1 = wmax(v1), m2 = wmax(v2), m3 = wmax(v3), m4 = wmax(v4);
    float e0 = 0.f, e1 = 0.f, e2 = 0.f, e3 = 0.f, e4 = 0.f;
    if (l < deg) {
      e0 = __expf(v0 - m0); e1 = __expf(v1 - m1); e2 = __expf(v2 - m2);
      e3 = __expf(v3 - m3); e4 = __expf(v4 - m4);
    }
    const float i0 = 1.f / (wsum(e0) + 1e-16f), i1 = 1.f / (wsum(e1) + 1e-16f),
                i2 = 1.f / (wsum(e2) + 1e-16f), i3 = 1.f / (wsum(e3) + 1e-16f),
                i4 = 1.f / (wsum(e4) + 1e-16f);
    const float a0 = e0 * i0, a1 = e1 * i1, a2 = e2 * i2, a3 = e3 * i3, a4 = e4 * i4;
    if (l < deg) {
      float* aw = alpha_out + (long)eid * 5;
      aw[0] = a0; aw[1] = a1; aw[2] = a2; aw[3] = a3; aw[4] = a4;
    }
    #pragma unroll 2
    for (int s = 0; s < deg; ++s) {
      const int srcs = __shfl(src, s, 64);
      const float b0 = __shfl(a0, s, 64), b1 = __shfl(a1, s, 64),
                  b2_ = __shfl(a2, s, 64), b3 = __shfl(a3, s, 64), b4 = __shfl(a4, s, 64);
      const float aA = hA == 0 ? b0 : hA == 1 ? b1 : hA == 2 ? b2_ : b3;
      const long xb = (long)srcs * HID;
      const ushort2 u2 = *(const ushort2*)(xlh + xb + 2 * l);
      accx += b2f(u2.x) * aA;
      accy += b2f(u2.y) * aA;
      if (l < 32) accz += b2f(xlh[xb + 128 + l]) * b4;
    }
  } else {
    // ---- slow path (rare): 3-pass over segment ----
    float m0 = -1e30f, m1 = -1e30f, m2 = -1e30f, m3 = -1e30f, m4 = -1e30f;
    for (int s = l; s < deg; s += 64) {
      const float* ap = a_s + csr_src[off + s] * 5;
      m0 = fmaxf(m0, lrelu2(ap[0] + ad0));
      m1 = fmaxf(m1, lrelu2(ap[1] + ad1));
      m2 = fmaxf(m2, lrelu2(ap[2] + ad2));
      m3 = fmaxf(m3, lrelu2(ap[3] + ad3));
      m4 = fmaxf(m4, lrelu2(ap[4] + ad4));
    }
    m0 = wmax(m0); m1 = wmax(m1); m2 = wmax(m2); m3 = wmax(m3); m4 = wmax(m4);
    float s0 = 0.f, s1 = 0.f, s2 = 0.f, s3 = 0.f, s4 = 0.f;
    for (int s = l; s < deg; s += 64) {
      const float* ap = a_s + csr_src[off + s] * 5;
      s0 += __expf(lrelu2(ap[0] + ad0) - m0);
      s1 += __expf(lrelu2(ap[1] + ad1) - m1);
      s2 += __expf(lrelu2(ap[2] + ad2) - m2);
      s3 += __expf(lrelu2(ap[3] + ad3) - m3);
      s4 += __expf(lrelu2(ap[4] + ad4) - m4);
    }
    const float i0 = 1.f / (wsum(s0) + 1e-16f), i1 = 1.f / (wsum(s1) + 1e-16f),
                i2 = 1.f / (wsum(s2) + 1e-16f), i3 = 1.f / (wsum(s3) + 1e-16f),
                i4 = 1.f / (wsum(s4) + 1e-16f);
    const float adA = hA == 0 ? ad0 : hA == 1 ? ad1 : hA == 2 ? ad2 : ad3;
    const float mA  = hA == 0 ? m0  : hA == 1 ? m1  : hA == 2 ? m2  : m3;
    const float iA  = hA == 0 ? i0  : hA == 1 ? i1  : hA == 2 ? i2  : i3;
    float adw = 0.f, mw = 0.f, iw = 0.f;
    if (l < 5) {
      adw = l == 0 ? ad0 : l == 1 ? ad1 : l == 2 ? ad2 : l == 3 ? ad3 : ad4;
      mw  = l == 0 ? m0  : l == 1 ? m1  : l == 2 ? m2  : l == 3 ? m3  : m4;
      iw  = l == 0 ? i0  : l == 1 ? i1  : l == 2 ? i2  : l == 3 ? i3  : i4;
    }
    for (int s = 0; s < deg; ++s) {
      const int p = off + s;
      const int srcs = csr_src[p];
      const float* ap = a_s + srcs * 5;
      const float aA = __expf(lrelu2(ap[hA] + adA) - mA) * iA;
      const long xb = (long)srcs * HID;
      const ushort2 u2 = *(const ushort2*)(xlh + xb + 2 * l);
      accx += b2f(u2.x) * aA;
      accy += b2f(u2.y) * aA;
      if (l < 32) {
        const float aC = __expf(lrelu2(ap[4] + ad4) - m4) * i4;
        accz += b2f(xlh[xb + 128 + l]) * aC;
      }
      if (l < 5) {
        alpha_out[(long)csr_eid[p] * 5 + l] = __expf(lrelu2(ap[l] + adw) - mw) * iw;
      }
    }
  }

  // epilogue
  const int c0 = 2 * l, c2 = 128 + l;
  float v0 = accx + bias[c0];     v0 = v0 > 0.f ? v0 : 0.01f * v0;
  float v1 = accy + bias[c0 + 1]; v1 = v1 > 0.f ? v1 : 0.01f * v1;
  float v2 = 0.f;
  if (l < 32) { v2 = accz + bias[c2]; v2 = v2 > 0.f ? v2 : 0.01f * v2; }

  const long hb = (long)n * HID;
  if (DO_LN) {
    const float tot = wsum(v0 + v1 + v2);
    const float mean = tot * (1.f / 160.f);
    const float d0 = v0 - mean, d1 = v1 - mean;
    float sq = d0 * d0 + d1 * d1;
    float d2 = 0.f;
    if (l < 32) { d2 = v2 - mean; sq += d2 * d2; }
    const float var = wsum(sq) * (1.f / 160.f);
    const float rstd = rsqrtf(var + 1e-5f);
    hout[hb + c0]     = d0 * rstd * gamma_[c0]     + beta_[c0];
    hout[hb + c0 + 1] = d1 * rstd * gamma_[c0 + 1] + beta_[c0 + 1];
    if (l < 32) hout[hb + c2] = d2 * rstd * gamma_[c2] + beta_[c2];
  } else {
    hout[hb + c0]     = v0;
    hout[hb + c0 + 1] = v1;
    if (l < 32) hout[hb + c2] = v2;
  }
}

extern "C" void kernel_launch(void* const* d_in, const int* in_sizes, int n_in,
                              void* d_out, int out_size, void* d_ws, size_t ws_size,
                              hipStream_t stream)
{
  const float* x     = (const float*)d_in[0];
  const int*   ei    = (const int*)d_in[1];
  const float* W1    = (const float*)d_in[2];
  const float* att1s = (const float*)d_in[3];
  const float* att1d = (const float*)d_in[4];
  const float* b1    = (const float*)d_in[5];
  const float* g1    = (const float*)d_in[6];
  const float* be1   = (const float*)d_in[7];
  const float* W2    = (const float*)d_in[8];
  const float* att2s = (const float*)d_in[9];
  const float* att2d = (const float*)d_in[10];
  const float* b2    = (const float*)d_in[11];
  const float* Wm    = (const float*)d_in[12];
  const float* bm    = (const float*)d_in[13];

  float* out    = (float*)d_out;                      // [N,160]
  float* alpha1 = out + (long)N_NODES * HID;          // [E,5]
  float* alpha2 = alpha1 + (long)E_TOT * 5;           // [E,5]

  char* p = (char*)d_ws;
  auto alloc = [&](size_t bytes) { void* r = (void*)p; p += (bytes + 255) & ~(size_t)255; return r; };
  float* xl   = (float*)alloc((size_t)N_NODES * HID * 4);
  float* hbuf = (float*)alloc((size_t)N_NODES * HID * 4);
  unsigned short* xlh = (unsigned short*)alloc((size_t)N_NODES * HID * 2);
  float* as_  = (float*)alloc((size_t)N_NODES * 5 * 4);
  float* ad_  = (float*)alloc((size_t)N_NODES * 5 * 4);
  int* deg    = (int*)alloc((size_t)N_NODES * 4);
  int* fillc  = (int*)alloc((size_t)N_NODES * 4);
  int* off    = (int*)alloc((size_t)(N_NODES + 1) * 4);
  int* csrS   = (int*)alloc((size_t)E_TOT * 4);
  int* csrE   = (int*)alloc((size_t)E_TOT * 4);
  int* flag   = (int*)alloc(256);
  unsigned short* Bt1 = (unsigned short*)alloc((size_t)2 * HID * KPAD * 2);
  unsigned short* Bt2 = (unsigned short*)alloc((size_t)2 * HID * KPAD * 2);
  unsigned short* Btm = (unsigned short*)alloc((size_t)2 * HID * KPAD * 2);

  hipMemsetAsync(deg, 0, (size_t)N_NODES * 4, stream);
  hipMemsetAsync(fillc, 0, (size_t)N_NODES * 4, stream);

  detect_kernel<<<1, 64, 0, stream>>>(ei, flag);
  const int EB = (E_TOT + 255) / 256;
  count_kernel<<<EB, 256, 0, stream>>>(ei, flag, deg);
  scan_kernel<<<1, 1024, 0, stream>>>(deg, off);
  fill_kernel<<<EB, 256, 0, stream>>>(ei, flag, off, fillc, csrS, csrE);

  const int CB = (HID * KPAD + 255) / 256;
  convert_B<<<CB, 256, 0, stream>>>(W1, Bt1, F_IN_K);
  convert_B<<<CB, 256, 0, stream>>>(W2, Bt2, HID);
  convert_B<<<CB, 256, 0, stream>>>(Wm, Btm, HID);

  const int GB = (N_NODES + 63) / 64;

  // layer 1 (split-bf16: ~f32 accuracy, feeds LN which amplifies abs error)
  gemm_direct<F_IN_K, 0, 1, 1><<<GB, 256, 0, stream>>>(x, Bt1, xl, xlh, nullptr);
  att_kernel<<<(N_NODES * 5 + 255) / 256, 256, 0, stream>>>(xl, att1s, att1d, as_, ad_);
  node_kernel<1><<<N_NODES / 4, 256, 0, stream>>>(off, csrS, csrE, xlh, as_, ad_, alpha1, b1, g1, be1, hbuf);

  // layer 2
  gemm_direct<HID, 0, 0, 1><<<GB, 256, 0, stream>>>(hbuf, Bt2, xl, xlh, nullptr);
  att_kernel<<<(N_NODES * 5 + 255) / 256, 256, 0, stream>>>(xl, att2s, att2d, as_, ad_);
  node_kernel<0><<<N_NODES / 4, 256, 0, stream>>>(off, csrS, csrE, xlh, as_, ad_, alpha2, b2, nullptr, nullptr, hbuf);

  // final MLP: out = leaky(h2 @ Wm + bm)
  gemm_direct<HID, 1, 0, 0><<<GB, 256, 0, stream>>>(hbuf, Btm, out, nullptr, bm);
}

// Round 6
// 591.742 us; speedup vs baseline: 1.6997x; 1.0422x over previous
//
#include <hip/hip_runtime.h>

#define N_NODES 50000
#define E_RAW_N 800000
#define E_TOT   850000
#define F_IN_K  500
#define HID     160
#define KPAD    512

using short8 = __attribute__((ext_vector_type(8))) short;
using f32x4  = __attribute__((ext_vector_type(4))) float;

__device__ __forceinline__ float b2f(unsigned short u) {
  union { unsigned int i; float f; } v; v.i = ((unsigned int)u) << 16; return v.f;
}
__device__ __forceinline__ unsigned short f2b(float f) {
  union { float f; unsigned int i; } v; v.f = f;
  unsigned int i = v.i;
  unsigned int lsb = (i >> 16) & 1u;
  i += 0x7fffu + lsb;
  return (unsigned short)(i >> 16);
}

__device__ __forceinline__ float wsum(float x) {
  #pragma unroll
  for (int o = 32; o; o >>= 1) x += __shfl_xor(x, o, 64);
  return x;
}
__device__ __forceinline__ float wmax(float x) {
  #pragma unroll
  for (int o = 32; o; o >>= 1) x = fmaxf(x, __shfl_xor(x, o, 64));
  return x;
}
__device__ __forceinline__ float lrelu2(float x) { return x > 0.f ? x : 0.2f * x; }

// ---------------- edge dtype detection (int64 vs int32 hedge) ----------------
__global__ void detect_kernel(const int* __restrict__ ei, int* __restrict__ flag) {
  if (threadIdx.x == 0 && blockIdx.x == 0) {
    int allz = 1;
    for (int i = 1; i < 128; i += 2) if (ei[i] != 0) { allz = 0; break; }
    *flag = allz;  // 1 => int64 layout
  }
}
__device__ __forceinline__ int edge_src(const int* ei, int wide, int e) {
  return wide ? ei[2 * e] : ei[e];
}
__device__ __forceinline__ int edge_dst(const int* ei, int wide, int e) {
  return wide ? ei[2 * (E_RAW_N + e)] : ei[E_RAW_N + e];
}

// ---------------- weight pre-convert: B[K][160] f32 -> Bt hi/lo [160][KPAD] ---
__global__ __launch_bounds__(256) void convert_B(const float* __restrict__ B,
                                                 unsigned short* __restrict__ Bt, int K) {
  const int i = blockIdx.x * 256 + threadIdx.x;
  if (i >= HID * KPAD) return;
  const int c = i / KPAD, k = i % KPAD;
  const float b = (k < K) ? B[(long)k * HID + c] : 0.f;
  const unsigned short hi = f2b(b);
  Bt[i] = hi;
  Bt[HID * KPAD + i] = f2b(b - b2f(hi));
}

// ---------------- GEMM: [M,160] = A[M,K] @ B, LDS-free, K-pipelined ----------
// block = 4 waves; wave = 16 rows x 160 cols (10 col-tiles, 16x16x32 MFMA).
// SPLIT=1: 3-MFMA split-bf16 (~f32 accuracy).
// MODE 0: C f32 store. MODE 1: +bias, leaky(0.01), C f32 store.
// MODE 2: bf16 store to Ch + FUSED attention dots -> a_s, a_d (no f32 C).
template<int K, int MODE, int SPLIT>
__global__ __launch_bounds__(256, 3) void gemm_direct(
    const float* __restrict__ A, const unsigned short* __restrict__ Bt,
    float* __restrict__ C, unsigned short* __restrict__ Ch,
    const float* __restrict__ bias,
    const float* __restrict__ att_s, const float* __restrict__ att_d,
    float* __restrict__ a_s, float* __restrict__ a_d)
{
  const int l = threadIdx.x & 63;
  const int w = threadIdx.x >> 6;
  const int m = l & 15;
  const int kgrp = (l >> 4) * 8;
  const int rbase = blockIdx.x * 64 + w * 16;
  const int arow = (rbase + m < N_NODES) ? rbase + m : N_NODES - 1;
  const float* Arow = A + (long)arow * K;

  f32x4 acc[10];
  #pragma unroll
  for (int i = 0; i < 10; ++i) acc[i] = (f32x4){0.f, 0.f, 0.f, 0.f};

  constexpr int FULL = K / 32;
  constexpr int TAIL = K % 32;

  // prologue: load ks=0
  float4 ca0 = *(const float4*)(Arow + kgrp);
  float4 ca1 = *(const float4*)(Arow + kgrp + 4);

  for (int ks = 0; ks < FULL; ++ks) {
    // prefetch next K-step while computing this one
    float4 na0 = {0.f,0.f,0.f,0.f}, na1 = {0.f,0.f,0.f,0.f};
    if (ks + 1 < FULL) {
      na0 = *(const float4*)(Arow + (ks + 1) * 32 + kgrp);
      na1 = *(const float4*)(Arow + (ks + 1) * 32 + kgrp + 4);
    } else if (TAIL) {
      const int kb = FULL * 32 + kgrp;
      float t[8];
      #pragma unroll
      for (int j = 0; j < 8; ++j) t[j] = (kb + j < K) ? Arow[kb + j] : 0.f;
      na0 = (float4){t[0], t[1], t[2], t[3]};
      na1 = (float4){t[4], t[5], t[6], t[7]};
    }
    float a[8] = {ca0.x, ca0.y, ca0.z, ca0.w, ca1.x, ca1.y, ca1.z, ca1.w};
    short8 ah, al;
    #pragma unroll
    for (int j = 0; j < 8; ++j) {
      const unsigned short h = f2b(a[j]);
      ah[j] = (short)h;
      if (SPLIT) al[j] = (short)f2b(a[j] - b2f(h));
    }
    #pragma unroll
    for (int ct = 0; ct < 10; ++ct) {
      const long bo = (long)(ct * 16 + m) * KPAD + ks * 32 + kgrp;
      const short8 bh = *(const short8*)(Bt + bo);
      acc[ct] = __builtin_amdgcn_mfma_f32_16x16x32_bf16(ah, bh, acc[ct], 0, 0, 0);
      if (SPLIT) {
        const short8 bl = *(const short8*)(Bt + (long)HID * KPAD + bo);
        acc[ct] = __builtin_amdgcn_mfma_f32_16x16x32_bf16(ah, bl, acc[ct], 0, 0, 0);
        acc[ct] = __builtin_amdgcn_mfma_f32_16x16x32_bf16(al, bh, acc[ct], 0, 0, 0);
      }
    }
    ca0 = na0; ca1 = na1;
  }
  if (TAIL) {  // tail K-step (data already in ca)
    float a[8] = {ca0.x, ca0.y, ca0.z, ca0.w, ca1.x, ca1.y, ca1.z, ca1.w};
    short8 ah, al;
    #pragma unroll
    for (int j = 0; j < 8; ++j) {
      const unsigned short h = f2b(a[j]);
      ah[j] = (short)h;
      if (SPLIT) al[j] = (short)f2b(a[j] - b2f(h));
    }
    #pragma unroll
    for (int ct = 0; ct < 10; ++ct) {
      const long bo = (long)(ct * 16 + m) * KPAD + FULL * 32 + kgrp;
      const short8 bh = *(const short8*)(Bt + bo);
      acc[ct] = __builtin_amdgcn_mfma_f32_16x16x32_bf16(ah, bh, acc[ct], 0, 0, 0);
      if (SPLIT) {
        const short8 bl = *(const short8*)(Bt + (long)HID * KPAD + bo);
        acc[ct] = __builtin_amdgcn_mfma_f32_16x16x32_bf16(ah, bl, acc[ct], 0, 0, 0);
        acc[ct] = __builtin_amdgcn_mfma_f32_16x16x32_bf16(al, bh, acc[ct], 0, 0, 0);
      }
    }
  }

  const int crow0 = rbase + (l >> 4) * 4;

  if (MODE == 2) {
    // fused attention dots: a_s[n,h] = sum_c xl[n,c] * att_s[h*32+c]
    #pragma unroll
    for (int r = 0; r < 4; ++r) {
      float ps[5], pd[5];
      #pragma unroll
      for (int h = 0; h < 5; ++h) {
        float s = acc[2*h][r]     * att_s[(2*h) * 16 + m]
                + acc[2*h + 1][r] * att_s[(2*h + 1) * 16 + m];
        float d = acc[2*h][r]     * att_d[(2*h) * 16 + m]
                + acc[2*h + 1][r] * att_d[(2*h + 1) * 16 + m];
        #pragma unroll
        for (int o = 1; o < 16; o <<= 1) {
          s += __shfl_xor(s, o, 64);
          d += __shfl_xor(d, o, 64);
        }
        ps[h] = s; pd[h] = d;
      }
      const int crow = crow0 + r;
      if (crow < N_NODES && m < 5) {
        const float vs = m == 0 ? ps[0] : m == 1 ? ps[1] : m == 2 ? ps[2] : m == 3 ? ps[3] : ps[4];
        const float vd = m == 0 ? pd[0] : m == 1 ? pd[1] : m == 2 ? pd[2] : m == 3 ? pd[3] : pd[4];
        a_s[crow * 5 + m] = vs;
        a_d[crow * 5 + m] = vd;
      }
    }
  }

  #pragma unroll
  for (int r = 0; r < 4; ++r) {
    const int crow = crow0 + r;
    if (crow < N_NODES) {
      #pragma unroll
      for (int ct = 0; ct < 10; ++ct) {
        const int col = ct * 16 + m;
        float v = acc[ct][r];
        if (MODE == 1) { v += bias[col]; v = v > 0.f ? v : 0.01f * v; }
        if (MODE == 2) Ch[(long)crow * HID + col] = f2b(v);
        else           C[(long)crow * HID + col] = v;
      }
    }
  }
}

// ---------------- CSR build ---------------------------------------------------
__global__ __launch_bounds__(256) void count_kernel(const int* __restrict__ ei,
    const int* __restrict__ flag, int* __restrict__ deg) {
  const int e = blockIdx.x * 256 + threadIdx.x;
  if (e >= E_TOT) return;
  const int wide = *flag;
  const int d = (e < E_RAW_N) ? edge_dst(ei, wide, e) : (e - E_RAW_N);
  atomicAdd(&deg[d], 1);
}

#define SCAN_CHUNK 49  // 1024*49 = 50176 >= 50000
__global__ __launch_bounds__(1024) void scan_kernel(const int* __restrict__ deg, int* __restrict__ off) {
  __shared__ int wtot[16];
  const int t = threadIdx.x;
  const int lane = t & 63, wid = t >> 6;
  const int base = t * SCAN_CHUNK;
  int local[SCAN_CHUNK];
  int sum = 0;
  #pragma unroll
  for (int i = 0; i < SCAN_CHUNK; ++i) {
    const int idx = base + i;
    const int v = (idx < N_NODES) ? deg[idx] : 0;
    local[i] = sum;
    sum += v;
  }
  int inc = sum;
  #pragma unroll
  for (int o = 1; o < 64; o <<= 1) {
    const int y = __shfl_up(inc, o, 64);
    if (lane >= o) inc += y;
  }
  if (lane == 63) wtot[wid] = inc;
  __syncthreads();
  if (wid == 0 && lane < 16) {
    const int v = wtot[lane];
    int inc2 = v;
    #pragma unroll
    for (int o = 1; o < 16; o <<= 1) {
      const int y = __shfl_up(inc2, o, 64);
      if (lane >= o) inc2 += y;
    }
    wtot[lane] = inc2 - v;  // exclusive
  }
  __syncthreads();
  const int pre = wtot[wid] + (inc - sum);
  #pragma unroll
  for (int i = 0; i < SCAN_CHUNK; ++i) {
    const int idx = base + i;
    if (idx < N_NODES) off[idx] = pre + local[i];
  }
  if (t == 1023) off[N_NODES] = E_TOT;
}

__global__ __launch_bounds__(256) void fill_kernel(const int* __restrict__ ei,
    const int* __restrict__ flag, const int* __restrict__ off,
    int* __restrict__ fillc, int* __restrict__ csr_src, int* __restrict__ csr_eid) {
  const int e = blockIdx.x * 256 + threadIdx.x;
  if (e >= E_TOT) return;
  const int wide = *flag;
  int s, d;
  if (e < E_RAW_N) { s = edge_src(ei, wide, e); d = edge_dst(ei, wide, e); }
  else { s = e - E_RAW_N; d = s; }
  const int p = off[d] + atomicAdd(&fillc[d], 1);
  csr_src[p] = s;
  csr_eid[p] = e;
}

// ---------------- fused per-node segment-softmax + aggregation ---------------
template<int DO_LN>
__global__ __launch_bounds__(256) void node_kernel(
    const int* __restrict__ off_, const int* __restrict__ csr_src, const int* __restrict__ csr_eid,
    const unsigned short* __restrict__ xlh,
    const float* __restrict__ a_s, const float* __restrict__ a_d,
    float* __restrict__ alpha_out,
    const float* __restrict__ bias,
    const float* __restrict__ gamma_, const float* __restrict__ beta_,
    float* __restrict__ hout)
{
  const int w = threadIdx.x >> 6;
  const int l = threadIdx.x & 63;
  const int n = blockIdx.x * 4 + w;
  if (n >= N_NODES) return;
  const int off = off_[n];
  const int deg = off_[n + 1] - off;

  const float ad0 = a_d[n*5+0], ad1 = a_d[n*5+1], ad2 = a_d[n*5+2], ad3 = a_d[n*5+3], ad4 = a_d[n*5+4];
  const int hA = l >> 4;  // head for cols 2l, 2l+1
  float accx = 0.f, accy = 0.f, accz = 0.f;

  if (deg <= 64) {
    // ---- fast path: one lane per edge ----
    int src = 0, eid = 0;
    float v0 = -1e30f, v1 = -1e30f, v2 = -1e30f, v3 = -1e30f, v4 = -1e30f;
    if (l < deg) {
      src = csr_src[off + l];
      eid = csr_eid[off + l];
      const float* ap = a_s + src * 5;
      v0 = lrelu2(ap[0] + ad0);
      v1 = lrelu2(ap[1] + ad1);
      v2 = lrelu2(ap[2] + ad2);
      v3 = lrelu2(ap[3] + ad3);
      v4 = lrelu2(ap[4] + ad4);
    }
    const float m0 = wmax(v0), m1 = wmax(v1), m2 = wmax(v2), m3 = wmax(v3), m4 = wmax(v4);
    float e0 = 0.f, e1 = 0.f, e2 = 0.f, e3 = 0.f, e4 = 0.f;
    if (l < deg) {
      e0 = __expf(v0 - m0); e1 = __expf(v1 - m1); e2 = __expf(v2 - m2);
      e3 = __expf(v3 - m3); e4 = __expf(v4 - m4);
    }
    const float i0 = 1.f / (wsum(e0) + 1e-16f), i1 = 1.f / (wsum(e1) + 1e-16f),
                i2 = 1.f / (wsum(e2) + 1e-16f), i3 = 1.f / (wsum(e3) + 1e-16f),
                i4 = 1.f / (wsum(e4) + 1e-16f);
    const float a0 = e0 * i0, a1 = e1 * i1, a2 = e2 * i2, a3 = e3 * i3, a4 = e4 * i4;
    if (l < deg) {
      float* aw = alpha_out + (long)eid * 5;
      aw[0] = a0; aw[1] = a1; aw[2] = a2; aw[3] = a3; aw[4] = a4;
    }
    #pragma unroll 2
    for (int s = 0; s < deg; ++s) {
      const int srcs = __shfl(src, s, 64);
      const float b0 = __shfl(a0, s, 64), b1 = __shfl(a1, s, 64),
                  b2_ = __shfl(a2, s, 64), b3 = __shfl(a3, s, 64), b4 = __shfl(a4, s, 64);
      const float aA = hA == 0 ? b0 : hA == 1 ? b1 : hA == 2 ? b2_ : b3;
      const long xb = (long)srcs * HID;
      const ushort2 u2 = *(const ushort2*)(xlh + xb + 2 * l);
      accx += b2f(u2.x) * aA;
      accy += b2f(u2.y) * aA;
      if (l < 32) accz += b2f(xlh[xb + 128 + l]) * b4;
    }
  } else {
    // ---- slow path (rare): 3-pass over segment ----
    float m0 = -1e30f, m1 = -1e30f, m2 = -1e30f, m3 = -1e30f, m4 = -1e30f;
    for (int s = l; s < deg; s += 64) {
      const float* ap = a_s + csr_src[off + s] * 5;
      m0 = fmaxf(m0, lrelu2(ap[0] + ad0));
      m1 = fmaxf(m1, lrelu2(ap[1] + ad1));
      m2 = fmaxf(m2, lrelu2(ap[2] + ad2));
      m3 = fmaxf(m3, lrelu2(ap[3] + ad3));
      m4 = fmaxf(m4, lrelu2(ap[4] + ad4));
    }
    m0 = wmax(m0); m1 = wmax(m1); m2 = wmax(m2); m3 = wmax(m3); m4 = wmax(m4);
    float s0 = 0.f, s1 = 0.f, s2 = 0.f, s3 = 0.f, s4 = 0.f;
    for (int s = l; s < deg; s += 64) {
      const float* ap = a_s + csr_src[off + s] * 5;
      s0 += __expf(lrelu2(ap[0] + ad0) - m0);
      s1 += __expf(lrelu2(ap[1] + ad1) - m1);
      s2 += __expf(lrelu2(ap[2] + ad2) - m2);
      s3 += __expf(lrelu2(ap[3] + ad3) - m3);
      s4 += __expf(lrelu2(ap[4] + ad4) - m4);
    }
    const float i0 = 1.f / (wsum(s0) + 1e-16f), i1 = 1.f / (wsum(s1) + 1e-16f),
                i2 = 1.f / (wsum(s2) + 1e-16f), i3 = 1.f / (wsum(s3) + 1e-16f),
                i4 = 1.f / (wsum(s4) + 1e-16f);
    const float adA = hA == 0 ? ad0 : hA == 1 ? ad1 : hA == 2 ? ad2 : ad3;
    const float mA  = hA == 0 ? m0  : hA == 1 ? m1  : hA == 2 ? m2  : m3;
    const float iA  = hA == 0 ? i0  : hA == 1 ? i1  : hA == 2 ? i2  : i3;
    float adw = 0.f, mw = 0.f, iw = 0.f;
    if (l < 5) {
      adw = l == 0 ? ad0 : l == 1 ? ad1 : l == 2 ? ad2 : l == 3 ? ad3 : ad4;
      mw  = l == 0 ? m0  : l == 1 ? m1  : l == 2 ? m2  : l == 3 ? m3  : m4;
      iw  = l == 0 ? i0  : l == 1 ? i1  : l == 2 ? i2  : l == 3 ? i3  : i4;
    }
    for (int s = 0; s < deg; ++s) {
      const int p = off + s;
      const int srcs = csr_src[p];
      const float* ap = a_s + srcs * 5;
      const float aA = __expf(lrelu2(ap[hA] + adA) - mA) * iA;
      const long xb = (long)srcs * HID;
      const ushort2 u2 = *(const ushort2*)(xlh + xb + 2 * l);
      accx += b2f(u2.x) * aA;
      accy += b2f(u2.y) * aA;
      if (l < 32) {
        const float aC = __expf(lrelu2(ap[4] + ad4) - m4) * i4;
        accz += b2f(xlh[xb + 128 + l]) * aC;
      }
      if (l < 5) {
        alpha_out[(long)csr_eid[p] * 5 + l] = __expf(lrelu2(ap[l] + adw) - mw) * iw;
      }
    }
  }

  // epilogue
  const int c0 = 2 * l, c2 = 128 + l;
  float v0 = accx + bias[c0];     v0 = v0 > 0.f ? v0 : 0.01f * v0;
  float v1 = accy + bias[c0 + 1]; v1 = v1 > 0.f ? v1 : 0.01f * v1;
  float v2 = 0.f;
  if (l < 32) { v2 = accz + bias[c2]; v2 = v2 > 0.f ? v2 : 0.01f * v2; }

  const long hb = (long)n * HID;
  if (DO_LN) {
    const float tot = wsum(v0 + v1 + v2);
    const float mean = tot * (1.f / 160.f);
    const float d0 = v0 - mean, d1 = v1 - mean;
    float sq = d0 * d0 + d1 * d1;
    float d2 = 0.f;
    if (l < 32) { d2 = v2 - mean; sq += d2 * d2; }
    const float var = wsum(sq) * (1.f / 160.f);
    const float rstd = rsqrtf(var + 1e-5f);
    hout[hb + c0]     = d0 * rstd * gamma_[c0]     + beta_[c0];
    hout[hb + c0 + 1] = d1 * rstd * gamma_[c0 + 1] + beta_[c0 + 1];
    if (l < 32) hout[hb + c2] = d2 * rstd * gamma_[c2] + beta_[c2];
  } else {
    hout[hb + c0]     = v0;
    hout[hb + c0 + 1] = v1;
    if (l < 32) hout[hb + c2] = v2;
  }
}

extern "C" void kernel_launch(void* const* d_in, const int* in_sizes, int n_in,
                              void* d_out, int out_size, void* d_ws, size_t ws_size,
                              hipStream_t stream)
{
  const float* x     = (const float*)d_in[0];
  const int*   ei    = (const int*)d_in[1];
  const float* W1    = (const float*)d_in[2];
  const float* att1s = (const float*)d_in[3];
  const float* att1d = (const float*)d_in[4];
  const float* b1    = (const float*)d_in[5];
  const float* g1    = (const float*)d_in[6];
  const float* be1   = (const float*)d_in[7];
  const float* W2    = (const float*)d_in[8];
  const float* att2s = (const float*)d_in[9];
  const float* att2d = (const float*)d_in[10];
  const float* b2    = (const float*)d_in[11];
  const float* Wm    = (const float*)d_in[12];
  const float* bm    = (const float*)d_in[13];

  float* out    = (float*)d_out;                      // [N,160]
  float* alpha1 = out + (long)N_NODES * HID;          // [E,5]
  float* alpha2 = alpha1 + (long)E_TOT * 5;           // [E,5]

  char* p = (char*)d_ws;
  auto alloc = [&](size_t bytes) { void* r = (void*)p; p += (bytes + 255) & ~(size_t)255; return r; };
  float* hbuf = (float*)alloc((size_t)N_NODES * HID * 4);
  unsigned short* xlh = (unsigned short*)alloc((size_t)N_NODES * HID * 2);
  float* as_  = (float*)alloc((size_t)N_NODES * 5 * 4);
  float* ad_  = (float*)alloc((size_t)N_NODES * 5 * 4);
  int* deg    = (int*)alloc((size_t)N_NODES * 4);
  int* fillc  = (int*)alloc((size_t)N_NODES * 4);
  int* off    = (int*)alloc((size_t)(N_NODES + 1) * 4);
  int* csrS   = (int*)alloc((size_t)E_TOT * 4);
  int* csrE   = (int*)alloc((size_t)E_TOT * 4);
  int* flag   = (int*)alloc(256);
  unsigned short* Bt1 = (unsigned short*)alloc((size_t)2 * HID * KPAD * 2);
  unsigned short* Bt2 = (unsigned short*)alloc((size_t)2 * HID * KPAD * 2);
  unsigned short* Btm = (unsigned short*)alloc((size_t)2 * HID * KPAD * 2);

  hipMemsetAsync(deg, 0, (size_t)N_NODES * 4, stream);
  hipMemsetAsync(fillc, 0, (size_t)N_NODES * 4, stream);

  detect_kernel<<<1, 64, 0, stream>>>(ei, flag);
  const int EB = (E_TOT + 255) / 256;
  count_kernel<<<EB, 256, 0, stream>>>(ei, flag, deg);
  scan_kernel<<<1, 1024, 0, stream>>>(deg, off);
  fill_kernel<<<EB, 256, 0, stream>>>(ei, flag, off, fillc, csrS, csrE);

  const int CB = (HID * KPAD + 255) / 256;
  convert_B<<<CB, 256, 0, stream>>>(W1, Bt1, F_IN_K);
  convert_B<<<CB, 256, 0, stream>>>(W2, Bt2, HID);
  convert_B<<<CB, 256, 0, stream>>>(Wm, Btm, HID);

  const int GB = (N_NODES + 63) / 64;

  // layer 1: split-bf16 GEMM + fused attention dots -> xlh, a_s, a_d
  gemm_direct<F_IN_K, 2, 1><<<GB, 256, 0, stream>>>(x, Bt1, nullptr, xlh, nullptr, att1s, att1d, as_, ad_);
  node_kernel<1><<<N_NODES / 4, 256, 0, stream>>>(off, csrS, csrE, xlh, as_, ad_, alpha1, b1, g1, be1, hbuf);

  // layer 2
  gemm_direct<HID, 2, 0><<<GB, 256, 0, stream>>>(hbuf, Bt2, nullptr, xlh, nullptr, att2s, att2d, as_, ad_);
  node_kernel<0><<<N_NODES / 4, 256, 0, stream>>>(off, csrS, csrE, xlh, as_, ad_, alpha2, b2, nullptr, nullptr, hbuf);

  // final MLP: out = leaky(h2 @ Wm + bm)
  gemm_direct<HID, 1, 0><<<GB, 256, 0, stream>>>(hbuf, Btm, out, nullptr, bm, nullptr, nullptr, nullptr, nullptr);
}

// Round 7
// 589.676 us; speedup vs baseline: 1.7057x; 1.0035x over previous
//
#include <hip/hip_runtime.h>

#define N_NODES 50000
#define E_RAW_N 800000
#define E_TOT   850000
#define F_IN_K  500
#define HID     160
#define KPAD    512

using short8 = __attribute__((ext_vector_type(8))) short;
using f32x4  = __attribute__((ext_vector_type(4))) float;

__device__ __forceinline__ float b2f(unsigned short u) {
  union { unsigned int i; float f; } v; v.i = ((unsigned int)u) << 16; return v.f;
}
__device__ __forceinline__ unsigned short f2b(float f) {
  union { float f; unsigned int i; } v; v.f = f;
  unsigned int i = v.i;
  unsigned int lsb = (i >> 16) & 1u;
  i += 0x7fffu + lsb;
  return (unsigned short)(i >> 16);
}

__device__ __forceinline__ float wsum(float x) {
  #pragma unroll
  for (int o = 32; o; o >>= 1) x += __shfl_xor(x, o, 64);
  return x;
}
__device__ __forceinline__ float wmax(float x) {
  #pragma unroll
  for (int o = 32; o; o >>= 1) x = fmaxf(x, __shfl_xor(x, o, 64));
  return x;
}
__device__ __forceinline__ float lrelu2(float x) { return x > 0.f ? x : 0.2f * x; }

// ---------------- edge dtype detection (int64 vs int32 hedge) ----------------
__global__ void detect_kernel(const int* __restrict__ ei, int* __restrict__ flag) {
  if (threadIdx.x == 0 && blockIdx.x == 0) {
    int allz = 1;
    for (int i = 1; i < 128; i += 2) if (ei[i] != 0) { allz = 0; break; }
    *flag = allz;  // 1 => int64 layout
  }
}
__device__ __forceinline__ int edge_src(const int* ei, int wide, int e) {
  return wide ? ei[2 * e] : ei[e];
}
__device__ __forceinline__ int edge_dst(const int* ei, int wide, int e) {
  return wide ? ei[2 * (E_RAW_N + e)] : ei[E_RAW_N + e];
}

// ---------------- weight pre-convert: B[K][160] f32 -> Bt hi/lo [160][KPAD] ---
__global__ __launch_bounds__(256) void convert_B(const float* __restrict__ B,
                                                 unsigned short* __restrict__ Bt, int K) {
  const int i = blockIdx.x * 256 + threadIdx.x;
  if (i >= HID * KPAD) return;
  const int c = i / KPAD, k = i % KPAD;
  const float b = (k < K) ? B[(long)k * HID + c] : 0.f;
  const unsigned short hi = f2b(b);
  Bt[i] = hi;
  Bt[HID * KPAD + i] = f2b(b - b2f(hi));
}

// ---------------- GEMM: [M,160] = A[M,K] @ B, LDS-free, K-pipelined ----------
// block = 4 waves; wave = 16 rows x 160 cols (10 col-tiles, 16x16x32 MFMA).
// B fragments for a K-step are BATCH-loaded into registers (one L2 latency
// per K-step instead of ~10 serialized ones).
// SPLIT=1: 3-MFMA split-bf16 (~f32 accuracy).
// MODE 0: C f32 store. MODE 1: +bias, leaky(0.01), C f32 store.
// MODE 2: bf16 store to Ch + FUSED attention dots -> a_s, a_d (no f32 C).
template<int K, int MODE, int SPLIT>
__global__ __launch_bounds__(256, 3) void gemm_direct(
    const float* __restrict__ A, const unsigned short* __restrict__ Bt,
    float* __restrict__ C, unsigned short* __restrict__ Ch,
    const float* __restrict__ bias,
    const float* __restrict__ att_s, const float* __restrict__ att_d,
    float* __restrict__ a_s, float* __restrict__ a_d)
{
  const int l = threadIdx.x & 63;
  const int w = threadIdx.x >> 6;
  const int m = l & 15;
  const int kgrp = (l >> 4) * 8;
  const int rbase = blockIdx.x * 64 + w * 16;
  const int arow = (rbase + m < N_NODES) ? rbase + m : N_NODES - 1;
  const float* Arow = A + (long)arow * K;
  const unsigned short* Bl = Bt + (long)m * KPAD + kgrp;  // lane base, hi plane

  f32x4 acc[10];
  #pragma unroll
  for (int i = 0; i < 10; ++i) acc[i] = (f32x4){0.f, 0.f, 0.f, 0.f};

  constexpr int FULL = K / 32;
  constexpr int TAIL = K % 32;
  constexpr int STEPS = FULL + (TAIL ? 1 : 0);

  // prologue: load ks=0 A
  float4 ca0 = *(const float4*)(Arow + kgrp);
  float4 ca1 = *(const float4*)(Arow + kgrp + 4);

  for (int ks = 0; ks < STEPS; ++ks) {
    // ---- batch-load all B fragments for this K-step ----
    short8 bh[10], bl[10];
    #pragma unroll
    for (int ct = 0; ct < 10; ++ct) {
      const long bo = (long)ct * 16 * KPAD + ks * 32;
      bh[ct] = *(const short8*)(Bl + bo);
      if (SPLIT) bl[ct] = *(const short8*)(Bl + (long)HID * KPAD + bo);
    }
    // ---- prefetch next A K-step ----
    float4 na0 = {0.f,0.f,0.f,0.f}, na1 = {0.f,0.f,0.f,0.f};
    if (ks + 1 < FULL) {
      na0 = *(const float4*)(Arow + (ks + 1) * 32 + kgrp);
      na1 = *(const float4*)(Arow + (ks + 1) * 32 + kgrp + 4);
    } else if (TAIL && ks + 1 == FULL) {
      const int kb = FULL * 32 + kgrp;
      float t[8];
      #pragma unroll
      for (int j = 0; j < 8; ++j) t[j] = (kb + j < K) ? Arow[kb + j] : 0.f;
      na0 = (float4){t[0], t[1], t[2], t[3]};
      na1 = (float4){t[4], t[5], t[6], t[7]};
    }
    // ---- convert A to bf16 hi/lo ----
    float a[8] = {ca0.x, ca0.y, ca0.z, ca0.w, ca1.x, ca1.y, ca1.z, ca1.w};
    short8 ah, al;
    #pragma unroll
    for (int j = 0; j < 8; ++j) {
      const unsigned short h = f2b(a[j]);
      ah[j] = (short)h;
      if (SPLIT) al[j] = (short)f2b(a[j] - b2f(h));
    }
    // ---- MFMA chain ----
    #pragma unroll
    for (int ct = 0; ct < 10; ++ct) {
      acc[ct] = __builtin_amdgcn_mfma_f32_16x16x32_bf16(ah, bh[ct], acc[ct], 0, 0, 0);
      if (SPLIT) {
        acc[ct] = __builtin_amdgcn_mfma_f32_16x16x32_bf16(ah, bl[ct], acc[ct], 0, 0, 0);
        acc[ct] = __builtin_amdgcn_mfma_f32_16x16x32_bf16(al, bh[ct], acc[ct], 0, 0, 0);
      }
    }
    ca0 = na0; ca1 = na1;
  }

  const int crow0 = rbase + (l >> 4) * 4;

  if (MODE == 2) {
    // fused attention dots: a_s[n,h] = sum_c xl[n,c] * att_s[h*32+c]
    #pragma unroll
    for (int r = 0; r < 4; ++r) {
      float ps[5], pd[5];
      #pragma unroll
      for (int h = 0; h < 5; ++h) {
        float s = acc[2*h][r]     * att_s[(2*h) * 16 + m]
                + acc[2*h + 1][r] * att_s[(2*h + 1) * 16 + m];
        float d = acc[2*h][r]     * att_d[(2*h) * 16 + m]
                + acc[2*h + 1][r] * att_d[(2*h + 1) * 16 + m];
        #pragma unroll
        for (int o = 1; o < 16; o <<= 1) {
          s += __shfl_xor(s, o, 64);
          d += __shfl_xor(d, o, 64);
        }
        ps[h] = s; pd[h] = d;
      }
      const int crow = crow0 + r;
      if (crow < N_NODES && m < 5) {
        const float vs = m == 0 ? ps[0] : m == 1 ? ps[1] : m == 2 ? ps[2] : m == 3 ? ps[3] : ps[4];
        const float vd = m == 0 ? pd[0] : m == 1 ? pd[1] : m == 2 ? pd[2] : m == 3 ? pd[3] : pd[4];
        a_s[crow * 5 + m] = vs;
        a_d[crow * 5 + m] = vd;
      }
    }
  }

  #pragma unroll
  for (int r = 0; r < 4; ++r) {
    const int crow = crow0 + r;
    if (crow < N_NODES) {
      #pragma unroll
      for (int ct = 0; ct < 10; ++ct) {
        const int col = ct * 16 + m;
        float v = acc[ct][r];
        if (MODE == 1) { v += bias[col]; v = v > 0.f ? v : 0.01f * v; }
        if (MODE == 2) Ch[(long)crow * HID + col] = f2b(v);
        else           C[(long)crow * HID + col] = v;
      }
    }
  }
}

// ---------------- CSR build ---------------------------------------------------
__global__ __launch_bounds__(256) void count_kernel(const int* __restrict__ ei,
    const int* __restrict__ flag, int* __restrict__ deg) {
  const int e = blockIdx.x * 256 + threadIdx.x;
  if (e >= E_TOT) return;
  const int wide = *flag;
  const int d = (e < E_RAW_N) ? edge_dst(ei, wide, e) : (e - E_RAW_N);
  atomicAdd(&deg[d], 1);
}

#define SCAN_CHUNK 49  // 1024*49 = 50176 >= 50000
__global__ __launch_bounds__(1024) void scan_kernel(const int* __restrict__ deg, int* __restrict__ off) {
  __shared__ int wtot[16];
  const int t = threadIdx.x;
  const int lane = t & 63, wid = t >> 6;
  const int base = t * SCAN_CHUNK;
  int local[SCAN_CHUNK];
  int sum = 0;
  #pragma unroll
  for (int i = 0; i < SCAN_CHUNK; ++i) {
    const int idx = base + i;
    const int v = (idx < N_NODES) ? deg[idx] : 0;
    local[i] = sum;
    sum += v;
  }
  int inc = sum;
  #pragma unroll
  for (int o = 1; o < 64; o <<= 1) {
    const int y = __shfl_up(inc, o, 64);
    if (lane >= o) inc += y;
  }
  if (lane == 63) wtot[wid] = inc;
  __syncthreads();
  if (wid == 0 && lane < 16) {
    const int v = wtot[lane];
    int inc2 = v;
    #pragma unroll
    for (int o = 1; o < 16; o <<= 1) {
      const int y = __shfl_up(inc2, o, 64);
      if (lane >= o) inc2 += y;
    }
    wtot[lane] = inc2 - v;  // exclusive
  }
  __syncthreads();
  const int pre = wtot[wid] + (inc - sum);
  #pragma unroll
  for (int i = 0; i < SCAN_CHUNK; ++i) {
    const int idx = base + i;
    if (idx < N_NODES) off[idx] = pre + local[i];
  }
  if (t == 1023) off[N_NODES] = E_TOT;
}

__global__ __launch_bounds__(256) void fill_kernel(const int* __restrict__ ei,
    const int* __restrict__ flag, const int* __restrict__ off,
    int* __restrict__ fillc, int* __restrict__ csr_src, int* __restrict__ csr_eid) {
  const int e = blockIdx.x * 256 + threadIdx.x;
  if (e >= E_TOT) return;
  const int wide = *flag;
  int s, d;
  if (e < E_RAW_N) { s = edge_src(ei, wide, e); d = edge_dst(ei, wide, e); }
  else { s = e - E_RAW_N; d = s; }
  const int p = off[d] + atomicAdd(&fillc[d], 1);
  csr_src[p] = s;
  csr_eid[p] = e;
}

// ---------------- fused per-node segment-softmax + aggregation ---------------
template<int DO_LN>
__global__ __launch_bounds__(256) void node_kernel(
    const int* __restrict__ off_, const int* __restrict__ csr_src, const int* __restrict__ csr_eid,
    const unsigned short* __restrict__ xlh,
    const float* __restrict__ a_s, const float* __restrict__ a_d,
    float* __restrict__ alpha_out,
    const float* __restrict__ bias,
    const float* __restrict__ gamma_, const float* __restrict__ beta_,
    float* __restrict__ hout)
{
  const int w = threadIdx.x >> 6;
  const int l = threadIdx.x & 63;
  const int n = blockIdx.x * 4 + w;
  if (n >= N_NODES) return;
  const int off = off_[n];
  const int deg = off_[n + 1] - off;

  const float ad0 = a_d[n*5+0], ad1 = a_d[n*5+1], ad2 = a_d[n*5+2], ad3 = a_d[n*5+3], ad4 = a_d[n*5+4];
  const int hA = l >> 4;  // head for cols 2l, 2l+1
  float accx = 0.f, accy = 0.f, accz = 0.f;

  if (deg <= 64) {
    // ---- fast path: one lane per edge ----
    int src = 0, eid = 0;
    float v0 = -1e30f, v1 = -1e30f, v2 = -1e30f, v3 = -1e30f, v4 = -1e30f;
    if (l < deg) {
      src = csr_src[off + l];
      eid = csr_eid[off + l];
      const float* ap = a_s + src * 5;
      v0 = lrelu2(ap[0] + ad0);
      v1 = lrelu2(ap[1] + ad1);
      v2 = lrelu2(ap[2] + ad2);
      v3 = lrelu2(ap[3] + ad3);
      v4 = lrelu2(ap[4] + ad4);
    }
    const float m0 = wmax(v0), m1 = wmax(v1), m2 = wmax(v2), m3 = wmax(v3), m4 = wmax(v4);
    float e0 = 0.f, e1 = 0.f, e2 = 0.f, e3 = 0.f, e4 = 0.f;
    if (l < deg) {
      e0 = __expf(v0 - m0); e1 = __expf(v1 - m1); e2 = __expf(v2 - m2);
      e3 = __expf(v3 - m3); e4 = __expf(v4 - m4);
    }
    const float i0 = 1.f / (wsum(e0) + 1e-16f), i1 = 1.f / (wsum(e1) + 1e-16f),
                i2 = 1.f / (wsum(e2) + 1e-16f), i3 = 1.f / (wsum(e3) + 1e-16f),
                i4 = 1.f / (wsum(e4) + 1e-16f);
    const float a0 = e0 * i0, a1 = e1 * i1, a2 = e2 * i2, a3 = e3 * i3, a4 = e4 * i4;
    if (l < deg) {
      float* aw = alpha_out + (long)eid * 5;
      aw[0] = a0; aw[1] = a1; aw[2] = a2; aw[3] = a3; aw[4] = a4;
    }
    #pragma unroll 2
    for (int s = 0; s < deg; ++s) {
      const int srcs = __shfl(src, s, 64);
      const float b0 = __shfl(a0, s, 64), b1 = __shfl(a1, s, 64),
                  b2_ = __shfl(a2, s, 64), b3 = __shfl(a3, s, 64), b4 = __shfl(a4, s, 64);
      const float aA = hA == 0 ? b0 : hA == 1 ? b1 : hA == 2 ? b2_ : b3;
      const long xb = (long)srcs * HID;
      const ushort2 u2 = *(const ushort2*)(xlh + xb + 2 * l);
      accx += b2f(u2.x) * aA;
      accy += b2f(u2.y) * aA;
      if (l < 32) accz += b2f(xlh[xb + 128 + l]) * b4;
    }
  } else {
    // ---- slow path (rare): 3-pass over segment ----
    float m0 = -1e30f, m1 = -1e30f, m2 = -1e30f, m3 = -1e30f, m4 = -1e30f;
    for (int s = l; s < deg; s += 64) {
      const float* ap = a_s + csr_src[off + s] * 5;
      m0 = fmaxf(m0, lrelu2(ap[0] + ad0));
      m1 = fmaxf(m1, lrelu2(ap[1] + ad1));
      m2 = fmaxf(m2, lrelu2(ap[2] + ad2));
      m3 = fmaxf(m3, lrelu2(ap[3] + ad3));
      m4 = fmaxf(m4, lrelu2(ap[4] + ad4));
    }
    m0 = wmax(m0); m1 = wmax(m1); m2 = wmax(m2); m3 = wmax(m3); m4 = wmax(m4);
    float s0 = 0.f, s1 = 0.f, s2 = 0.f, s3 = 0.f, s4 = 0.f;
    for (int s = l; s < deg; s += 64) {
      const float* ap = a_s + csr_src[off + s] * 5;
      s0 += __expf(lrelu2(ap[0] + ad0) - m0);
      s1 += __expf(lrelu2(ap[1] + ad1) - m1);
      s2 += __expf(lrelu2(ap[2] + ad2) - m2);
      s3 += __expf(lrelu2(ap[3] + ad3) - m3);
      s4 += __expf(lrelu2(ap[4] + ad4) - m4);
    }
    const float i0 = 1.f / (wsum(s0) + 1e-16f), i1 = 1.f / (wsum(s1) + 1e-16f),
                i2 = 1.f / (wsum(s2) + 1e-16f), i3 = 1.f / (wsum(s3) + 1e-16f),
                i4 = 1.f / (wsum(s4) + 1e-16f);
    const float adA = hA == 0 ? ad0 : hA == 1 ? ad1 : hA == 2 ? ad2 : ad3;
    const float mA  = hA == 0 ? m0  : hA == 1 ? m1  : hA == 2 ? m2  : m3;
    const float iA  = hA == 0 ? i0  : hA == 1 ? i1  : hA == 2 ? i2  : i3;
    float adw = 0.f, mw = 0.f, iw = 0.f;
    if (l < 5) {
      adw = l == 0 ? ad0 : l == 1 ? ad1 : l == 2 ? ad2 : l == 3 ? ad3 : ad4;
      mw  = l == 0 ? m0  : l == 1 ? m1  : l == 2 ? m2  : l == 3 ? m3  : m4;
      iw  = l == 0 ? i0  : l == 1 ? i1  : l == 2 ? i2  : l == 3 ? i3  : i4;
    }
    for (int s = 0; s < deg; ++s) {
      const int p = off + s;
      const int srcs = csr_src[p];
      const float* ap = a_s + srcs * 5;
      const float aA = __expf(lrelu2(ap[hA] + adA) - mA) * iA;
      const long xb = (long)srcs * HID;
      const ushort2 u2 = *(const ushort2*)(xlh + xb + 2 * l);
      accx += b2f(u2.x) * aA;
      accy += b2f(u2.y) * aA;
      if (l < 32) {
        const float aC = __expf(lrelu2(ap[4] + ad4) - m4) * i4;
        accz += b2f(xlh[xb + 128 + l]) * aC;
      }
      if (l < 5) {
        alpha_out[(long)csr_eid[p] * 5 + l] = __expf(lrelu2(ap[l] + adw) - mw) * iw;
      }
    }
  }

  // epilogue
  const int c0 = 2 * l, c2 = 128 + l;
  float v0 = accx + bias[c0];     v0 = v0 > 0.f ? v0 : 0.01f * v0;
  float v1 = accy + bias[c0 + 1]; v1 = v1 > 0.f ? v1 : 0.01f * v1;
  float v2 = 0.f;
  if (l < 32) { v2 = accz + bias[c2]; v2 = v2 > 0.f ? v2 : 0.01f * v2; }

  const long hb = (long)n * HID;
  if (DO_LN) {
    const float tot = wsum(v0 + v1 + v2);
    const float mean = tot * (1.f / 160.f);
    const float d0 = v0 - mean, d1 = v1 - mean;
    float sq = d0 * d0 + d1 * d1;
    float d2 = 0.f;
    if (l < 32) { d2 = v2 - mean; sq += d2 * d2; }
    const float var = wsum(sq) * (1.f / 160.f);
    const float rstd = rsqrtf(var + 1e-5f);
    hout[hb + c0]     = d0 * rstd * gamma_[c0]     + beta_[c0];
    hout[hb + c0 + 1] = d1 * rstd * gamma_[c0 + 1] + beta_[c0 + 1];
    if (l < 32) hout[hb + c2] = d2 * rstd * gamma_[c2] + beta_[c2];
  } else {
    hout[hb + c0]     = v0;
    hout[hb + c0 + 1] = v1;
    if (l < 32) hout[hb + c2] = v2;
  }
}

extern "C" void kernel_launch(void* const* d_in, const int* in_sizes, int n_in,
                              void* d_out, int out_size, void* d_ws, size_t ws_size,
                              hipStream_t stream)
{
  const float* x     = (const float*)d_in[0];
  const int*   ei    = (const int*)d_in[1];
  const float* W1    = (const float*)d_in[2];
  const float* att1s = (const float*)d_in[3];
  const float* att1d = (const float*)d_in[4];
  const float* b1    = (const float*)d_in[5];
  const float* g1    = (const float*)d_in[6];
  const float* be1   = (const float*)d_in[7];
  const float* W2    = (const float*)d_in[8];
  const float* att2s = (const float*)d_in[9];
  const float* att2d = (const float*)d_in[10];
  const float* b2    = (const float*)d_in[11];
  const float* Wm    = (const float*)d_in[12];
  const float* bm    = (const float*)d_in[13];

  float* out    = (float*)d_out;                      // [N,160]
  float* alpha1 = out + (long)N_NODES * HID;          // [E,5]
  float* alpha2 = alpha1 + (long)E_TOT * 5;           // [E,5]

  char* p = (char*)d_ws;
  auto alloc = [&](size_t bytes) { void* r = (void*)p; p += (bytes + 255) & ~(size_t)255; return r; };
  float* hbuf = (float*)alloc((size_t)N_NODES * HID * 4);
  unsigned short* xlh = (unsigned short*)alloc((size_t)N_NODES * HID * 2);
  float* as_  = (float*)alloc((size_t)N_NODES * 5 * 4);
  float* ad_  = (float*)alloc((size_t)N_NODES * 5 * 4);
  int* deg    = (int*)alloc((size_t)N_NODES * 4);
  int* fillc  = (int*)alloc((size_t)N_NODES * 4);
  int* off    = (int*)alloc((size_t)(N_NODES + 1) * 4);
  int* csrS   = (int*)alloc((size_t)E_TOT * 4);
  int* csrE   = (int*)alloc((size_t)E_TOT * 4);
  int* flag   = (int*)alloc(256);
  unsigned short* Bt1 = (unsigned short*)alloc((size_t)2 * HID * KPAD * 2);
  unsigned short* Bt2 = (unsigned short*)alloc((size_t)2 * HID * KPAD * 2);
  unsigned short* Btm = (unsigned short*)alloc((size_t)2 * HID * KPAD * 2);

  hipMemsetAsync(deg, 0, (size_t)N_NODES * 4, stream);
  hipMemsetAsync(fillc, 0, (size_t)N_NODES * 4, stream);

  detect_kernel<<<1, 64, 0, stream>>>(ei, flag);
  const int EB = (E_TOT + 255) / 256;
  count_kernel<<<EB, 256, 0, stream>>>(ei, flag, deg);
  scan_kernel<<<1, 1024, 0, stream>>>(deg, off);
  fill_kernel<<<EB, 256, 0, stream>>>(ei, flag, off, fillc, csrS, csrE);

  const int CB = (HID * KPAD + 255) / 256;
  convert_B<<<CB, 256, 0, stream>>>(W1, Bt1, F_IN_K);
  convert_B<<<CB, 256, 0, stream>>>(W2, Bt2, HID);
  convert_B<<<CB, 256, 0, stream>>>(Wm, Btm, HID);

  const int GB = (N_NODES + 63) / 64;

  // layer 1: split-bf16 GEMM + fused attention dots -> xlh, a_s, a_d
  gemm_direct<F_IN_K, 2, 1><<<GB, 256, 0, stream>>>(x, Bt1, nullptr, xlh, nullptr, att1s, att1d, as_, ad_);
  node_kernel<1><<<N_NODES / 4, 256, 0, stream>>>(off, csrS, csrE, xlh, as_, ad_, alpha1, b1, g1, be1, hbuf);

  // layer 2
  gemm_direct<HID, 2, 0><<<GB, 256, 0, stream>>>(hbuf, Bt2, nullptr, xlh, nullptr, att2s, att2d, as_, ad_);
  node_kernel<0><<<N_NODES / 4, 256, 0, stream>>>(off, csrS, csrE, xlh, as_, ad_, alpha2, b2, nullptr, nullptr, hbuf);

  // final MLP: out = leaky(h2 @ Wm + bm)
  gemm_direct<HID, 1, 0><<<GB, 256, 0, stream>>>(hbuf, Btm, out, nullptr, bm, nullptr, nullptr, nullptr, nullptr);
}

// Round 8
// 505.920 us; speedup vs baseline: 1.9881x; 1.1656x over previous
//
#include <hip/hip_runtime.h>

#define N_NODES 50000
#define E_RAW_N 800000
#define E_TOT   850000
#define F_IN_K  500
#define HID     160

using short8 = __attribute__((ext_vector_type(8))) short;
using f32x4  = __attribute__((ext_vector_type(4))) float;

__device__ __forceinline__ float b2f(unsigned short u) {
  union { unsigned int i; float f; } v; v.i = ((unsigned int)u) << 16; return v.f;
}
__device__ __forceinline__ unsigned short f2b(float f) {
  union { float f; unsigned int i; } v; v.f = f;
  unsigned int i = v.i;
  unsigned int lsb = (i >> 16) & 1u;
  i += 0x7fffu + lsb;
  return (unsigned short)(i >> 16);
}

__device__ __forceinline__ float wsum(float x) {
  #pragma unroll
  for (int o = 32; o; o >>= 1) x += __shfl_xor(x, o, 64);
  return x;
}
__device__ __forceinline__ float wmax(float x) {
  #pragma unroll
  for (int o = 32; o; o >>= 1) x = fmaxf(x, __shfl_xor(x, o, 64));
  return x;
}
__device__ __forceinline__ float lrelu2(float x) { return x > 0.f ? x : 0.2f * x; }

// ---------------- edge dtype detection (int64 vs int32 hedge) ----------------
__global__ void detect_kernel(const int* __restrict__ ei, int* __restrict__ flag) {
  if (threadIdx.x == 0 && blockIdx.x == 0) {
    int allz = 1;
    for (int i = 1; i < 128; i += 2) if (ei[i] != 0) { allz = 0; break; }
    *flag = allz;  // 1 => int64 layout
  }
}
__device__ __forceinline__ int edge_src(const int* ei, int wide, int e) {
  return wide ? ei[2 * e] : ei[e];
}
__device__ __forceinline__ int edge_dst(const int* ei, int wide, int e) {
  return wide ? ei[2 * (E_RAW_N + e)] : ei[E_RAW_N + e];
}

// ------- weight pre-convert: B[K][160] f32 -> Bt hi/lo planes [160][KPAD] ----
__global__ __launch_bounds__(256) void convert_B(const float* __restrict__ B,
                                                 unsigned short* __restrict__ Bt,
                                                 int K, int KPAD) {
  const int i = blockIdx.x * 256 + threadIdx.x;
  if (i >= HID * KPAD) return;
  const int c = i / KPAD, k = i % KPAD;
  const float b = (k < K) ? B[(long)k * HID + c] : 0.f;
  const unsigned short hi = f2b(b);
  Bt[i] = hi;
  Bt[HID * KPAD + i] = f2b(b - b2f(hi));
}

// ---------------- GEMM: [M,160] = A[M,K] @ B, LDS-staged B -------------------
// block = 4 waves; wave = 16 rows x 160 cols (10 col-tiles, 16x16x32 MFMA).
// B staged chunk-wise into LDS (padded stride, bank-uniform); A prefetched
// per chunk into registers before the staging barrier (HBM latency hidden).
// SPLIT=1: 3-MFMA split-bf16 (~f32 accuracy).
// MODE 0: C f32. MODE 1: +bias, leaky(0.01), C f32.
// MODE 2: bf16 -> Ch + fused attention dots -> a_s, a_d.
template<int K, int KPAD, int BK, int MODE, int SPLIT>
__global__ __launch_bounds__(256) void gemm_lds(
    const float* __restrict__ A, const unsigned short* __restrict__ Bt,
    float* __restrict__ C, unsigned short* __restrict__ Ch,
    const float* __restrict__ bias,
    const float* __restrict__ att_s, const float* __restrict__ att_d,
    float* __restrict__ a_s, float* __restrict__ a_d)
{
  constexpr int NP = SPLIT ? 2 : 1;
  constexpr int LSTR = BK + 8;          // padded stride (elems), keeps 16B align
  constexpr int CHUNKS = KPAD / BK;
  constexpr int KSC = BK / 32;          // K-steps per chunk
  __shared__ __align__(16) unsigned short Bs[NP][HID][LSTR];

  const int t = threadIdx.x;
  const int l = t & 63;
  const int w = t >> 6;
  const int m = l & 15;
  const int kgrp = (l >> 4) * 8;
  const int rbase = blockIdx.x * 64 + w * 16;
  const int arow = (rbase + m < N_NODES) ? rbase + m : N_NODES - 1;
  const float* Arow = A + (long)arow * K;

  f32x4 acc[10];
  #pragma unroll
  for (int i = 0; i < 10; ++i) acc[i] = (f32x4){0.f, 0.f, 0.f, 0.f};

  for (int cc = 0; cc < CHUNKS; ++cc) {
    // ---- prefetch this chunk's A fragments (regs; overlaps staging) ----
    float ar[KSC][8];
    #pragma unroll
    for (int ks = 0; ks < KSC; ++ks) {
      const int kb = cc * BK + ks * 32 + kgrp;
      if (kb + 8 <= K) {
        const float4 a0 = *(const float4*)(Arow + kb);
        const float4 a1 = *(const float4*)(Arow + kb + 4);
        ar[ks][0]=a0.x; ar[ks][1]=a0.y; ar[ks][2]=a0.z; ar[ks][3]=a0.w;
        ar[ks][4]=a1.x; ar[ks][5]=a1.y; ar[ks][6]=a1.z; ar[ks][7]=a1.w;
      } else {
        #pragma unroll
        for (int j = 0; j < 8; ++j) ar[ks][j] = (kb + j < K) ? Arow[kb + j] : 0.f;
      }
    }

    if (cc) __syncthreads();   // previous chunk's reads done before overwrite
    // ---- stage B chunk into LDS ----
    constexpr int UNITS = NP * HID * (BK / 8);
    for (int u = t; u < UNITS; u += 256) {
      const int p = u / (HID * (BK / 8));
      const int rem = u % (HID * (BK / 8));
      const int c = rem / (BK / 8);
      const int k8 = rem % (BK / 8);
      const short8 v = *(const short8*)(Bt + (long)p * HID * KPAD + (long)c * KPAD + cc * BK + k8 * 8);
      *(short8*)&Bs[p][c][k8 * 8] = v;
    }
    __syncthreads();

    // ---- compute ----
    #pragma unroll
    for (int ks = 0; ks < KSC; ++ks) {
      short8 ah, al;
      #pragma unroll
      for (int j = 0; j < 8; ++j) {
        const unsigned short h = f2b(ar[ks][j]);
        ah[j] = (short)h;
        if (SPLIT) al[j] = (short)f2b(ar[ks][j] - b2f(h));
      }
      #pragma unroll
      for (int ct = 0; ct < 10; ++ct) {
        const short8 bh = *(const short8*)&Bs[0][ct * 16 + m][ks * 32 + kgrp];
        acc[ct] = __builtin_amdgcn_mfma_f32_16x16x32_bf16(ah, bh, acc[ct], 0, 0, 0);
        if (SPLIT) {
          const short8 bl = *(const short8*)&Bs[SPLIT][ct * 16 + m][ks * 32 + kgrp];
          acc[ct] = __builtin_amdgcn_mfma_f32_16x16x32_bf16(ah, bl, acc[ct], 0, 0, 0);
          acc[ct] = __builtin_amdgcn_mfma_f32_16x16x32_bf16(al, bh, acc[ct], 0, 0, 0);
        }
      }
    }
  }

  const int crow0 = rbase + (l >> 4) * 4;

  if (MODE == 2) {
    // fused attention dots: a_s[n,h] = sum_c xl[n,c] * att_s[h*32+c]
    #pragma unroll
    for (int r = 0; r < 4; ++r) {
      float ps[5], pd[5];
      #pragma unroll
      for (int h = 0; h < 5; ++h) {
        float s = acc[2*h][r]     * att_s[(2*h) * 16 + m]
                + acc[2*h + 1][r] * att_s[(2*h + 1) * 16 + m];
        float d = acc[2*h][r]     * att_d[(2*h) * 16 + m]
                + acc[2*h + 1][r] * att_d[(2*h + 1) * 16 + m];
        #pragma unroll
        for (int o = 1; o < 16; o <<= 1) {
          s += __shfl_xor(s, o, 64);
          d += __shfl_xor(d, o, 64);
        }
        ps[h] = s; pd[h] = d;
      }
      const int crow = crow0 + r;
      if (crow < N_NODES && m < 5) {
        const float vs = m == 0 ? ps[0] : m == 1 ? ps[1] : m == 2 ? ps[2] : m == 3 ? ps[3] : ps[4];
        const float vd = m == 0 ? pd[0] : m == 1 ? pd[1] : m == 2 ? pd[2] : m == 3 ? pd[3] : pd[4];
        a_s[crow * 5 + m] = vs;
        a_d[crow * 5 + m] = vd;
      }
    }
  }

  #pragma unroll
  for (int r = 0; r < 4; ++r) {
    const int crow = crow0 + r;
    if (crow < N_NODES) {
      #pragma unroll
      for (int ct = 0; ct < 10; ++ct) {
        const int col = ct * 16 + m;
        float v = acc[ct][r];
        if (MODE == 1) { v += bias[col]; v = v > 0.f ? v : 0.01f * v; }
        if (MODE == 2) Ch[(long)crow * HID + col] = f2b(v);
        else           C[(long)crow * HID + col] = v;
      }
    }
  }
}

// ---------------- CSR build ---------------------------------------------------
__global__ __launch_bounds__(256) void count_kernel(const int* __restrict__ ei,
    const int* __restrict__ flag, int* __restrict__ deg) {
  const int e = blockIdx.x * 256 + threadIdx.x;
  if (e >= E_TOT) return;
  const int wide = *flag;
  const int d = (e < E_RAW_N) ? edge_dst(ei, wide, e) : (e - E_RAW_N);
  atomicAdd(&deg[d], 1);
}

#define SCAN_CHUNK 49  // 1024*49 = 50176 >= 50000
__global__ __launch_bounds__(1024) void scan_kernel(const int* __restrict__ deg, int* __restrict__ off) {
  __shared__ int wtot[16];
  const int t = threadIdx.x;
  const int lane = t & 63, wid = t >> 6;
  const int base = t * SCAN_CHUNK;
  int local[SCAN_CHUNK];
  int sum = 0;
  #pragma unroll
  for (int i = 0; i < SCAN_CHUNK; ++i) {
    const int idx = base + i;
    const int v = (idx < N_NODES) ? deg[idx] : 0;
    local[i] = sum;
    sum += v;
  }
  int inc = sum;
  #pragma unroll
  for (int o = 1; o < 64; o <<= 1) {
    const int y = __shfl_up(inc, o, 64);
    if (lane >= o) inc += y;
  }
  if (lane == 63) wtot[wid] = inc;
  __syncthreads();
  if (wid == 0 && lane < 16) {
    const int v = wtot[lane];
    int inc2 = v;
    #pragma unroll
    for (int o = 1; o < 16; o <<= 1) {
      const int y = __shfl_up(inc2, o, 64);
      if (lane >= o) inc2 += y;
    }
    wtot[lane] = inc2 - v;  // exclusive
  }
  __syncthreads();
  const int pre = wtot[wid] + (inc - sum);
  #pragma unroll
  for (int i = 0; i < SCAN_CHUNK; ++i) {
    const int idx = base + i;
    if (idx < N_NODES) off[idx] = pre + local[i];
  }
  if (t == 1023) off[N_NODES] = E_TOT;
}

__global__ __launch_bounds__(256) void fill_kernel(const int* __restrict__ ei,
    const int* __restrict__ flag, const int* __restrict__ off,
    int* __restrict__ fillc, int* __restrict__ csr_src, int* __restrict__ csr_eid) {
  const int e = blockIdx.x * 256 + threadIdx.x;
  if (e >= E_TOT) return;
  const int wide = *flag;
  int s, d;
  if (e < E_RAW_N) { s = edge_src(ei, wide, e); d = edge_dst(ei, wide, e); }
  else { s = e - E_RAW_N; d = s; }
  const int p = off[d] + atomicAdd(&fillc[d], 1);
  csr_src[p] = s;
  csr_eid[p] = e;
}

// ---------------- fused per-node segment-softmax + aggregation ---------------
template<int DO_LN>
__global__ __launch_bounds__(256) void node_kernel(
    const int* __restrict__ off_, const int* __restrict__ csr_src, const int* __restrict__ csr_eid,
    const unsigned short* __restrict__ xlh,
    const float* __restrict__ a_s, const float* __restrict__ a_d,
    float* __restrict__ alpha_out,
    const float* __restrict__ bias,
    const float* __restrict__ gamma_, const float* __restrict__ beta_,
    float* __restrict__ hout)
{
  const int w = threadIdx.x >> 6;
  const int l = threadIdx.x & 63;
  const int n = blockIdx.x * 4 + w;
  if (n >= N_NODES) return;
  const int off = off_[n];
  const int deg = off_[n + 1] - off;

  const float ad0 = a_d[n*5+0], ad1 = a_d[n*5+1], ad2 = a_d[n*5+2], ad3 = a_d[n*5+3], ad4 = a_d[n*5+4];
  const int hA = l >> 4;  // head for cols 2l, 2l+1
  float accx = 0.f, accy = 0.f, accz = 0.f;

  if (deg <= 64) {
    // ---- fast path: one lane per edge ----
    int src = 0, eid = 0;
    float v0 = -1e30f, v1 = -1e30f, v2 = -1e30f, v3 = -1e30f, v4 = -1e30f;
    if (l < deg) {
      src = csr_src[off + l];
      eid = csr_eid[off + l];
      const float* ap = a_s + src * 5;
      v0 = lrelu2(ap[0] + ad0);
      v1 = lrelu2(ap[1] + ad1);
      v2 = lrelu2(ap[2] + ad2);
      v3 = lrelu2(ap[3] + ad3);
      v4 = lrelu2(ap[4] + ad4);
    }
    const float m0 = wmax(v0), m1 = wmax(v1), m2 = wmax(v2), m3 = wmax(v3), m4 = wmax(v4);
    float e0 = 0.f, e1 = 0.f, e2 = 0.f, e3 = 0.f, e4 = 0.f;
    if (l < deg) {
      e0 = __expf(v0 - m0); e1 = __expf(v1 - m1); e2 = __expf(v2 - m2);
      e3 = __expf(v3 - m3); e4 = __expf(v4 - m4);
    }
    const float i0 = 1.f / (wsum(e0) + 1e-16f), i1 = 1.f / (wsum(e1) + 1e-16f),
                i2 = 1.f / (wsum(e2) + 1e-16f), i3 = 1.f / (wsum(e3) + 1e-16f),
                i4 = 1.f / (wsum(e4) + 1e-16f);
    const float a0 = e0 * i0, a1 = e1 * i1, a2 = e2 * i2, a3 = e3 * i3, a4 = e4 * i4;
    if (l < deg) {
      float* aw = alpha_out + (long)eid * 5;
      aw[0] = a0; aw[1] = a1; aw[2] = a2; aw[3] = a3; aw[4] = a4;
    }
    #pragma unroll 2
    for (int s = 0; s < deg; ++s) {
      const int srcs = __shfl(src, s, 64);
      const float b0 = __shfl(a0, s, 64), b1 = __shfl(a1, s, 64),
                  b2_ = __shfl(a2, s, 64), b3 = __shfl(a3, s, 64), b4 = __shfl(a4, s, 64);
      const float aA = hA == 0 ? b0 : hA == 1 ? b1 : hA == 2 ? b2_ : b3;
      const long xb = (long)srcs * HID;
      const ushort2 u2 = *(const ushort2*)(xlh + xb + 2 * l);
      accx += b2f(u2.x) * aA;
      accy += b2f(u2.y) * aA;
      if (l < 32) accz += b2f(xlh[xb + 128 + l]) * b4;
    }
  } else {
    // ---- slow path (rare): 3-pass over segment ----
    float m0 = -1e30f, m1 = -1e30f, m2 = -1e30f, m3 = -1e30f, m4 = -1e30f;
    for (int s = l; s < deg; s += 64) {
      const float* ap = a_s + csr_src[off + s] * 5;
      m0 = fmaxf(m0, lrelu2(ap[0] + ad0));
      m1 = fmaxf(m1, lrelu2(ap[1] + ad1));
      m2 = fmaxf(m2, lrelu2(ap[2] + ad2));
      m3 = fmaxf(m3, lrelu2(ap[3] + ad3));
      m4 = fmaxf(m4, lrelu2(ap[4] + ad4));
    }
    m0 = wmax(m0); m1 = wmax(m1); m2 = wmax(m2); m3 = wmax(m3); m4 = wmax(m4);
    float s0 = 0.f, s1 = 0.f, s2 = 0.f, s3 = 0.f, s4 = 0.f;
    for (int s = l; s < deg; s += 64) {
      const float* ap = a_s + csr_src[off + s] * 5;
      s0 += __expf(lrelu2(ap[0] + ad0) - m0);
      s1 += __expf(lrelu2(ap[1] + ad1) - m1);
      s2 += __expf(lrelu2(ap[2] + ad2) - m2);
      s3 += __expf(lrelu2(ap[3] + ad3) - m3);
      s4 += __expf(lrelu2(ap[4] + ad4) - m4);
    }
    const float i0 = 1.f / (wsum(s0) + 1e-16f), i1 = 1.f / (wsum(s1) + 1e-16f),
                i2 = 1.f / (wsum(s2) + 1e-16f), i3 = 1.f / (wsum(s3) + 1e-16f),
                i4 = 1.f / (wsum(s4) + 1e-16f);
    const float adA = hA == 0 ? ad0 : hA == 1 ? ad1 : hA == 2 ? ad2 : ad3;
    const float mA  = hA == 0 ? m0  : hA == 1 ? m1  : hA == 2 ? m2  : m3;
    const float iA  = hA == 0 ? i0  : hA == 1 ? i1  : hA == 2 ? i2  : i3;
    float adw = 0.f, mw = 0.f, iw = 0.f;
    if (l < 5) {
      adw = l == 0 ? ad0 : l == 1 ? ad1 : l == 2 ? ad2 : l == 3 ? ad3 : ad4;
      mw  = l == 0 ? m0  : l == 1 ? m1  : l == 2 ? m2  : l == 3 ? m3  : m4;
      iw  = l == 0 ? i0  : l == 1 ? i1  : l == 2 ? i2  : l == 3 ? i3  : i4;
    }
    for (int s = 0; s < deg; ++s) {
      const int p = off + s;
      const int srcs = csr_src[p];
      const float* ap = a_s + srcs * 5;
      const float aA = __expf(lrelu2(ap[hA] + adA) - mA) * iA;
      const long xb = (long)srcs * HID;
      const ushort2 u2 = *(const ushort2*)(xlh + xb + 2 * l);
      accx += b2f(u2.x) * aA;
      accy += b2f(u2.y) * aA;
      if (l < 32) {
        const float aC = __expf(lrelu2(ap[4] + ad4) - m4) * i4;
        accz += b2f(xlh[xb + 128 + l]) * aC;
      }
      if (l < 5) {
        alpha_out[(long)csr_eid[p] * 5 + l] = __expf(lrelu2(ap[l] + adw) - mw) * iw;
      }
    }
  }

  // epilogue
  const int c0 = 2 * l, c2 = 128 + l;
  float v0 = accx + bias[c0];     v0 = v0 > 0.f ? v0 : 0.01f * v0;
  float v1 = accy + bias[c0 + 1]; v1 = v1 > 0.f ? v1 : 0.01f * v1;
  float v2 = 0.f;
  if (l < 32) { v2 = accz + bias[c2]; v2 = v2 > 0.f ? v2 : 0.01f * v2; }

  const long hb = (long)n * HID;
  if (DO_LN) {
    const float tot = wsum(v0 + v1 + v2);
    const float mean = tot * (1.f / 160.f);
    const float d0 = v0 - mean, d1 = v1 - mean;
    float sq = d0 * d0 + d1 * d1;
    float d2 = 0.f;
    if (l < 32) { d2 = v2 - mean; sq += d2 * d2; }
    const float var = wsum(sq) * (1.f / 160.f);
    const float rstd = rsqrtf(var + 1e-5f);
    hout[hb + c0]     = d0 * rstd * gamma_[c0]     + beta_[c0];
    hout[hb + c0 + 1] = d1 * rstd * gamma_[c0 + 1] + beta_[c0 + 1];
    if (l < 32) hout[hb + c2] = d2 * rstd * gamma_[c2] + beta_[c2];
  } else {
    hout[hb + c0]     = v0;
    hout[hb + c0 + 1] = v1;
    if (l < 32) hout[hb + c2] = v2;
  }
}

extern "C" void kernel_launch(void* const* d_in, const int* in_sizes, int n_in,
                              void* d_out, int out_size, void* d_ws, size_t ws_size,
                              hipStream_t stream)
{
  const float* x     = (const float*)d_in[0];
  const int*   ei    = (const int*)d_in[1];
  const float* W1    = (const float*)d_in[2];
  const float* att1s = (const float*)d_in[3];
  const float* att1d = (const float*)d_in[4];
  const float* b1    = (const float*)d_in[5];
  const float* g1    = (const float*)d_in[6];
  const float* be1   = (const float*)d_in[7];
  const float* W2    = (const float*)d_in[8];
  const float* att2s = (const float*)d_in[9];
  const float* att2d = (const float*)d_in[10];
  const float* b2    = (const float*)d_in[11];
  const float* Wm    = (const float*)d_in[12];
  const float* bm    = (const float*)d_in[13];

  float* out    = (float*)d_out;                      // [N,160]
  float* alpha1 = out + (long)N_NODES * HID;          // [E,5]
  float* alpha2 = alpha1 + (long)E_TOT * 5;           // [E,5]

  char* p = (char*)d_ws;
  auto alloc = [&](size_t bytes) { void* r = (void*)p; p += (bytes + 255) & ~(size_t)255; return r; };
  float* hbuf = (float*)alloc((size_t)N_NODES * HID * 4);
  unsigned short* xlh = (unsigned short*)alloc((size_t)N_NODES * HID * 2);
  float* as_  = (float*)alloc((size_t)N_NODES * 5 * 4);
  float* ad_  = (float*)alloc((size_t)N_NODES * 5 * 4);
  int* deg    = (int*)alloc((size_t)N_NODES * 4);
  int* fillc  = (int*)alloc((size_t)N_NODES * 4);
  int* off    = (int*)alloc((size_t)(N_NODES + 1) * 4);
  int* csrS   = (int*)alloc((size_t)E_TOT * 4);
  int* csrE   = (int*)alloc((size_t)E_TOT * 4);
  int* flag   = (int*)alloc(256);
  unsigned short* Bt1 = (unsigned short*)alloc((size_t)2 * HID * 512 * 2);
  unsigned short* Bt2 = (unsigned short*)alloc((size_t)2 * HID * 160 * 2);
  unsigned short* Btm = (unsigned short*)alloc((size_t)2 * HID * 160 * 2);

  hipMemsetAsync(deg, 0, (size_t)N_NODES * 4, stream);
  hipMemsetAsync(fillc, 0, (size_t)N_NODES * 4, stream);

  detect_kernel<<<1, 64, 0, stream>>>(ei, flag);
  const int EB = (E_TOT + 255) / 256;
  count_kernel<<<EB, 256, 0, stream>>>(ei, flag, deg);
  scan_kernel<<<1, 1024, 0, stream>>>(deg, off);
  fill_kernel<<<EB, 256, 0, stream>>>(ei, flag, off, fillc, csrS, csrE);

  convert_B<<<(HID * 512 + 255) / 256, 256, 0, stream>>>(W1, Bt1, F_IN_K, 512);
  convert_B<<<(HID * 160 + 255) / 256, 256, 0, stream>>>(W2, Bt2, HID, 160);
  convert_B<<<(HID * 160 + 255) / 256, 256, 0, stream>>>(Wm, Btm, HID, 160);

  const int GB = (N_NODES + 63) / 64;

  // layer 1: split-bf16 LDS-GEMM + fused attention dots -> xlh, a_s, a_d
  gemm_lds<F_IN_K, 512, 64, 2, 1><<<GB, 256, 0, stream>>>(x, Bt1, nullptr, xlh, nullptr, att1s, att1d, as_, ad_);
  node_kernel<1><<<N_NODES / 4, 256, 0, stream>>>(off, csrS, csrE, xlh, as_, ad_, alpha1, b1, g1, be1, hbuf);

  // layer 2
  gemm_lds<HID, 160, 160, 2, 0><<<GB, 256, 0, stream>>>(hbuf, Bt2, nullptr, xlh, nullptr, att2s, att2d, as_, ad_);
  node_kernel<0><<<N_NODES / 4, 256, 0, stream>>>(off, csrS, csrE, xlh, as_, ad_, alpha2, b2, nullptr, nullptr, hbuf);

  // final MLP: out = leaky(h2 @ Wm + bm)
  gemm_lds<HID, 160, 160, 1, 0><<<GB, 256, 0, stream>>>(hbuf, Btm, out, nullptr, bm, nullptr, nullptr, nullptr, nullptr);
}

// Round 9
// 467.603 us; speedup vs baseline: 2.1510x; 1.0819x over previous
//
#include <hip/hip_runtime.h>

#define N_NODES 50000
#define E_RAW_N 800000
#define E_TOT   850000
#define F_IN_K  500
#define HID     160

using short8 = __attribute__((ext_vector_type(8))) short;
using f32x4  = __attribute__((ext_vector_type(4))) float;

__device__ __forceinline__ float b2f(unsigned short u) {
  union { unsigned int i; float f; } v; v.i = ((unsigned int)u) << 16; return v.f;
}
__device__ __forceinline__ unsigned short f2b(float f) {
  union { float f; unsigned int i; } v; v.f = f;
  unsigned int i = v.i;
  unsigned int lsb = (i >> 16) & 1u;
  i += 0x7fffu + lsb;
  return (unsigned short)(i >> 16);
}

__device__ __forceinline__ float wsum(float x) {
  #pragma unroll
  for (int o = 32; o; o >>= 1) x += __shfl_xor(x, o, 64);
  return x;
}
__device__ __forceinline__ float wmax(float x) {
  #pragma unroll
  for (int o = 32; o; o >>= 1) x = fmaxf(x, __shfl_xor(x, o, 64));
  return x;
}
__device__ __forceinline__ float lrelu2(float x) { return x > 0.f ? x : 0.2f * x; }

// ---------------- edge dtype detection (int64 vs int32 hedge) ----------------
__global__ void detect_kernel(const int* __restrict__ ei, int* __restrict__ flag) {
  if (threadIdx.x == 0 && blockIdx.x == 0) {
    int allz = 1;
    for (int i = 1; i < 128; i += 2) if (ei[i] != 0) { allz = 0; break; }
    *flag = allz;  // 1 => int64 layout
  }
}
__device__ __forceinline__ int edge_src(const int* ei, int wide, int e) {
  return wide ? ei[2 * e] : ei[e];
}
__device__ __forceinline__ int edge_dst(const int* ei, int wide, int e) {
  return wide ? ei[2 * (E_RAW_N + e)] : ei[E_RAW_N + e];
}

// ------- weight pre-convert: B[K][160] f32 -> Bt hi/lo planes [160][KPAD] ----
__global__ __launch_bounds__(256) void convert_B(const float* __restrict__ B,
                                                 unsigned short* __restrict__ Bt,
                                                 int K, int KPAD) {
  const int i = blockIdx.x * 256 + threadIdx.x;
  if (i >= HID * KPAD) return;
  const int c = i / KPAD, k = i % KPAD;
  const float b = (k < K) ? B[(long)k * HID + c] : 0.f;
  const unsigned short hi = f2b(b);
  Bt[i] = hi;
  Bt[HID * KPAD + i] = f2b(b - b2f(hi));
}

// ---------------- GEMM: [M,160] = A[M,K] @ B, LDS-staged B, pipelined --------
// block = 4 waves; wave = 16 rows x 160 cols (10 col-tiles, 16x16x32 MFMA).
// CHUNKS>1: register-prefetched B chunk (T14 async-stage) — loads for chunk
// cc+1 issued right after barrier(b), in flight under compute(cc); the
// vmcnt-drain at barrier(a) is then benign.
// SPLIT=1: 3-MFMA split-bf16 (~f32 accuracy).
// MODE 0: C f32. MODE 1: +bias, leaky(0.01), C f32.
// MODE 2: bf16 -> Ch + fused attention dots -> a_s, a_d.
template<int K, int KPAD, int BK, int MODE, int SPLIT>
__global__ __launch_bounds__(256) void gemm_lds(
    const float* __restrict__ A, const unsigned short* __restrict__ Bt,
    float* __restrict__ C, unsigned short* __restrict__ Ch,
    const float* __restrict__ bias,
    const float* __restrict__ att_s, const float* __restrict__ att_d,
    float* __restrict__ a_s, float* __restrict__ a_d)
{
  constexpr int NP = SPLIT ? 2 : 1;
  constexpr int LSTR = BK + 8;          // padded stride (elems), 16B aligned
  constexpr int CHUNKS = KPAD / BK;
  constexpr int KSC = BK / 32;          // K-steps per chunk
  constexpr int ROWU = BK / 8;          // 16B units per row
  constexpr int UNITS = NP * HID * ROWU;
  __shared__ __align__(16) unsigned short Bs[NP][HID][LSTR];

  const int t = threadIdx.x;
  const int l = t & 63;
  const int w = t >> 6;
  const int m = l & 15;
  const int kgrp = (l >> 4) * 8;
  const int rbase = blockIdx.x * 64 + w * 16;
  const int arow = (rbase + m < N_NODES) ? rbase + m : N_NODES - 1;
  const float* Arow = A + (long)arow * K;

  f32x4 acc[10];
  #pragma unroll
  for (int i = 0; i < 10; ++i) acc[i] = (f32x4){0.f, 0.f, 0.f, 0.f};

  if constexpr (CHUNKS == 1) {
    // ---- single chunk: stage once, then compute over full K ----
    float ar[KSC][8];
    #pragma unroll
    for (int ks = 0; ks < KSC; ++ks) {
      const int kb = ks * 32 + kgrp;
      if (kb + 8 <= K) {
        const float4 a0 = *(const float4*)(Arow + kb);
        const float4 a1 = *(const float4*)(Arow + kb + 4);
        ar[ks][0]=a0.x; ar[ks][1]=a0.y; ar[ks][2]=a0.z; ar[ks][3]=a0.w;
        ar[ks][4]=a1.x; ar[ks][5]=a1.y; ar[ks][6]=a1.z; ar[ks][7]=a1.w;
      } else {
        #pragma unroll
        for (int j = 0; j < 8; ++j) ar[ks][j] = (kb + j < K) ? Arow[kb + j] : 0.f;
      }
    }
    for (int u = t; u < UNITS; u += 256) {
      const int p = u / (HID * ROWU);
      const int rem = u % (HID * ROWU);
      const int c = rem / ROWU;
      const int k8 = rem % ROWU;
      const short8 v = *(const short8*)(Bt + (long)p * HID * KPAD + (long)c * KPAD + k8 * 8);
      *(short8*)&Bs[p][c][k8 * 8] = v;
    }
    __syncthreads();
    #pragma unroll
    for (int ks = 0; ks < KSC; ++ks) {
      short8 ah, al;
      #pragma unroll
      for (int j = 0; j < 8; ++j) {
        const unsigned short h = f2b(ar[ks][j]);
        ah[j] = (short)h;
        if (SPLIT) al[j] = (short)f2b(ar[ks][j] - b2f(h));
      }
      #pragma unroll
      for (int ct = 0; ct < 10; ++ct) {
        const short8 bh = *(const short8*)&Bs[0][ct * 16 + m][ks * 32 + kgrp];
        acc[ct] = __builtin_amdgcn_mfma_f32_16x16x32_bf16(ah, bh, acc[ct], 0, 0, 0);
        if (SPLIT) {
          const short8 bl = *(const short8*)&Bs[SPLIT][ct * 16 + m][ks * 32 + kgrp];
          acc[ct] = __builtin_amdgcn_mfma_f32_16x16x32_bf16(ah, bl, acc[ct], 0, 0, 0);
          acc[ct] = __builtin_amdgcn_mfma_f32_16x16x32_bf16(al, bh, acc[ct], 0, 0, 0);
        }
      }
    }
  } else {
    // ---- pipelined chunks: reg-prefetch B + A one chunk ahead ----
    static_assert(UNITS % 256 == 0, "units must tile threads");
    constexpr int UPT = UNITS / 256;
    short8 rb[UPT];
    float ar[KSC][8];

    // prologue: load chunk 0 into registers
    #pragma unroll
    for (int i = 0; i < UPT; ++i) {
      const int u = i * 256 + t;
      const int p = u / (HID * ROWU);
      const int rem = u % (HID * ROWU);
      const int c = rem / ROWU;
      const int k8 = rem % ROWU;
      rb[i] = *(const short8*)(Bt + (long)p * HID * KPAD + (long)c * KPAD + k8 * 8);
    }
    #pragma unroll
    for (int ks = 0; ks < KSC; ++ks) {
      const int kb = ks * 32 + kgrp;
      const float4 a0 = *(const float4*)(Arow + kb);
      const float4 a1 = *(const float4*)(Arow + kb + 4);
      ar[ks][0]=a0.x; ar[ks][1]=a0.y; ar[ks][2]=a0.z; ar[ks][3]=a0.w;
      ar[ks][4]=a1.x; ar[ks][5]=a1.y; ar[ks][6]=a1.z; ar[ks][7]=a1.w;
    }

    for (int cc = 0; cc < CHUNKS; ++cc) {
      __syncthreads();   // (a) prev chunk's reads done; prefetch already complete
      #pragma unroll
      for (int i = 0; i < UPT; ++i) {
        const int u = i * 256 + t;
        const int p = u / (HID * ROWU);
        const int rem = u % (HID * ROWU);
        const int c = rem / ROWU;
        const int k8 = rem % ROWU;
        *(short8*)&Bs[p][c][k8 * 8] = rb[i];
      }
      __syncthreads();   // (b) writes visible
      // issue next chunk's loads NOW — they fly under compute(cc)
      short8 rb2[UPT];
      float ar2[KSC][8];
      if (cc + 1 < CHUNKS) {
        #pragma unroll
        for (int i = 0; i < UPT; ++i) {
          const int u = i * 256 + t;
          const int p = u / (HID * ROWU);
          const int rem = u % (HID * ROWU);
          const int c = rem / ROWU;
          const int k8 = rem % ROWU;
          rb2[i] = *(const short8*)(Bt + (long)p * HID * KPAD + (long)c * KPAD + (cc + 1) * BK + k8 * 8);
        }
        #pragma unroll
        for (int ks = 0; ks < KSC; ++ks) {
          const int kb = (cc + 1) * BK + ks * 32 + kgrp;
          if (kb + 8 <= K) {
            const float4 a0 = *(const float4*)(Arow + kb);
            const float4 a1 = *(const float4*)(Arow + kb + 4);
            ar2[ks][0]=a0.x; ar2[ks][1]=a0.y; ar2[ks][2]=a0.z; ar2[ks][3]=a0.w;
            ar2[ks][4]=a1.x; ar2[ks][5]=a1.y; ar2[ks][6]=a1.z; ar2[ks][7]=a1.w;
          } else {
            #pragma unroll
            for (int j = 0; j < 8; ++j) ar2[ks][j] = (kb + j < K) ? Arow[kb + j] : 0.f;
          }
        }
        __builtin_amdgcn_sched_barrier(0);  // pin load issue before MFMA cluster
      }
      // compute chunk cc
      #pragma unroll
      for (int ks = 0; ks < KSC; ++ks) {
        short8 ah, al;
        #pragma unroll
        for (int j = 0; j < 8; ++j) {
          const unsigned short h = f2b(ar[ks][j]);
          ah[j] = (short)h;
          if (SPLIT) al[j] = (short)f2b(ar[ks][j] - b2f(h));
        }
        #pragma unroll
        for (int ct = 0; ct < 10; ++ct) {
          const short8 bh = *(const short8*)&Bs[0][ct * 16 + m][ks * 32 + kgrp];
          acc[ct] = __builtin_amdgcn_mfma_f32_16x16x32_bf16(ah, bh, acc[ct], 0, 0, 0);
          if (SPLIT) {
            const short8 bl = *(const short8*)&Bs[SPLIT][ct * 16 + m][ks * 32 + kgrp];
            acc[ct] = __builtin_amdgcn_mfma_f32_16x16x32_bf16(ah, bl, acc[ct], 0, 0, 0);
            acc[ct] = __builtin_amdgcn_mfma_f32_16x16x32_bf16(al, bh, acc[ct], 0, 0, 0);
          }
        }
      }
      if (cc + 1 < CHUNKS) {
        #pragma unroll
        for (int i = 0; i < UPT; ++i) rb[i] = rb2[i];
        #pragma unroll
        for (int ks = 0; ks < KSC; ++ks)
          #pragma unroll
          for (int j = 0; j < 8; ++j) ar[ks][j] = ar2[ks][j];
      }
    }
  }

  const int crow0 = rbase + (l >> 4) * 4;

  if (MODE == 2) {
    // fused attention dots: a_s[n,h] = sum_c xl[n,c] * att_s[h*32+c]
    #pragma unroll
    for (int r = 0; r < 4; ++r) {
      float ps[5], pd[5];
      #pragma unroll
      for (int h = 0; h < 5; ++h) {
        float s = acc[2*h][r]     * att_s[(2*h) * 16 + m]
                + acc[2*h + 1][r] * att_s[(2*h + 1) * 16 + m];
        float d = acc[2*h][r]     * att_d[(2*h) * 16 + m]
                + acc[2*h + 1][r] * att_d[(2*h + 1) * 16 + m];
        #pragma unroll
        for (int o = 1; o < 16; o <<= 1) {
          s += __shfl_xor(s, o, 64);
          d += __shfl_xor(d, o, 64);
        }
        ps[h] = s; pd[h] = d;
      }
      const int crow = crow0 + r;
      if (crow < N_NODES && m < 5) {
        const float vs = m == 0 ? ps[0] : m == 1 ? ps[1] : m == 2 ? ps[2] : m == 3 ? ps[3] : ps[4];
        const float vd = m == 0 ? pd[0] : m == 1 ? pd[1] : m == 2 ? pd[2] : m == 3 ? pd[3] : pd[4];
        a_s[crow * 5 + m] = vs;
        a_d[crow * 5 + m] = vd;
      }
    }
  }

  #pragma unroll
  for (int r = 0; r < 4; ++r) {
    const int crow = crow0 + r;
    if (crow < N_NODES) {
      #pragma unroll
      for (int ct = 0; ct < 10; ++ct) {
        const int col = ct * 16 + m;
        float v = acc[ct][r];
        if (MODE == 1) { v += bias[col]; v = v > 0.f ? v : 0.01f * v; }
        if (MODE == 2) Ch[(long)crow * HID + col] = f2b(v);
        else           C[(long)crow * HID + col] = v;
      }
    }
  }
}

// ---------------- CSR build ---------------------------------------------------
__global__ __launch_bounds__(256) void count_kernel(const int* __restrict__ ei,
    const int* __restrict__ flag, int* __restrict__ deg) {
  const int e = blockIdx.x * 256 + threadIdx.x;
  if (e >= E_TOT) return;
  const int wide = *flag;
  const int d = (e < E_RAW_N) ? edge_dst(ei, wide, e) : (e - E_RAW_N);
  atomicAdd(&deg[d], 1);
}

#define SCAN_CHUNK 49  // 1024*49 = 50176 >= 50000
__global__ __launch_bounds__(1024) void scan_kernel(const int* __restrict__ deg, int* __restrict__ off) {
  __shared__ int wtot[16];
  const int t = threadIdx.x;
  const int lane = t & 63, wid = t >> 6;
  const int base = t * SCAN_CHUNK;
  int local[SCAN_CHUNK];
  int sum = 0;
  #pragma unroll
  for (int i = 0; i < SCAN_CHUNK; ++i) {
    const int idx = base + i;
    const int v = (idx < N_NODES) ? deg[idx] : 0;
    local[i] = sum;
    sum += v;
  }
  int inc = sum;
  #pragma unroll
  for (int o = 1; o < 64; o <<= 1) {
    const int y = __shfl_up(inc, o, 64);
    if (lane >= o) inc += y;
  }
  if (lane == 63) wtot[wid] = inc;
  __syncthreads();
  if (wid == 0 && lane < 16) {
    const int v = wtot[lane];
    int inc2 = v;
    #pragma unroll
    for (int o = 1; o < 16; o <<= 1) {
      const int y = __shfl_up(inc2, o, 64);
      if (lane >= o) inc2 += y;
    }
    wtot[lane] = inc2 - v;  // exclusive
  }
  __syncthreads();
  const int pre = wtot[wid] + (inc - sum);
  #pragma unroll
  for (int i = 0; i < SCAN_CHUNK; ++i) {
    const int idx = base + i;
    if (idx < N_NODES) off[idx] = pre + local[i];
  }
  if (t == 1023) off[N_NODES] = E_TOT;
}

__global__ __launch_bounds__(256) void fill_kernel(const int* __restrict__ ei,
    const int* __restrict__ flag, const int* __restrict__ off,
    int* __restrict__ fillc, int* __restrict__ csr_src, int* __restrict__ csr_eid) {
  const int e = blockIdx.x * 256 + threadIdx.x;
  if (e >= E_TOT) return;
  const int wide = *flag;
  int s, d;
  if (e < E_RAW_N) { s = edge_src(ei, wide, e); d = edge_dst(ei, wide, e); }
  else { s = e - E_RAW_N; d = s; }
  const int p = off[d] + atomicAdd(&fillc[d], 1);
  csr_src[p] = s;
  csr_eid[p] = e;
}

// ---------------- fused per-node segment-softmax + aggregation ---------------
template<int DO_LN>
__global__ __launch_bounds__(256) void node_kernel(
    const int* __restrict__ off_, const int* __restrict__ csr_src, const int* __restrict__ csr_eid,
    const unsigned short* __restrict__ xlh,
    const float* __restrict__ a_s, const float* __restrict__ a_d,
    float* __restrict__ alpha_out,
    const float* __restrict__ bias,
    const float* __restrict__ gamma_, const float* __restrict__ beta_,
    float* __restrict__ hout)
{
  const int w = threadIdx.x >> 6;
  const int l = threadIdx.x & 63;
  const int n = blockIdx.x * 4 + w;
  if (n >= N_NODES) return;
  const int off = off_[n];
  const int deg = off_[n + 1] - off;

  const float ad0 = a_d[n*5+0], ad1 = a_d[n*5+1], ad2 = a_d[n*5+2], ad3 = a_d[n*5+3], ad4 = a_d[n*5+4];
  const int hA = l >> 4;  // head for cols 2l, 2l+1
  float accx = 0.f, accy = 0.f, accz = 0.f;

  if (deg <= 64) {
    // ---- fast path: one lane per edge ----
    int src = 0, eid = 0;
    float v0 = -1e30f, v1 = -1e30f, v2 = -1e30f, v3 = -1e30f, v4 = -1e30f;
    if (l < deg) {
      src = csr_src[off + l];
      eid = csr_eid[off + l];
      const float* ap = a_s + src * 5;
      v0 = lrelu2(ap[0] + ad0);
      v1 = lrelu2(ap[1] + ad1);
      v2 = lrelu2(ap[2] + ad2);
      v3 = lrelu2(ap[3] + ad3);
      v4 = lrelu2(ap[4] + ad4);
    }
    const float m0 = wmax(v0), m1 = wmax(v1), m2 = wmax(v2), m3 = wmax(v3), m4 = wmax(v4);
    float e0 = 0.f, e1 = 0.f, e2 = 0.f, e3 = 0.f, e4 = 0.f;
    if (l < deg) {
      e0 = __expf(v0 - m0); e1 = __expf(v1 - m1); e2 = __expf(v2 - m2);
      e3 = __expf(v3 - m3); e4 = __expf(v4 - m4);
    }
    const float i0 = 1.f / (wsum(e0) + 1e-16f), i1 = 1.f / (wsum(e1) + 1e-16f),
                i2 = 1.f / (wsum(e2) + 1e-16f), i3 = 1.f / (wsum(e3) + 1e-16f),
                i4 = 1.f / (wsum(e4) + 1e-16f);
    const float a0 = e0 * i0, a1 = e1 * i1, a2 = e2 * i2, a3 = e3 * i3, a4 = e4 * i4;
    if (l < deg) {
      float* aw = alpha_out + (long)eid * 5;
      aw[0] = a0; aw[1] = a1; aw[2] = a2; aw[3] = a3; aw[4] = a4;
    }
    #pragma unroll 2
    for (int s = 0; s < deg; ++s) {
      const int srcs = __shfl(src, s, 64);
      const float b0 = __shfl(a0, s, 64), b1 = __shfl(a1, s, 64),
                  b2_ = __shfl(a2, s, 64), b3 = __shfl(a3, s, 64), b4 = __shfl(a4, s, 64);
      const float aA = hA == 0 ? b0 : hA == 1 ? b1 : hA == 2 ? b2_ : b3;
      const long xb = (long)srcs * HID;
      const ushort2 u2 = *(const ushort2*)(xlh + xb + 2 * l);
      accx += b2f(u2.x) * aA;
      accy += b2f(u2.y) * aA;
      if (l < 32) accz += b2f(xlh[xb + 128 + l]) * b4;
    }
  } else {
    // ---- slow path (rare): 3-pass over segment ----
    float m0 = -1e30f, m1 = -1e30f, m2 = -1e30f, m3 = -1e30f, m4 = -1e30f;
    for (int s = l; s < deg; s += 64) {
      const float* ap = a_s + csr_src[off + s] * 5;
      m0 = fmaxf(m0, lrelu2(ap[0] + ad0));
      m1 = fmaxf(m1, lrelu2(ap[1] + ad1));
      m2 = fmaxf(m2, lrelu2(ap[2] + ad2));
      m3 = fmaxf(m3, lrelu2(ap[3] + ad3));
      m4 = fmaxf(m4, lrelu2(ap[4] + ad4));
    }
    m0 = wmax(m0); m1 = wmax(m1); m2 = wmax(m2); m3 = wmax(m3); m4 = wmax(m4);
    float s0 = 0.f, s1 = 0.f, s2 = 0.f, s3 = 0.f, s4 = 0.f;
    for (int s = l; s < deg; s += 64) {
      const float* ap = a_s + csr_src[off + s] * 5;
      s0 += __expf(lrelu2(ap[0] + ad0) - m0);
      s1 += __expf(lrelu2(ap[1] + ad1) - m1);
      s2 += __expf(lrelu2(ap[2] + ad2) - m2);
      s3 += __expf(lrelu2(ap[3] + ad3) - m3);
      s4 += __expf(lrelu2(ap[4] + ad4) - m4);
    }
    const float i0 = 1.f / (wsum(s0) + 1e-16f), i1 = 1.f / (wsum(s1) + 1e-16f),
                i2 = 1.f / (wsum(s2) + 1e-16f), i3 = 1.f / (wsum(s3) + 1e-16f),
                i4 = 1.f / (wsum(s4) + 1e-16f);
    const float adA = hA == 0 ? ad0 : hA == 1 ? ad1 : hA == 2 ? ad2 : ad3;
    const float mA  = hA == 0 ? m0  : hA == 1 ? m1  : hA == 2 ? m2  : m3;
    const float iA  = hA == 0 ? i0  : hA == 1 ? i1  : hA == 2 ? i2  : i3;
    float adw = 0.f, mw = 0.f, iw = 0.f;
    if (l < 5) {
      adw = l == 0 ? ad0 : l == 1 ? ad1 : l == 2 ? ad2 : l == 3 ? ad3 : ad4;
      mw  = l == 0 ? m0  : l == 1 ? m1  : l == 2 ? m2  : l == 3 ? m3  : m4;
      iw  = l == 0 ? i0  : l == 1 ? i1  : l == 2 ? i2  : l == 3 ? i3  : i4;
    }
    for (int s = 0; s < deg; ++s) {
      const int p = off + s;
      const int srcs = csr_src[p];
      const float* ap = a_s + srcs * 5;
      const float aA = __expf(lrelu2(ap[hA] + adA) - mA) * iA;
      const long xb = (long)srcs * HID;
      const ushort2 u2 = *(const ushort2*)(xlh + xb + 2 * l);
      accx += b2f(u2.x) * aA;
      accy += b2f(u2.y) * aA;
      if (l < 32) {
        const float aC = __expf(lrelu2(ap[4] + ad4) - m4) * i4;
        accz += b2f(xlh[xb + 128 + l]) * aC;
      }
      if (l < 5) {
        alpha_out[(long)csr_eid[p] * 5 + l] = __expf(lrelu2(ap[l] + adw) - mw) * iw;
      }
    }
  }

  // epilogue
  const int c0 = 2 * l, c2 = 128 + l;
  float v0 = accx + bias[c0];     v0 = v0 > 0.f ? v0 : 0.01f * v0;
  float v1 = accy + bias[c0 + 1]; v1 = v1 > 0.f ? v1 : 0.01f * v1;
  float v2 = 0.f;
  if (l < 32) { v2 = accz + bias[c2]; v2 = v2 > 0.f ? v2 : 0.01f * v2; }

  const long hb = (long)n * HID;
  if (DO_LN) {
    const float tot = wsum(v0 + v1 + v2);
    const float mean = tot * (1.f / 160.f);
    const float d0 = v0 - mean, d1 = v1 - mean;
    float sq = d0 * d0 + d1 * d1;
    float d2 = 0.f;
    if (l < 32) { d2 = v2 - mean; sq += d2 * d2; }
    const float var = wsum(sq) * (1.f / 160.f);
    const float rstd = rsqrtf(var + 1e-5f);
    hout[hb + c0]     = d0 * rstd * gamma_[c0]     + beta_[c0];
    hout[hb + c0 + 1] = d1 * rstd * gamma_[c0 + 1] + beta_[c0 + 1];
    if (l < 32) hout[hb + c2] = d2 * rstd * gamma_[c2] + beta_[c2];
  } else {
    hout[hb + c0]     = v0;
    hout[hb + c0 + 1] = v1;
    if (l < 32) hout[hb + c2] = v2;
  }
}

extern "C" void kernel_launch(void* const* d_in, const int* in_sizes, int n_in,
                              void* d_out, int out_size, void* d_ws, size_t ws_size,
                              hipStream_t stream)
{
  const float* x     = (const float*)d_in[0];
  const int*   ei    = (const int*)d_in[1];
  const float* W1    = (const float*)d_in[2];
  const float* att1s = (const float*)d_in[3];
  const float* att1d = (const float*)d_in[4];
  const float* b1    = (const float*)d_in[5];
  const float* g1    = (const float*)d_in[6];
  const float* be1   = (const float*)d_in[7];
  const float* W2    = (const float*)d_in[8];
  const float* att2s = (const float*)d_in[9];
  const float* att2d = (const float*)d_in[10];
  const float* b2    = (const float*)d_in[11];
  const float* Wm    = (const float*)d_in[12];
  const float* bm    = (const float*)d_in[13];

  float* out    = (float*)d_out;                      // [N,160]
  float* alpha1 = out + (long)N_NODES * HID;          // [E,5]
  float* alpha2 = alpha1 + (long)E_TOT * 5;           // [E,5]

  char* p = (char*)d_ws;
  auto alloc = [&](size_t bytes) { void* r = (void*)p; p += (bytes + 255) & ~(size_t)255; return r; };
  float* hbuf = (float*)alloc((size_t)N_NODES * HID * 4);
  unsigned short* xlh = (unsigned short*)alloc((size_t)N_NODES * HID * 2);
  float* as_  = (float*)alloc((size_t)N_NODES * 5 * 4);
  float* ad_  = (float*)alloc((size_t)N_NODES * 5 * 4);
  int* deg    = (int*)alloc((size_t)N_NODES * 4);
  int* fillc  = (int*)alloc((size_t)N_NODES * 4);
  int* off    = (int*)alloc((size_t)(N_NODES + 1) * 4);
  int* csrS   = (int*)alloc((size_t)E_TOT * 4);
  int* csrE   = (int*)alloc((size_t)E_TOT * 4);
  int* flag   = (int*)alloc(256);
  unsigned short* Bt1 = (unsigned short*)alloc((size_t)2 * HID * 512 * 2);
  unsigned short* Bt2 = (unsigned short*)alloc((size_t)2 * HID * 160 * 2);
  unsigned short* Btm = (unsigned short*)alloc((size_t)2 * HID * 160 * 2);

  hipMemsetAsync(deg, 0, (size_t)N_NODES * 4, stream);
  hipMemsetAsync(fillc, 0, (size_t)N_NODES * 4, stream);

  detect_kernel<<<1, 64, 0, stream>>>(ei, flag);
  const int EB = (E_TOT + 255) / 256;
  count_kernel<<<EB, 256, 0, stream>>>(ei, flag, deg);
  scan_kernel<<<1, 1024, 0, stream>>>(deg, off);
  fill_kernel<<<EB, 256, 0, stream>>>(ei, flag, off, fillc, csrS, csrE);

  convert_B<<<(HID * 512 + 255) / 256, 256, 0, stream>>>(W1, Bt1, F_IN_K, 512);
  convert_B<<<(HID * 160 + 255) / 256, 256, 0, stream>>>(W2, Bt2, HID, 160);
  convert_B<<<(HID * 160 + 255) / 256, 256, 0, stream>>>(Wm, Btm, HID, 160);

  const int GB = (N_NODES + 63) / 64;

  // layer 1: split-bf16 pipelined LDS-GEMM + fused attention dots
  gemm_lds<F_IN_K, 512, 64, 2, 1><<<GB, 256, 0, stream>>>(x, Bt1, nullptr, xlh, nullptr, att1s, att1d, as_, ad_);
  node_kernel<1><<<N_NODES / 4, 256, 0, stream>>>(off, csrS, csrE, xlh, as_, ad_, alpha1, b1, g1, be1, hbuf);

  // layer 2
  gemm_lds<HID, 160, 160, 2, 0><<<GB, 256, 0, stream>>>(hbuf, Bt2, nullptr, xlh, nullptr, att2s, att2d, as_, ad_);
  node_kernel<0><<<N_NODES / 4, 256, 0, stream>>>(off, csrS, csrE, xlh, as_, ad_, alpha2, b2, nullptr, nullptr, hbuf);

  // final MLP: out = leaky(h2 @ Wm + bm)
  gemm_lds<HID, 160, 160, 1, 0><<<GB, 256, 0, stream>>>(hbuf, Btm, out, nullptr, bm, nullptr, nullptr, nullptr, nullptr);
}

// Round 10
// 441.369 us; speedup vs baseline: 2.2788x; 1.0594x over previous
//
#include <hip/hip_runtime.h>

#define N_NODES 50000
#define E_RAW_N 800000
#define E_TOT   850000
#define F_IN_K  500
#define HID     160

using short8 = __attribute__((ext_vector_type(8))) short;
using f32x4  = __attribute__((ext_vector_type(4))) float;

__device__ __forceinline__ float b2f(unsigned short u) {
  union { unsigned int i; float f; } v; v.i = ((unsigned int)u) << 16; return v.f;
}
__device__ __forceinline__ unsigned short f2b(float f) {
  union { float f; unsigned int i; } v; v.f = f;
  unsigned int i = v.i;
  unsigned int lsb = (i >> 16) & 1u;
  i += 0x7fffu + lsb;
  return (unsigned short)(i >> 16);
}

__device__ __forceinline__ float wsum(float x) {
  #pragma unroll
  for (int o = 32; o; o >>= 1) x += __shfl_xor(x, o, 64);
  return x;
}
__device__ __forceinline__ float wmax(float x) {
  #pragma unroll
  for (int o = 32; o; o >>= 1) x = fmaxf(x, __shfl_xor(x, o, 64));
  return x;
}
__device__ __forceinline__ float lrelu2(float x) { return x > 0.f ? x : 0.2f * x; }

// ---------------- edge dtype detection (int64 vs int32 hedge) ----------------
__global__ void detect_kernel(const int* __restrict__ ei, int* __restrict__ flag) {
  if (threadIdx.x == 0 && blockIdx.x == 0) {
    int allz = 1;
    for (int i = 1; i < 128; i += 2) if (ei[i] != 0) { allz = 0; break; }
    *flag = allz;  // 1 => int64 layout
  }
}
__device__ __forceinline__ int edge_src(const int* ei, int wide, int e) {
  return wide ? ei[2 * e] : ei[e];
}
__device__ __forceinline__ int edge_dst(const int* ei, int wide, int e) {
  return wide ? ei[2 * (E_RAW_N + e)] : ei[E_RAW_N + e];
}

// ------- weight pre-convert: B[K][160] f32 -> Bt hi/lo planes [160][KPAD] ----
__global__ __launch_bounds__(256) void convert_B(const float* __restrict__ B,
                                                 unsigned short* __restrict__ Bt,
                                                 int K, int KPAD) {
  const int i = blockIdx.x * 256 + threadIdx.x;
  if (i >= HID * KPAD) return;
  const int c = i / KPAD, k = i % KPAD;
  const float b = (k < K) ? B[(long)k * HID + c] : 0.f;
  const unsigned short hi = f2b(b);
  Bt[i] = hi;
  Bt[HID * KPAD + i] = f2b(b - b2f(hi));
}

// ---------------- GEMM: [M,160] = A[M,K] @ B, LDS-staged B, pipelined --------
template<int K, int KPAD, int BK, int MODE, int SPLIT>
__global__ __launch_bounds__(256) void gemm_lds(
    const float* __restrict__ A, const unsigned short* __restrict__ Bt,
    float* __restrict__ C, unsigned short* __restrict__ Ch,
    const float* __restrict__ bias,
    const float* __restrict__ att_s, const float* __restrict__ att_d,
    float* __restrict__ a_s, float* __restrict__ a_d)
{
  constexpr int NP = SPLIT ? 2 : 1;
  constexpr int LSTR = BK + 8;
  constexpr int CHUNKS = KPAD / BK;
  constexpr int KSC = BK / 32;
  constexpr int ROWU = BK / 8;
  constexpr int UNITS = NP * HID * ROWU;
  __shared__ __align__(16) unsigned short Bs[NP][HID][LSTR];

  const int t = threadIdx.x;
  const int l = t & 63;
  const int w = t >> 6;
  const int m = l & 15;
  const int kgrp = (l >> 4) * 8;
  const int rbase = blockIdx.x * 64 + w * 16;
  const int arow = (rbase + m < N_NODES) ? rbase + m : N_NODES - 1;
  const float* Arow = A + (long)arow * K;

  f32x4 acc[10];
  #pragma unroll
  for (int i = 0; i < 10; ++i) acc[i] = (f32x4){0.f, 0.f, 0.f, 0.f};

  if constexpr (CHUNKS == 1) {
    float ar[KSC][8];
    #pragma unroll
    for (int ks = 0; ks < KSC; ++ks) {
      const int kb = ks * 32 + kgrp;
      if (kb + 8 <= K) {
        const float4 a0 = *(const float4*)(Arow + kb);
        const float4 a1 = *(const float4*)(Arow + kb + 4);
        ar[ks][0]=a0.x; ar[ks][1]=a0.y; ar[ks][2]=a0.z; ar[ks][3]=a0.w;
        ar[ks][4]=a1.x; ar[ks][5]=a1.y; ar[ks][6]=a1.z; ar[ks][7]=a1.w;
      } else {
        #pragma unroll
        for (int j = 0; j < 8; ++j) ar[ks][j] = (kb + j < K) ? Arow[kb + j] : 0.f;
      }
    }
    for (int u = t; u < UNITS; u += 256) {
      const int p = u / (HID * ROWU);
      const int rem = u % (HID * ROWU);
      const int c = rem / ROWU;
      const int k8 = rem % ROWU;
      const short8 v = *(const short8*)(Bt + (long)p * HID * KPAD + (long)c * KPAD + k8 * 8);
      *(short8*)&Bs[p][c][k8 * 8] = v;
    }
    __syncthreads();
    #pragma unroll
    for (int ks = 0; ks < KSC; ++ks) {
      short8 ah, al;
      #pragma unroll
      for (int j = 0; j < 8; ++j) {
        const unsigned short h = f2b(ar[ks][j]);
        ah[j] = (short)h;
        if (SPLIT) al[j] = (short)f2b(ar[ks][j] - b2f(h));
      }
      #pragma unroll
      for (int ct = 0; ct < 10; ++ct) {
        const short8 bh = *(const short8*)&Bs[0][ct * 16 + m][ks * 32 + kgrp];
        acc[ct] = __builtin_amdgcn_mfma_f32_16x16x32_bf16(ah, bh, acc[ct], 0, 0, 0);
        if (SPLIT) {
          const short8 bl = *(const short8*)&Bs[SPLIT][ct * 16 + m][ks * 32 + kgrp];
          acc[ct] = __builtin_amdgcn_mfma_f32_16x16x32_bf16(ah, bl, acc[ct], 0, 0, 0);
          acc[ct] = __builtin_amdgcn_mfma_f32_16x16x32_bf16(al, bh, acc[ct], 0, 0, 0);
        }
      }
    }
  } else {
    static_assert(UNITS % 256 == 0, "units must tile threads");
    constexpr int UPT = UNITS / 256;
    short8 rb[UPT];
    float ar[KSC][8];

    #pragma unroll
    for (int i = 0; i < UPT; ++i) {
      const int u = i * 256 + t;
      const int p = u / (HID * ROWU);
      const int rem = u % (HID * ROWU);
      const int c = rem / ROWU;
      const int k8 = rem % ROWU;
      rb[i] = *(const short8*)(Bt + (long)p * HID * KPAD + (long)c * KPAD + k8 * 8);
    }
    #pragma unroll
    for (int ks = 0; ks < KSC; ++ks) {
      const int kb = ks * 32 + kgrp;
      const float4 a0 = *(const float4*)(Arow + kb);
      const float4 a1 = *(const float4*)(Arow + kb + 4);
      ar[ks][0]=a0.x; ar[ks][1]=a0.y; ar[ks][2]=a0.z; ar[ks][3]=a0.w;
      ar[ks][4]=a1.x; ar[ks][5]=a1.y; ar[ks][6]=a1.z; ar[ks][7]=a1.w;
    }

    for (int cc = 0; cc < CHUNKS; ++cc) {
      __syncthreads();
      #pragma unroll
      for (int i = 0; i < UPT; ++i) {
        const int u = i * 256 + t;
        const int p = u / (HID * ROWU);
        const int rem = u % (HID * ROWU);
        const int c = rem / ROWU;
        const int k8 = rem % ROWU;
        *(short8*)&Bs[p][c][k8 * 8] = rb[i];
      }
      __syncthreads();
      short8 rb2[UPT];
      float ar2[KSC][8];
      if (cc + 1 < CHUNKS) {
        #pragma unroll
        for (int i = 0; i < UPT; ++i) {
          const int u = i * 256 + t;
          const int p = u / (HID * ROWU);
          const int rem = u % (HID * ROWU);
          const int c = rem / ROWU;
          const int k8 = rem % ROWU;
          rb2[i] = *(const short8*)(Bt + (long)p * HID * KPAD + (long)c * KPAD + (cc + 1) * BK + k8 * 8);
        }
        #pragma unroll
        for (int ks = 0; ks < KSC; ++ks) {
          const int kb = (cc + 1) * BK + ks * 32 + kgrp;
          if (kb + 8 <= K) {
            const float4 a0 = *(const float4*)(Arow + kb);
            const float4 a1 = *(const float4*)(Arow + kb + 4);
            ar2[ks][0]=a0.x; ar2[ks][1]=a0.y; ar2[ks][2]=a0.z; ar2[ks][3]=a0.w;
            ar2[ks][4]=a1.x; ar2[ks][5]=a1.y; ar2[ks][6]=a1.z; ar2[ks][7]=a1.w;
          } else {
            #pragma unroll
            for (int j = 0; j < 8; ++j) ar2[ks][j] = (kb + j < K) ? Arow[kb + j] : 0.f;
          }
        }
        __builtin_amdgcn_sched_barrier(0);
      }
      #pragma unroll
      for (int ks = 0; ks < KSC; ++ks) {
        short8 ah, al;
        #pragma unroll
        for (int j = 0; j < 8; ++j) {
          const unsigned short h = f2b(ar[ks][j]);
          ah[j] = (short)h;
          if (SPLIT) al[j] = (short)f2b(ar[ks][j] - b2f(h));
        }
        #pragma unroll
        for (int ct = 0; ct < 10; ++ct) {
          const short8 bh = *(const short8*)&Bs[0][ct * 16 + m][ks * 32 + kgrp];
          acc[ct] = __builtin_amdgcn_mfma_f32_16x16x32_bf16(ah, bh, acc[ct], 0, 0, 0);
          if (SPLIT) {
            const short8 bl = *(const short8*)&Bs[SPLIT][ct * 16 + m][ks * 32 + kgrp];
            acc[ct] = __builtin_amdgcn_mfma_f32_16x16x32_bf16(ah, bl, acc[ct], 0, 0, 0);
            acc[ct] = __builtin_amdgcn_mfma_f32_16x16x32_bf16(al, bh, acc[ct], 0, 0, 0);
          }
        }
      }
      if (cc + 1 < CHUNKS) {
        #pragma unroll
        for (int i = 0; i < UPT; ++i) rb[i] = rb2[i];
        #pragma unroll
        for (int ks = 0; ks < KSC; ++ks)
          #pragma unroll
          for (int j = 0; j < 8; ++j) ar[ks][j] = ar2[ks][j];
      }
    }
  }

  const int crow0 = rbase + (l >> 4) * 4;

  if (MODE == 2) {
    #pragma unroll
    for (int r = 0; r < 4; ++r) {
      float ps[5], pd[5];
      #pragma unroll
      for (int h = 0; h < 5; ++h) {
        float s = acc[2*h][r]     * att_s[(2*h) * 16 + m]
                + acc[2*h + 1][r] * att_s[(2*h + 1) * 16 + m];
        float d = acc[2*h][r]     * att_d[(2*h) * 16 + m]
                + acc[2*h + 1][r] * att_d[(2*h + 1) * 16 + m];
        #pragma unroll
        for (int o = 1; o < 16; o <<= 1) {
          s += __shfl_xor(s, o, 64);
          d += __shfl_xor(d, o, 64);
        }
        ps[h] = s; pd[h] = d;
      }
      const int crow = crow0 + r;
      if (crow < N_NODES && m < 5) {
        const float vs = m == 0 ? ps[0] : m == 1 ? ps[1] : m == 2 ? ps[2] : m == 3 ? ps[3] : ps[4];
        const float vd = m == 0 ? pd[0] : m == 1 ? pd[1] : m == 2 ? pd[2] : m == 3 ? pd[3] : pd[4];
        a_s[crow * 5 + m] = vs;
        a_d[crow * 5 + m] = vd;
      }
    }
  }

  #pragma unroll
  for (int r = 0; r < 4; ++r) {
    const int crow = crow0 + r;
    if (crow < N_NODES) {
      #pragma unroll
      for (int ct = 0; ct < 10; ++ct) {
        const int col = ct * 16 + m;
        float v = acc[ct][r];
        if (MODE == 1) { v += bias[col]; v = v > 0.f ? v : 0.01f * v; }
        if (MODE == 2) Ch[(long)crow * HID + col] = f2b(v);
        else           C[(long)crow * HID + col] = v;
      }
    }
  }
}

// ---------------- CSR build ---------------------------------------------------
__global__ __launch_bounds__(256) void count_kernel(const int* __restrict__ ei,
    const int* __restrict__ flag, int* __restrict__ deg) {
  const int e = blockIdx.x * 256 + threadIdx.x;
  if (e >= E_TOT) return;
  const int wide = *flag;
  const int d = (e < E_RAW_N) ? edge_dst(ei, wide, e) : (e - E_RAW_N);
  atomicAdd(&deg[d], 1);
}

#define SCAN_CHUNK 49  // 1024*49 = 50176 >= 50000
__global__ __launch_bounds__(1024) void scan_kernel(const int* __restrict__ deg, int* __restrict__ off) {
  __shared__ int wtot[16];
  const int t = threadIdx.x;
  const int lane = t & 63, wid = t >> 6;
  const int base = t * SCAN_CHUNK;
  int local[SCAN_CHUNK];
  int sum = 0;
  #pragma unroll
  for (int i = 0; i < SCAN_CHUNK; ++i) {
    const int idx = base + i;
    const int v = (idx < N_NODES) ? deg[idx] : 0;
    local[i] = sum;
    sum += v;
  }
  int inc = sum;
  #pragma unroll
  for (int o = 1; o < 64; o <<= 1) {
    const int y = __shfl_up(inc, o, 64);
    if (lane >= o) inc += y;
  }
  if (lane == 63) wtot[wid] = inc;
  __syncthreads();
  if (wid == 0 && lane < 16) {
    const int v = wtot[lane];
    int inc2 = v;
    #pragma unroll
    for (int o = 1; o < 16; o <<= 1) {
      const int y = __shfl_up(inc2, o, 64);
      if (lane >= o) inc2 += y;
    }
    wtot[lane] = inc2 - v;  // exclusive
  }
  __syncthreads();
  const int pre = wtot[wid] + (inc - sum);
  #pragma unroll
  for (int i = 0; i < SCAN_CHUNK; ++i) {
    const int idx = base + i;
    if (idx < N_NODES) off[idx] = pre + local[i];
  }
  if (t == 1023) off[N_NODES] = E_TOT;
}

__global__ __launch_bounds__(256) void fill_kernel(const int* __restrict__ ei,
    const int* __restrict__ flag, const int* __restrict__ off,
    int* __restrict__ fillc, int* __restrict__ csr_src, int* __restrict__ csr_eid) {
  const int e = blockIdx.x * 256 + threadIdx.x;
  if (e >= E_TOT) return;
  const int wide = *flag;
  int s, d;
  if (e < E_RAW_N) { s = edge_src(ei, wide, e); d = edge_dst(ei, wide, e); }
  else { s = e - E_RAW_N; d = s; }
  const int p = off[d] + atomicAdd(&fillc[d], 1);
  csr_src[p] = s;
  csr_eid[p] = e;
}

// ---------------- fused per-node segment-softmax + aggregation ---------------
// one wave per dst node. Fast path (deg<=64): register softmax; edge table
// {src, alpha0..4} dumped to LDS (zero-padded to x4); aggregate loop unroll-4
// with grouped loads (~24 gathers in flight/wave), 3 broadcast ds_reads/edge.
template<int DO_LN>
__global__ __launch_bounds__(256) void node_kernel(
    const int* __restrict__ off_, const int* __restrict__ csr_src, const int* __restrict__ csr_eid,
    const unsigned short* __restrict__ xlh,
    const float* __restrict__ a_s, const float* __restrict__ a_d,
    float* __restrict__ alpha_out,
    const float* __restrict__ bias,
    const float* __restrict__ gamma_, const float* __restrict__ beta_,
    float* __restrict__ hout)
{
  __shared__ int   srcS[4][64];
  __shared__ float alS[4][64][6];   // 5 alphas, stride 6 floats (24B)

  const int w = threadIdx.x >> 6;
  const int l = threadIdx.x & 63;
  const int n = blockIdx.x * 4 + w;
  if (n >= N_NODES) return;
  const int off = off_[n];
  const int deg = off_[n + 1] - off;

  const float ad0 = a_d[n*5+0], ad1 = a_d[n*5+1], ad2 = a_d[n*5+2], ad3 = a_d[n*5+3], ad4 = a_d[n*5+4];
  const int hA = l >> 4;  // head for cols 2l, 2l+1
  float accx = 0.f, accy = 0.f, accz = 0.f;

  if (deg <= 64) {
    // ---- register softmax: one lane per edge ----
    int src = 0, eid = 0;
    float v0 = -1e30f, v1 = -1e30f, v2 = -1e30f, v3 = -1e30f, v4 = -1e30f;
    if (l < deg) {
      src = csr_src[off + l];
      eid = csr_eid[off + l];
      const float* ap = a_s + src * 5;
      v0 = lrelu2(ap[0] + ad0);
      v1 = lrelu2(ap[1] + ad1);
      v2 = lrelu2(ap[2] + ad2);
      v3 = lrelu2(ap[3] + ad3);
      v4 = lrelu2(ap[4] + ad4);
    }
    const float m0 = wmax(v0), m1 = wmax(v1), m2 = wmax(v2), m3 = wmax(v3), m4 = wmax(v4);
    float e0 = 0.f, e1 = 0.f, e2 = 0.f, e3 = 0.f, e4 = 0.f;
    if (l < deg) {
      e0 = __expf(v0 - m0); e1 = __expf(v1 - m1); e2 = __expf(v2 - m2);
      e3 = __expf(v3 - m3); e4 = __expf(v4 - m4);
    }
    const float i0 = 1.f / (wsum(e0) + 1e-16f), i1 = 1.f / (wsum(e1) + 1e-16f),
                i2 = 1.f / (wsum(e2) + 1e-16f), i3 = 1.f / (wsum(e3) + 1e-16f),
                i4 = 1.f / (wsum(e4) + 1e-16f);
    const float a0 = e0 * i0, a1 = e1 * i1, a2 = e2 * i2, a3 = e3 * i3, a4 = e4 * i4;
    if (l < deg) {
      float* aw = alpha_out + (long)eid * 5;
      aw[0] = a0; aw[1] = a1; aw[2] = a2; aw[3] = a3; aw[4] = a4;
    }
    // ---- dump edge table to LDS (zeros beyond deg) ----
    srcS[w][l] = src;                       // src=0 for l>=deg (alpha 0)
    alS[w][l][0] = a0; alS[w][l][1] = a1; alS[w][l][2] = a2;
    alS[w][l][3] = a3; alS[w][l][4] = a4;

    const int degR = (deg + 3) & ~3;
    const unsigned cx = 2 * l, cz = 128 + l;
    for (int s0 = 0; s0 < degR; s0 += 4) {
      int sr[4]; float aA[4], aB[4];
      #pragma unroll
      for (int j = 0; j < 4; ++j) {
        sr[j] = srcS[w][s0 + j];
        aA[j] = alS[w][s0 + j][hA];
        aB[j] = alS[w][s0 + j][4];
      }
      ushort2 u2[4]; unsigned short z[4];
      #pragma unroll
      for (int j = 0; j < 4; ++j) {
        const unsigned xb = (unsigned)sr[j] * HID;
        u2[j] = *(const ushort2*)(xlh + xb + cx);
        if (l < 32) z[j] = xlh[xb + cz];
      }
      #pragma unroll
      for (int j = 0; j < 4; ++j) {
        accx += b2f(u2[j].x) * aA[j];
        accy += b2f(u2[j].y) * aA[j];
        if (l < 32) accz += b2f(z[j]) * aB[j];
      }
    }
  } else {
    // ---- slow path (rare): 3-pass over segment ----
    float m0 = -1e30f, m1 = -1e30f, m2 = -1e30f, m3 = -1e30f, m4 = -1e30f;
    for (int s = l; s < deg; s += 64) {
      const float* ap = a_s + csr_src[off + s] * 5;
      m0 = fmaxf(m0, lrelu2(ap[0] + ad0));
      m1 = fmaxf(m1, lrelu2(ap[1] + ad1));
      m2 = fmaxf(m2, lrelu2(ap[2] + ad2));
      m3 = fmaxf(m3, lrelu2(ap[3] + ad3));
      m4 = fmaxf(m4, lrelu2(ap[4] + ad4));
    }
    m0 = wmax(m0); m1 = wmax(m1); m2 = wmax(m2); m3 = wmax(m3); m4 = wmax(m4);
    float s0 = 0.f, s1 = 0.f, s2 = 0.f, s3 = 0.f, s4 = 0.f;
    for (int s = l; s < deg; s += 64) {
      const float* ap = a_s + csr_src[off + s] * 5;
      s0 += __expf(lrelu2(ap[0] + ad0) - m0);
      s1 += __expf(lrelu2(ap[1] + ad1) - m1);
      s2 += __expf(lrelu2(ap[2] + ad2) - m2);
      s3 += __expf(lrelu2(ap[3] + ad3) - m3);
      s4 += __expf(lrelu2(ap[4] + ad4) - m4);
    }
    const float i0 = 1.f / (wsum(s0) + 1e-16f), i1 = 1.f / (wsum(s1) + 1e-16f),
                i2 = 1.f / (wsum(s2) + 1e-16f), i3 = 1.f / (wsum(s3) + 1e-16f),
                i4 = 1.f / (wsum(s4) + 1e-16f);
    const float adA = hA == 0 ? ad0 : hA == 1 ? ad1 : hA == 2 ? ad2 : ad3;
    const float mA  = hA == 0 ? m0  : hA == 1 ? m1  : hA == 2 ? m2  : m3;
    const float iA  = hA == 0 ? i0  : hA == 1 ? i1  : hA == 2 ? i2  : i3;
    float adw = 0.f, mw = 0.f, iw = 0.f;
    if (l < 5) {
      adw = l == 0 ? ad0 : l == 1 ? ad1 : l == 2 ? ad2 : l == 3 ? ad3 : ad4;
      mw  = l == 0 ? m0  : l == 1 ? m1  : l == 2 ? m2  : l == 3 ? m3  : m4;
      iw  = l == 0 ? i0  : l == 1 ? i1  : l == 2 ? i2  : l == 3 ? i3  : i4;
    }
    for (int s = 0; s < deg; ++s) {
      const int p = off + s;
      const int srcs = csr_src[p];
      const float* ap = a_s + srcs * 5;
      const float aA = __expf(lrelu2(ap[hA] + adA) - mA) * iA;
      const long xb = (long)srcs * HID;
      const ushort2 u2 = *(const ushort2*)(xlh + xb + 2 * l);
      accx += b2f(u2.x) * aA;
      accy += b2f(u2.y) * aA;
      if (l < 32) {
        const float aC = __expf(lrelu2(ap[4] + ad4) - m4) * i4;
        accz += b2f(xlh[xb + 128 + l]) * aC;
      }
      if (l < 5) {
        alpha_out[(long)csr_eid[p] * 5 + l] = __expf(lrelu2(ap[l] + adw) - mw) * iw;
      }
    }
  }

  // epilogue
  const int c0 = 2 * l, c2 = 128 + l;
  float v0 = accx + bias[c0];     v0 = v0 > 0.f ? v0 : 0.01f * v0;
  float v1 = accy + bias[c0 + 1]; v1 = v1 > 0.f ? v1 : 0.01f * v1;
  float v2 = 0.f;
  if (l < 32) { v2 = accz + bias[c2]; v2 = v2 > 0.f ? v2 : 0.01f * v2; }

  const long hb = (long)n * HID;
  if (DO_LN) {
    const float tot = wsum(v0 + v1 + v2);
    const float mean = tot * (1.f / 160.f);
    const float d0 = v0 - mean, d1 = v1 - mean;
    float sq = d0 * d0 + d1 * d1;
    float d2 = 0.f;
    if (l < 32) { d2 = v2 - mean; sq += d2 * d2; }
    const float var = wsum(sq) * (1.f / 160.f);
    const float rstd = rsqrtf(var + 1e-5f);
    hout[hb + c0]     = d0 * rstd * gamma_[c0]     + beta_[c0];
    hout[hb + c0 + 1] = d1 * rstd * gamma_[c0 + 1] + beta_[c0 + 1];
    if (l < 32) hout[hb + c2] = d2 * rstd * gamma_[c2] + beta_[c2];
  } else {
    hout[hb + c0]     = v0;
    hout[hb + c0 + 1] = v1;
    if (l < 32) hout[hb + c2] = v2;
  }
}

extern "C" void kernel_launch(void* const* d_in, const int* in_sizes, int n_in,
                              void* d_out, int out_size, void* d_ws, size_t ws_size,
                              hipStream_t stream)
{
  const float* x     = (const float*)d_in[0];
  const int*   ei    = (const int*)d_in[1];
  const float* W1    = (const float*)d_in[2];
  const float* att1s = (const float*)d_in[3];
  const float* att1d = (const float*)d_in[4];
  const float* b1    = (const float*)d_in[5];
  const float* g1    = (const float*)d_in[6];
  const float* be1   = (const float*)d_in[7];
  const float* W2    = (const float*)d_in[8];
  const float* att2s = (const float*)d_in[9];
  const float* att2d = (const float*)d_in[10];
  const float* b2    = (const float*)d_in[11];
  const float* Wm    = (const float*)d_in[12];
  const float* bm    = (const float*)d_in[13];

  float* out    = (float*)d_out;                      // [N,160]
  float* alpha1 = out + (long)N_NODES * HID;          // [E,5]
  float* alpha2 = alpha1 + (long)E_TOT * 5;           // [E,5]

  char* p = (char*)d_ws;
  auto alloc = [&](size_t bytes) { void* r = (void*)p; p += (bytes + 255) & ~(size_t)255; return r; };
  float* hbuf = (float*)alloc((size_t)N_NODES * HID * 4);
  unsigned short* xlh = (unsigned short*)alloc((size_t)N_NODES * HID * 2);
  float* as_  = (float*)alloc((size_t)N_NODES * 5 * 4);
  float* ad_  = (float*)alloc((size_t)N_NODES * 5 * 4);
  int* deg    = (int*)alloc((size_t)N_NODES * 4);
  int* fillc  = (int*)alloc((size_t)N_NODES * 4);
  int* off    = (int*)alloc((size_t)(N_NODES + 1) * 4);
  int* csrS   = (int*)alloc((size_t)E_TOT * 4);
  int* csrE   = (int*)alloc((size_t)E_TOT * 4);
  int* flag   = (int*)alloc(256);
  unsigned short* Bt1 = (unsigned short*)alloc((size_t)2 * HID * 512 * 2);
  unsigned short* Bt2 = (unsigned short*)alloc((size_t)2 * HID * 160 * 2);
  unsigned short* Btm = (unsigned short*)alloc((size_t)2 * HID * 160 * 2);

  hipMemsetAsync(deg, 0, (size_t)N_NODES * 4, stream);
  hipMemsetAsync(fillc, 0, (size_t)N_NODES * 4, stream);

  detect_kernel<<<1, 64, 0, stream>>>(ei, flag);
  const int EB = (E_TOT + 255) / 256;
  count_kernel<<<EB, 256, 0, stream>>>(ei, flag, deg);
  scan_kernel<<<1, 1024, 0, stream>>>(deg, off);
  fill_kernel<<<EB, 256, 0, stream>>>(ei, flag, off, fillc, csrS, csrE);

  convert_B<<<(HID * 512 + 255) / 256, 256, 0, stream>>>(W1, Bt1, F_IN_K, 512);
  convert_B<<<(HID * 160 + 255) / 256, 256, 0, stream>>>(W2, Bt2, HID, 160);
  convert_B<<<(HID * 160 + 255) / 256, 256, 0, stream>>>(Wm, Btm, HID, 160);

  const int GB = (N_NODES + 63) / 64;

  // layer 1: split-bf16 pipelined LDS-GEMM + fused attention dots
  gemm_lds<F_IN_K, 512, 64, 2, 1><<<GB, 256, 0, stream>>>(x, Bt1, nullptr, xlh, nullptr, att1s, att1d, as_, ad_);
  node_kernel<1><<<N_NODES / 4, 256, 0, stream>>>(off, csrS, csrE, xlh, as_, ad_, alpha1, b1, g1, be1, hbuf);

  // layer 2
  gemm_lds<HID, 160, 160, 2, 0><<<GB, 256, 0, stream>>>(hbuf, Bt2, nullptr, xlh, nullptr, att2s, att2d, as_, ad_);
  node_kernel<0><<<N_NODES / 4, 256, 0, stream>>>(off, csrS, csrE, xlh, as_, ad_, alpha2, b2, nullptr, nullptr, hbuf);

  // final MLP: out = leaky(h2 @ Wm + bm)
  gemm_lds<HID, 160, 160, 1, 0><<<GB, 256, 0, stream>>>(hbuf, Btm, out, nullptr, bm, nullptr, nullptr, nullptr, nullptr);
}

// Round 11
// 424.255 us; speedup vs baseline: 2.3708x; 1.0403x over previous
//
#include <hip/hip_runtime.h>

#define N_NODES 50000
#define E_RAW_N 800000
#define E_TOT   850000
#define F_IN_K  500
#define HID     160

using short8 = __attribute__((ext_vector_type(8))) short;
using f32x4  = __attribute__((ext_vector_type(4))) float;

__device__ __forceinline__ float b2f(unsigned short u) {
  union { unsigned int i; float f; } v; v.i = ((unsigned int)u) << 16; return v.f;
}
__device__ __forceinline__ unsigned short f2b(float f) {
  union { float f; unsigned int i; } v; v.f = f;
  unsigned int i = v.i;
  unsigned int lsb = (i >> 16) & 1u;
  i += 0x7fffu + lsb;
  return (unsigned short)(i >> 16);
}

__device__ __forceinline__ float wsum(float x) {
  #pragma unroll
  for (int o = 32; o; o >>= 1) x += __shfl_xor(x, o, 64);
  return x;
}
__device__ __forceinline__ float wmax(float x) {
  #pragma unroll
  for (int o = 32; o; o >>= 1) x = fmaxf(x, __shfl_xor(x, o, 64));
  return x;
}
__device__ __forceinline__ float lrelu2(float x) { return x > 0.f ? x : 0.2f * x; }

// ---------------- edge dtype detection (int64 vs int32 hedge) ----------------
__global__ void detect_kernel(const int* __restrict__ ei, int* __restrict__ flag) {
  if (threadIdx.x == 0 && blockIdx.x == 0) {
    int allz = 1;
    for (int i = 1; i < 128; i += 2) if (ei[i] != 0) { allz = 0; break; }
    *flag = allz;  // 1 => int64 layout
  }
}
__device__ __forceinline__ int edge_src(const int* ei, int wide, int e) {
  return wide ? ei[2 * e] : ei[e];
}
__device__ __forceinline__ int edge_dst(const int* ei, int wide, int e) {
  return wide ? ei[2 * (E_RAW_N + e)] : ei[E_RAW_N + e];
}

// ------- weight pre-convert: B[K][160] f32 -> Bt hi/lo planes [160][KPAD] ----
__global__ __launch_bounds__(256) void convert_B(const float* __restrict__ B,
                                                 unsigned short* __restrict__ Bt,
                                                 int K, int KPAD) {
  const int i = blockIdx.x * 256 + threadIdx.x;
  if (i >= HID * KPAD) return;
  const int c = i / KPAD, k = i % KPAD;
  const float b = (k < K) ? B[(long)k * HID + c] : 0.f;
  const unsigned short hi = f2b(b);
  Bt[i] = hi;
  Bt[HID * KPAD + i] = f2b(b - b2f(hi));
}

// ---------------- GEMM: [M,160] = A[M,K] @ B, LDS-staged B, pipelined --------
// block = 4 waves; wave = 16 rows x 160 cols (10 col-tiles, 16x16x32 MFMA).
// AT=float: A converted to bf16 (hi/lo if SPLIT) in-register.
// AT=ushort: A already bf16 -> direct short8 loads, SPLIT must be 0.
// Reg-prefetch: B loads for chunk cc+1 issued right after rb's ds_write (rb
// dead) -> no double register buffer for B; A uses a small double buffer.
// MODE 1: +bias, leaky(0.01), C f32. MODE 2: bf16 -> Ch + fused att dots.
template<typename AT, int K, int KPAD, int BK, int MODE, int SPLIT>
__global__ __launch_bounds__(256) void gemm_lds(
    const AT* __restrict__ A, const unsigned short* __restrict__ Bt,
    float* __restrict__ C, unsigned short* __restrict__ Ch,
    const float* __restrict__ bias,
    const float* __restrict__ att_s, const float* __restrict__ att_d,
    float* __restrict__ a_s, float* __restrict__ a_d)
{
  constexpr bool AB16 = (sizeof(AT) == 2);
  constexpr int NP = SPLIT ? 2 : 1;
  constexpr int LSTR = BK + 8;
  constexpr int CHUNKS = KPAD / BK;
  constexpr int KSC = BK / 32;
  constexpr int ROWU = BK / 8;
  constexpr int UNITS = NP * HID * ROWU;
  static_assert(UNITS % 256 == 0, "units must tile threads");
  constexpr int UPT = UNITS / 256;
  __shared__ __align__(16) unsigned short Bs[NP][HID][LSTR];

  const int t = threadIdx.x;
  const int l = t & 63;
  const int w = t >> 6;
  const int m = l & 15;
  const int kgrp = (l >> 4) * 8;
  const int rbase = blockIdx.x * 64 + w * 16;
  const int arow = (rbase + m < N_NODES) ? rbase + m : N_NODES - 1;
  const AT* Arow = A + (long)arow * K;

  f32x4 acc[10];
  #pragma unroll
  for (int i = 0; i < 10; ++i) acc[i] = (f32x4){0.f, 0.f, 0.f, 0.f};

  short8 rb[UPT];
  float  arF[KSC][8], arF2[KSC][8];
  short8 arS[KSC], arS2[KSC];

  auto loadB = [&](int cc, short8* dst) {
    #pragma unroll
    for (int i = 0; i < UPT; ++i) {
      const int u = i * 256 + t;
      const int p = u / (HID * ROWU);
      const int rem = u % (HID * ROWU);
      const int c = rem / ROWU;
      const int k8 = rem % ROWU;
      dst[i] = *(const short8*)(Bt + (long)p * HID * KPAD + (long)c * KPAD + cc * BK + k8 * 8);
    }
  };
  auto loadA = [&](int cc, float aF[KSC][8], short8* aS) {
    #pragma unroll
    for (int ks = 0; ks < KSC; ++ks) {
      const int kb = cc * BK + ks * 32 + kgrp;
      if constexpr (AB16) {
        short8 v = (short8){0,0,0,0,0,0,0,0};
        if (kb + 8 <= K) v = *(const short8*)(Arow + kb);
        else if (kb < K) {
          #pragma unroll
          for (int j = 0; j < 8; ++j) v[j] = (kb + j < K) ? (short)Arow[kb + j] : (short)0;
        }
        aS[ks] = v;
      } else {
        if (kb + 8 <= K) {
          const float4 a0 = *(const float4*)(Arow + kb);
          const float4 a1 = *(const float4*)(Arow + kb + 4);
          aF[ks][0]=a0.x; aF[ks][1]=a0.y; aF[ks][2]=a0.z; aF[ks][3]=a0.w;
          aF[ks][4]=a1.x; aF[ks][5]=a1.y; aF[ks][6]=a1.z; aF[ks][7]=a1.w;
        } else {
          #pragma unroll
          for (int j = 0; j < 8; ++j) aF[ks][j] = (kb + j < K) ? (float)Arow[kb + j] : 0.f;
        }
      }
    }
  };

  // prologue: chunk 0 into registers
  loadB(0, rb);
  loadA(0, arF, arS);

  for (int cc = 0; cc < CHUNKS; ++cc) {
    __syncthreads();   // (a) prev chunk's LDS reads done; rb loads arrived
    #pragma unroll
    for (int i = 0; i < UPT; ++i) {
      const int u = i * 256 + t;
      const int p = u / (HID * ROWU);
      const int rem = u % (HID * ROWU);
      const int c = rem / ROWU;
      const int k8 = rem % ROWU;
      *(short8*)&Bs[p][c][k8 * 8] = rb[i];
    }
    __syncthreads();   // (b) writes visible
    if (cc + 1 < CHUNKS) {
      loadB(cc + 1, rb);            // rb dead after ds_write -> reuse, in flight under compute
      loadA(cc + 1, arF2, arS2);
      __builtin_amdgcn_sched_barrier(0);  // pin load issue before MFMA cluster
    }
    __builtin_amdgcn_s_setprio(1);
    #pragma unroll
    for (int ks = 0; ks < KSC; ++ks) {
      short8 ah, al;
      if constexpr (AB16) {
        ah = arS[ks];
      } else {
        #pragma unroll
        for (int j = 0; j < 8; ++j) {
          const unsigned short h = f2b(arF[ks][j]);
          ah[j] = (short)h;
          if (SPLIT) al[j] = (short)f2b(arF[ks][j] - b2f(h));
        }
      }
      #pragma unroll
      for (int ct = 0; ct < 10; ++ct) {
        const short8 bh = *(const short8*)&Bs[0][ct * 16 + m][ks * 32 + kgrp];
        acc[ct] = __builtin_amdgcn_mfma_f32_16x16x32_bf16(ah, bh, acc[ct], 0, 0, 0);
        if (SPLIT) {
          const short8 bl = *(const short8*)&Bs[SPLIT][ct * 16 + m][ks * 32 + kgrp];
          acc[ct] = __builtin_amdgcn_mfma_f32_16x16x32_bf16(ah, bl, acc[ct], 0, 0, 0);
          acc[ct] = __builtin_amdgcn_mfma_f32_16x16x32_bf16(al, bh, acc[ct], 0, 0, 0);
        }
      }
    }
    __builtin_amdgcn_s_setprio(0);
    if (cc + 1 < CHUNKS) {
      #pragma unroll
      for (int ks = 0; ks < KSC; ++ks) {
        if constexpr (AB16) arS[ks] = arS2[ks];
        else {
          #pragma unroll
          for (int j = 0; j < 8; ++j) arF[ks][j] = arF2[ks][j];
        }
      }
    }
  }

  const int crow0 = rbase + (l >> 4) * 4;

  if (MODE == 2) {
    // fused attention dots: a_s[n,h] = sum_c xl[n,c] * att_s[h*32+c]
    #pragma unroll
    for (int r = 0; r < 4; ++r) {
      float ps[5], pd[5];
      #pragma unroll
      for (int h = 0; h < 5; ++h) {
        float s = acc[2*h][r]     * att_s[(2*h) * 16 + m]
                + acc[2*h + 1][r] * att_s[(2*h + 1) * 16 + m];
        float d = acc[2*h][r]     * att_d[(2*h) * 16 + m]
                + acc[2*h + 1][r] * att_d[(2*h + 1) * 16 + m];
        #pragma unroll
        for (int o = 1; o < 16; o <<= 1) {
          s += __shfl_xor(s, o, 64);
          d += __shfl_xor(d, o, 64);
        }
        ps[h] = s; pd[h] = d;
      }
      const int crow = crow0 + r;
      if (crow < N_NODES && m < 5) {
        const float vs = m == 0 ? ps[0] : m == 1 ? ps[1] : m == 2 ? ps[2] : m == 3 ? ps[3] : ps[4];
        const float vd = m == 0 ? pd[0] : m == 1 ? pd[1] : m == 2 ? pd[2] : m == 3 ? pd[3] : pd[4];
        a_s[crow * 5 + m] = vs;
        a_d[crow * 5 + m] = vd;
      }
    }
  }

  #pragma unroll
  for (int r = 0; r < 4; ++r) {
    const int crow = crow0 + r;
    if (crow < N_NODES) {
      #pragma unroll
      for (int ct = 0; ct < 10; ++ct) {
        const int col = ct * 16 + m;
        float v = acc[ct][r];
        if (MODE == 1) { v += bias[col]; v = v > 0.f ? v : 0.01f * v; }
        if (MODE == 2) Ch[(long)crow * HID + col] = f2b(v);
        else           C[(long)crow * HID + col] = v;
      }
    }
  }
}

// ---------------- CSR build ---------------------------------------------------
__global__ __launch_bounds__(256) void count_kernel(const int* __restrict__ ei,
    const int* __restrict__ flag, int* __restrict__ deg) {
  const int e = blockIdx.x * 256 + threadIdx.x;
  if (e >= E_TOT) return;
  const int wide = *flag;
  const int d = (e < E_RAW_N) ? edge_dst(ei, wide, e) : (e - E_RAW_N);
  atomicAdd(&deg[d], 1);
}

#define SCAN_CHUNK 49  // 1024*49 = 50176 >= 50000
__global__ __launch_bounds__(1024) void scan_kernel(const int* __restrict__ deg, int* __restrict__ off) {
  __shared__ int wtot[16];
  const int t = threadIdx.x;
  const int lane = t & 63, wid = t >> 6;
  const int base = t * SCAN_CHUNK;
  int local[SCAN_CHUNK];
  int sum = 0;
  #pragma unroll
  for (int i = 0; i < SCAN_CHUNK; ++i) {
    const int idx = base + i;
    const int v = (idx < N_NODES) ? deg[idx] : 0;
    local[i] = sum;
    sum += v;
  }
  int inc = sum;
  #pragma unroll
  for (int o = 1; o < 64; o <<= 1) {
    const int y = __shfl_up(inc, o, 64);
    if (lane >= o) inc += y;
  }
  if (lane == 63) wtot[wid] = inc;
  __syncthreads();
  if (wid == 0 && lane < 16) {
    const int v = wtot[lane];
    int inc2 = v;
    #pragma unroll
    for (int o = 1; o < 16; o <<= 1) {
      const int y = __shfl_up(inc2, o, 64);
      if (lane >= o) inc2 += y;
    }
    wtot[lane] = inc2 - v;  // exclusive
  }
  __syncthreads();
  const int pre = wtot[wid] + (inc - sum);
  #pragma unroll
  for (int i = 0; i < SCAN_CHUNK; ++i) {
    const int idx = base + i;
    if (idx < N_NODES) off[idx] = pre + local[i];
  }
  if (t == 1023) off[N_NODES] = E_TOT;
}

__global__ __launch_bounds__(256) void fill_kernel(const int* __restrict__ ei,
    const int* __restrict__ flag, const int* __restrict__ off,
    int* __restrict__ fillc, int* __restrict__ csr_src, int* __restrict__ csr_eid) {
  const int e = blockIdx.x * 256 + threadIdx.x;
  if (e >= E_TOT) return;
  const int wide = *flag;
  int s, d;
  if (e < E_RAW_N) { s = edge_src(ei, wide, e); d = edge_dst(ei, wide, e); }
  else { s = e - E_RAW_N; d = s; }
  const int p = off[d] + atomicAdd(&fillc[d], 1);
  csr_src[p] = s;
  csr_eid[p] = e;
}

// ---------------- fused per-node segment-softmax + aggregation ---------------
// one wave per dst node. Fast path (deg<=64): register softmax; edge table
// {src, alpha0..4} in LDS; aggregate loop unroll-8 (grouped loads, ~48
// gathers in flight/wave). hout stored bf16 (bit-identical to downstream
// GEMM's A conversion).
template<int DO_LN>
__global__ __launch_bounds__(256) void node_kernel(
    const int* __restrict__ off_, const int* __restrict__ csr_src, const int* __restrict__ csr_eid,
    const unsigned short* __restrict__ xlh,
    const float* __restrict__ a_s, const float* __restrict__ a_d,
    float* __restrict__ alpha_out,
    const float* __restrict__ bias,
    const float* __restrict__ gamma_, const float* __restrict__ beta_,
    unsigned short* __restrict__ hout)
{
  __shared__ int   srcS[4][64];
  __shared__ float alS[4][64][6];   // 5 alphas, stride 6 floats (24B)

  const int w = threadIdx.x >> 6;
  const int l = threadIdx.x & 63;
  const int n = blockIdx.x * 4 + w;
  if (n >= N_NODES) return;
  const int off = off_[n];
  const int deg = off_[n + 1] - off;

  const float ad0 = a_d[n*5+0], ad1 = a_d[n*5+1], ad2 = a_d[n*5+2], ad3 = a_d[n*5+3], ad4 = a_d[n*5+4];
  const int hA = l >> 4;  // head for cols 2l, 2l+1
  float accx = 0.f, accy = 0.f, accz = 0.f;

  if (deg <= 64) {
    // ---- register softmax: one lane per edge ----
    int src = 0, eid = 0;
    float v0 = -1e30f, v1 = -1e30f, v2 = -1e30f, v3 = -1e30f, v4 = -1e30f;
    if (l < deg) {
      src = csr_src[off + l];
      eid = csr_eid[off + l];
      const float* ap = a_s + src * 5;
      v0 = lrelu2(ap[0] + ad0);
      v1 = lrelu2(ap[1] + ad1);
      v2 = lrelu2(ap[2] + ad2);
      v3 = lrelu2(ap[3] + ad3);
      v4 = lrelu2(ap[4] + ad4);
    }
    const float m0 = wmax(v0), m1 = wmax(v1), m2 = wmax(v2), m3 = wmax(v3), m4 = wmax(v4);
    float e0 = 0.f, e1 = 0.f, e2 = 0.f, e3 = 0.f, e4 = 0.f;
    if (l < deg) {
      e0 = __expf(v0 - m0); e1 = __expf(v1 - m1); e2 = __expf(v2 - m2);
      e3 = __expf(v3 - m3); e4 = __expf(v4 - m4);
    }
    const float i0 = 1.f / (wsum(e0) + 1e-16f), i1 = 1.f / (wsum(e1) + 1e-16f),
                i2 = 1.f / (wsum(e2) + 1e-16f), i3 = 1.f / (wsum(e3) + 1e-16f),
                i4 = 1.f / (wsum(e4) + 1e-16f);
    const float a0 = e0 * i0, a1 = e1 * i1, a2 = e2 * i2, a3 = e3 * i3, a4 = e4 * i4;
    if (l < deg) {
      float* aw = alpha_out + (long)eid * 5;
      aw[0] = a0; aw[1] = a1; aw[2] = a2; aw[3] = a3; aw[4] = a4;
    }
    // ---- dump edge table to LDS (zeros beyond deg) ----
    srcS[w][l] = src;
    alS[w][l][0] = a0; alS[w][l][1] = a1; alS[w][l][2] = a2;
    alS[w][l][3] = a3; alS[w][l][4] = a4;

    const int degR = (deg + 7) & ~7;
    const unsigned cx = 2 * l, cz = 128 + l;
    for (int s0 = 0; s0 < degR; s0 += 8) {
      int sr[8]; float aA[8], aB[8];
      #pragma unroll
      for (int j = 0; j < 8; ++j) {
        sr[j] = srcS[w][s0 + j];
        aA[j] = alS[w][s0 + j][hA];
        aB[j] = alS[w][s0 + j][4];
      }
      ushort2 u2[8]; unsigned short z[8];
      #pragma unroll
      for (int j = 0; j < 8; ++j) {
        const unsigned xb = (unsigned)sr[j] * HID;
        u2[j] = *(const ushort2*)(xlh + xb + cx);
        if (l < 32) z[j] = xlh[xb + cz];
      }
      #pragma unroll
      for (int j = 0; j < 8; ++j) {
        accx += b2f(u2[j].x) * aA[j];
        accy += b2f(u2[j].y) * aA[j];
        if (l < 32) accz += b2f(z[j]) * aB[j];
      }
    }
  } else {
    // ---- slow path (rare): 3-pass over segment ----
    float m0 = -1e30f, m1 = -1e30f, m2 = -1e30f, m3 = -1e30f, m4 = -1e30f;
    for (int s = l; s < deg; s += 64) {
      const float* ap = a_s + csr_src[off + s] * 5;
      m0 = fmaxf(m0, lrelu2(ap[0] + ad0));
      m1 = fmaxf(m1, lrelu2(ap[1] + ad1));
      m2 = fmaxf(m2, lrelu2(ap[2] + ad2));
      m3 = fmaxf(m3, lrelu2(ap[3] + ad3));
      m4 = fmaxf(m4, lrelu2(ap[4] + ad4));
    }
    m0 = wmax(m0); m1 = wmax(m1); m2 = wmax(m2); m3 = wmax(m3); m4 = wmax(m4);
    float s0 = 0.f, s1 = 0.f, s2 = 0.f, s3 = 0.f, s4 = 0.f;
    for (int s = l; s < deg; s += 64) {
      const float* ap = a_s + csr_src[off + s] * 5;
      s0 += __expf(lrelu2(ap[0] + ad0) - m0);
      s1 += __expf(lrelu2(ap[1] + ad1) - m1);
      s2 += __expf(lrelu2(ap[2] + ad2) - m2);
      s3 += __expf(lrelu2(ap[3] + ad3) - m3);
      s4 += __expf(lrelu2(ap[4] + ad4) - m4);
    }
    const float i0 = 1.f / (wsum(s0) + 1e-16f), i1 = 1.f / (wsum(s1) + 1e-16f),
                i2 = 1.f / (wsum(s2) + 1e-16f), i3 = 1.f / (wsum(s3) + 1e-16f),
                i4 = 1.f / (wsum(s4) + 1e-16f);
    const float adA = hA == 0 ? ad0 : hA == 1 ? ad1 : hA == 2 ? ad2 : ad3;
    const float mA  = hA == 0 ? m0  : hA == 1 ? m1  : hA == 2 ? m2  : m3;
    const float iA  = hA == 0 ? i0  : hA == 1 ? i1  : hA == 2 ? i2  : i3;
    float adw = 0.f, mw = 0.f, iw = 0.f;
    if (l < 5) {
      adw = l == 0 ? ad0 : l == 1 ? ad1 : l == 2 ? ad2 : l == 3 ? ad3 : ad4;
      mw  = l == 0 ? m0  : l == 1 ? m1  : l == 2 ? m2  : l == 3 ? m3  : m4;
      iw  = l == 0 ? i0  : l == 1 ? i1  : l == 2 ? i2  : l == 3 ? i3  : i4;
    }
    for (int s = 0; s < deg; ++s) {
      const int p = off + s;
      const int srcs = csr_src[p];
      const float* ap = a_s + srcs * 5;
      const float aA = __expf(lrelu2(ap[hA] + adA) - mA) * iA;
      const long xb = (long)srcs * HID;
      const ushort2 u2 = *(const ushort2*)(xlh + xb + 2 * l);
      accx += b2f(u2.x) * aA;
      accy += b2f(u2.y) * aA;
      if (l < 32) {
        const float aC = __expf(lrelu2(ap[4] + ad4) - m4) * i4;
        accz += b2f(xlh[xb + 128 + l]) * aC;
      }
      if (l < 5) {
        alpha_out[(long)csr_eid[p] * 5 + l] = __expf(lrelu2(ap[l] + adw) - mw) * iw;
      }
    }
  }

  // epilogue (bf16 store — identical to downstream GEMM's A rounding)
  const int c0 = 2 * l, c2 = 128 + l;
  float v0 = accx + bias[c0];     v0 = v0 > 0.f ? v0 : 0.01f * v0;
  float v1 = accy + bias[c0 + 1]; v1 = v1 > 0.f ? v1 : 0.01f * v1;
  float v2 = 0.f;
  if (l < 32) { v2 = accz + bias[c2]; v2 = v2 > 0.f ? v2 : 0.01f * v2; }

  const long hb = (long)n * HID;
  if (DO_LN) {
    const float tot = wsum(v0 + v1 + v2);
    const float mean = tot * (1.f / 160.f);
    const float d0 = v0 - mean, d1 = v1 - mean;
    float sq = d0 * d0 + d1 * d1;
    float d2 = 0.f;
    if (l < 32) { d2 = v2 - mean; sq += d2 * d2; }
    const float var = wsum(sq) * (1.f / 160.f);
    const float rstd = rsqrtf(var + 1e-5f);
    hout[hb + c0]     = f2b(d0 * rstd * gamma_[c0]     + beta_[c0]);
    hout[hb + c0 + 1] = f2b(d1 * rstd * gamma_[c0 + 1] + beta_[c0 + 1]);
    if (l < 32) hout[hb + c2] = f2b(d2 * rstd * gamma_[c2] + beta_[c2]);
  } else {
    hout[hb + c0]     = f2b(v0);
    hout[hb + c0 + 1] = f2b(v1);
    if (l < 32) hout[hb + c2] = f2b(v2);
  }
}

extern "C" void kernel_launch(void* const* d_in, const int* in_sizes, int n_in,
                              void* d_out, int out_size, void* d_ws, size_t ws_size,
                              hipStream_t stream)
{
  const float* x     = (const float*)d_in[0];
  const int*   ei    = (const int*)d_in[1];
  const float* W1    = (const float*)d_in[2];
  const float* att1s = (const float*)d_in[3];
  const float* att1d = (const float*)d_in[4];
  const float* b1    = (const float*)d_in[5];
  const float* g1    = (const float*)d_in[6];
  const float* be1   = (const float*)d_in[7];
  const float* W2    = (const float*)d_in[8];
  const float* att2s = (const float*)d_in[9];
  const float* att2d = (const float*)d_in[10];
  const float* b2    = (const float*)d_in[11];
  const float* Wm    = (const float*)d_in[12];
  const float* bm    = (const float*)d_in[13];

  float* out    = (float*)d_out;                      // [N,160]
  float* alpha1 = out + (long)N_NODES * HID;          // [E,5]
  float* alpha2 = alpha1 + (long)E_TOT * 5;           // [E,5]

  char* p = (char*)d_ws;
  auto alloc = [&](size_t bytes) { void* r = (void*)p; p += (bytes + 255) & ~(size_t)255; return r; };
  unsigned short* hb16 = (unsigned short*)alloc((size_t)N_NODES * HID * 2);
  unsigned short* xlh  = (unsigned short*)alloc((size_t)N_NODES * HID * 2);
  float* as_  = (float*)alloc((size_t)N_NODES * 5 * 4);
  float* ad_  = (float*)alloc((size_t)N_NODES * 5 * 4);
  int* deg    = (int*)alloc((size_t)N_NODES * 4);
  int* fillc  = (int*)alloc((size_t)N_NODES * 4);
  int* off    = (int*)alloc((size_t)(N_NODES + 1) * 4);
  int* csrS   = (int*)alloc((size_t)E_TOT * 4);
  int* csrE   = (int*)alloc((size_t)E_TOT * 4);
  int* flag   = (int*)alloc(256);
  unsigned short* Bt1 = (unsigned short*)alloc((size_t)2 * HID * 512 * 2);
  unsigned short* Bt2 = (unsigned short*)alloc((size_t)2 * HID * 192 * 2);
  unsigned short* Btm = (unsigned short*)alloc((size_t)2 * HID * 192 * 2);

  hipMemsetAsync(deg, 0, (size_t)N_NODES * 4, stream);
  hipMemsetAsync(fillc, 0, (size_t)N_NODES * 4, stream);

  detect_kernel<<<1, 64, 0, stream>>>(ei, flag);
  const int EB = (E_TOT + 255) / 256;
  count_kernel<<<EB, 256, 0, stream>>>(ei, flag, deg);
  scan_kernel<<<1, 1024, 0, stream>>>(deg, off);
  fill_kernel<<<EB, 256, 0, stream>>>(ei, flag, off, fillc, csrS, csrE);

  convert_B<<<(HID * 512 + 255) / 256, 256, 0, stream>>>(W1, Bt1, F_IN_K, 512);
  convert_B<<<(HID * 192 + 255) / 256, 256, 0, stream>>>(W2, Bt2, HID, 192);
  convert_B<<<(HID * 192 + 255) / 256, 256, 0, stream>>>(Wm, Btm, HID, 192);

  const int GB = (N_NODES + 63) / 64;

  // layer 1: split-bf16 pipelined LDS-GEMM (BK=32, high occupancy) + att dots
  gemm_lds<float, F_IN_K, 512, 32, 2, 1><<<GB, 256, 0, stream>>>(x, Bt1, nullptr, xlh, nullptr, att1s, att1d, as_, ad_);
  node_kernel<1><<<N_NODES / 4, 256, 0, stream>>>(off, csrS, csrE, xlh, as_, ad_, alpha1, b1, g1, be1, hb16);

  // layer 2: bf16-A GEMM
  gemm_lds<unsigned short, HID, 192, 64, 2, 0><<<GB, 256, 0, stream>>>(hb16, Bt2, nullptr, xlh, nullptr, att2s, att2d, as_, ad_);
  node_kernel<0><<<N_NODES / 4, 256, 0, stream>>>(off, csrS, csrE, xlh, as_, ad_, alpha2, b2, nullptr, nullptr, hb16);

  // final MLP: out = leaky(h2 @ Wm + bm)
  gemm_lds<unsigned short, HID, 192, 64, 1, 0><<<GB, 256, 0, stream>>>(hb16, Btm, out, nullptr, bm, nullptr, nullptr, nullptr, nullptr);
}

// Round 12
// 404.653 us; speedup vs baseline: 2.4856x; 1.0484x over previous
//
#include <hip/hip_runtime.h>

#define N_NODES 50000
#define E_RAW_N 800000
#define E_TOT   850000
#define F_IN_K  500
#define HID     160

using short8 = __attribute__((ext_vector_type(8))) short;
using f32x4  = __attribute__((ext_vector_type(4))) float;

__device__ __forceinline__ float b2f(unsigned short u) {
  union { unsigned int i; float f; } v; v.i = ((unsigned int)u) << 16; return v.f;
}
__device__ __forceinline__ unsigned short f2b(float f) {
  union { float f; unsigned int i; } v; v.f = f;
  unsigned int i = v.i;
  unsigned int lsb = (i >> 16) & 1u;
  i += 0x7fffu + lsb;
  return (unsigned short)(i >> 16);
}

__device__ __forceinline__ float wsum(float x) {
  #pragma unroll
  for (int o = 32; o; o >>= 1) x += __shfl_xor(x, o, 64);
  return x;
}
__device__ __forceinline__ float wmax(float x) {
  #pragma unroll
  for (int o = 32; o; o >>= 1) x = fmaxf(x, __shfl_xor(x, o, 64));
  return x;
}
__device__ __forceinline__ float lrelu2(float x) { return x > 0.f ? x : 0.2f * x; }

// ---------------- edge dtype detection (int64 vs int32 hedge) ----------------
__global__ void detect_kernel(const int* __restrict__ ei, int* __restrict__ flag) {
  if (threadIdx.x == 0 && blockIdx.x == 0) {
    int allz = 1;
    for (int i = 1; i < 128; i += 2) if (ei[i] != 0) { allz = 0; break; }
    *flag = allz;  // 1 => int64 layout
  }
}
__device__ __forceinline__ int edge_src(const int* ei, int wide, int e) {
  return wide ? ei[2 * e] : ei[e];
}
__device__ __forceinline__ int edge_dst(const int* ei, int wide, int e) {
  return wide ? ei[2 * (E_RAW_N + e)] : ei[E_RAW_N + e];
}

// ------- weight pre-convert (all 3 weights in one launch): f32 -> bf16 -------
// W1[500][160] -> Bt1[160][512]; W2,Wm[160][160] -> Bt2,Btm[160][192]
__global__ __launch_bounds__(256) void convert_all(
    const float* __restrict__ W1, const float* __restrict__ W2, const float* __restrict__ Wm,
    unsigned short* __restrict__ Bt1, unsigned short* __restrict__ Bt2,
    unsigned short* __restrict__ Btm)
{
  const int i = blockIdx.x * 256 + threadIdx.x;
  if (i < HID * 512) {
    const int c = i / 512, k = i % 512;
    Bt1[i] = f2b((k < F_IN_K) ? W1[(long)k * HID + c] : 0.f);
  }
  if (i < HID * 192) {
    const int c = i / 192, k = i % 192;
    Bt2[i] = f2b((k < HID) ? W2[(long)k * HID + c] : 0.f);
    Btm[i] = f2b((k < HID) ? Wm[(long)k * HID + c] : 0.f);
  }
}

// ---------------- GEMM: [M,160] = A[M,K] @ B, LDS-staged B, pipelined --------
// block = 4 waves; wave = 16 rows x 160 cols (10 col-tiles, 16x16x32 MFMA).
// AT=float: A converted to bf16 in-register. AT=ushort: direct short8 loads.
// Reg-prefetch: B loads for chunk cc+1 issued right after rb's ds_write.
// MODE 1: +bias, leaky(0.01), C f32. MODE 2: bf16 -> Ch + fused att dots.
template<typename AT, int K, int KPAD, int BK, int MODE>
__global__ __launch_bounds__(256) void gemm_lds(
    const AT* __restrict__ A, const unsigned short* __restrict__ Bt,
    float* __restrict__ C, unsigned short* __restrict__ Ch,
    const float* __restrict__ bias,
    const float* __restrict__ att_s, const float* __restrict__ att_d,
    float* __restrict__ a_s, float* __restrict__ a_d)
{
  constexpr bool AB16 = (sizeof(AT) == 2);
  constexpr int LSTR = BK + 8;
  constexpr int CHUNKS = KPAD / BK;
  constexpr int KSC = BK / 32;
  constexpr int ROWU = BK / 8;
  constexpr int UNITS = HID * ROWU;
  static_assert(UNITS % 256 == 0, "units must tile threads");
  constexpr int UPT = UNITS / 256;
  __shared__ __align__(16) unsigned short Bs[HID][LSTR];

  const int t = threadIdx.x;
  const int l = t & 63;
  const int w = t >> 6;
  const int m = l & 15;
  const int kgrp = (l >> 4) * 8;
  const int rbase = blockIdx.x * 64 + w * 16;
  const int arow = (rbase + m < N_NODES) ? rbase + m : N_NODES - 1;
  const AT* Arow = A + (long)arow * K;

  f32x4 acc[10];
  #pragma unroll
  for (int i = 0; i < 10; ++i) acc[i] = (f32x4){0.f, 0.f, 0.f, 0.f};

  short8 rb[UPT];
  float  arF[KSC][8], arF2[KSC][8];
  short8 arS[KSC], arS2[KSC];

  auto loadB = [&](int cc, short8* dst) {
    #pragma unroll
    for (int i = 0; i < UPT; ++i) {
      const int u = i * 256 + t;
      const int c = u / ROWU;
      const int k8 = u % ROWU;
      dst[i] = *(const short8*)(Bt + (long)c * KPAD + cc * BK + k8 * 8);
    }
  };
  auto loadA = [&](int cc, float aF[KSC][8], short8* aS) {
    #pragma unroll
    for (int ks = 0; ks < KSC; ++ks) {
      const int kb = cc * BK + ks * 32 + kgrp;
      if constexpr (AB16) {
        short8 v = (short8){0,0,0,0,0,0,0,0};
        if (kb + 8 <= K) v = *(const short8*)(Arow + kb);
        else if (kb < K) {
          #pragma unroll
          for (int j = 0; j < 8; ++j) v[j] = (kb + j < K) ? (short)Arow[kb + j] : (short)0;
        }
        aS[ks] = v;
      } else {
        if (kb + 8 <= K) {
          const float4 a0 = *(const float4*)(Arow + kb);
          const float4 a1 = *(const float4*)(Arow + kb + 4);
          aF[ks][0]=a0.x; aF[ks][1]=a0.y; aF[ks][2]=a0.z; aF[ks][3]=a0.w;
          aF[ks][4]=a1.x; aF[ks][5]=a1.y; aF[ks][6]=a1.z; aF[ks][7]=a1.w;
        } else {
          #pragma unroll
          for (int j = 0; j < 8; ++j) aF[ks][j] = (kb + j < K) ? (float)Arow[kb + j] : 0.f;
        }
      }
    }
  };

  // prologue: chunk 0 into registers
  loadB(0, rb);
  loadA(0, arF, arS);

  for (int cc = 0; cc < CHUNKS; ++cc) {
    __syncthreads();   // (a) prev chunk's LDS reads done; rb loads arrived
    #pragma unroll
    for (int i = 0; i < UPT; ++i) {
      const int u = i * 256 + t;
      const int c = u / ROWU;
      const int k8 = u % ROWU;
      *(short8*)&Bs[c][k8 * 8] = rb[i];
    }
    __syncthreads();   // (b) writes visible
    if (cc + 1 < CHUNKS) {
      loadB(cc + 1, rb);            // rb dead after ds_write -> reuse
      loadA(cc + 1, arF2, arS2);
      __builtin_amdgcn_sched_barrier(0);  // pin load issue before MFMA cluster
    }
    __builtin_amdgcn_s_setprio(1);
    #pragma unroll
    for (int ks = 0; ks < KSC; ++ks) {
      short8 ah;
      if constexpr (AB16) {
        ah = arS[ks];
      } else {
        #pragma unroll
        for (int j = 0; j < 8; ++j) ah[j] = (short)f2b(arF[ks][j]);
      }
      #pragma unroll
      for (int ct = 0; ct < 10; ++ct) {
        const short8 bh = *(const short8*)&Bs[ct * 16 + m][ks * 32 + kgrp];
        acc[ct] = __builtin_amdgcn_mfma_f32_16x16x32_bf16(ah, bh, acc[ct], 0, 0, 0);
      }
    }
    __builtin_amdgcn_s_setprio(0);
    if (cc + 1 < CHUNKS) {
      #pragma unroll
      for (int ks = 0; ks < KSC; ++ks) {
        if constexpr (AB16) arS[ks] = arS2[ks];
        else {
          #pragma unroll
          for (int j = 0; j < 8; ++j) arF[ks][j] = arF2[ks][j];
        }
      }
    }
  }

  const int crow0 = rbase + (l >> 4) * 4;

  if (MODE == 2) {
    // fused attention dots: a_s[n,h] = sum_c xl[n,c] * att_s[h*32+c]
    #pragma unroll
    for (int r = 0; r < 4; ++r) {
      float ps[5], pd[5];
      #pragma unroll
      for (int h = 0; h < 5; ++h) {
        float s = acc[2*h][r]     * att_s[(2*h) * 16 + m]
                + acc[2*h + 1][r] * att_s[(2*h + 1) * 16 + m];
        float d = acc[2*h][r]     * att_d[(2*h) * 16 + m]
                + acc[2*h + 1][r] * att_d[(2*h + 1) * 16 + m];
        #pragma unroll
        for (int o = 1; o < 16; o <<= 1) {
          s += __shfl_xor(s, o, 64);
          d += __shfl_xor(d, o, 64);
        }
        ps[h] = s; pd[h] = d;
      }
      const int crow = crow0 + r;
      if (crow < N_NODES && m < 5) {
        const float vs = m == 0 ? ps[0] : m == 1 ? ps[1] : m == 2 ? ps[2] : m == 3 ? ps[3] : ps[4];
        const float vd = m == 0 ? pd[0] : m == 1 ? pd[1] : m == 2 ? pd[2] : m == 3 ? pd[3] : pd[4];
        a_s[crow * 5 + m] = vs;
        a_d[crow * 5 + m] = vd;
      }
    }
  }

  #pragma unroll
  for (int r = 0; r < 4; ++r) {
    const int crow = crow0 + r;
    if (crow < N_NODES) {
      #pragma unroll
      for (int ct = 0; ct < 10; ++ct) {
        const int col = ct * 16 + m;
        float v = acc[ct][r];
        if (MODE == 1) { v += bias[col]; v = v > 0.f ? v : 0.01f * v; }
        if (MODE == 2) Ch[(long)crow * HID + col] = f2b(v);
        else           C[(long)crow * HID + col] = v;
      }
    }
  }
}

// ---------------- CSR build ---------------------------------------------------
__global__ __launch_bounds__(256) void count_kernel(const int* __restrict__ ei,
    const int* __restrict__ flag, int* __restrict__ deg) {
  const int e = blockIdx.x * 256 + threadIdx.x;
  if (e >= E_TOT) return;
  const int wide = *flag;
  const int d = (e < E_RAW_N) ? edge_dst(ei, wide, e) : (e - E_RAW_N);
  atomicAdd(&deg[d], 1);
}

#define SCAN_CHUNK 49  // 1024*49 = 50176 >= 50000
__global__ __launch_bounds__(1024) void scan_kernel(const int* __restrict__ deg, int* __restrict__ off) {
  __shared__ int wtot[16];
  const int t = threadIdx.x;
  const int lane = t & 63, wid = t >> 6;
  const int base = t * SCAN_CHUNK;
  int local[SCAN_CHUNK];
  int sum = 0;
  #pragma unroll
  for (int i = 0; i < SCAN_CHUNK; ++i) {
    const int idx = base + i;
    const int v = (idx < N_NODES) ? deg[idx] : 0;
    local[i] = sum;
    sum += v;
  }
  int inc = sum;
  #pragma unroll
  for (int o = 1; o < 64; o <<= 1) {
    const int y = __shfl_up(inc, o, 64);
    if (lane >= o) inc += y;
  }
  if (lane == 63) wtot[wid] = inc;
  __syncthreads();
  if (wid == 0 && lane < 16) {
    const int v = wtot[lane];
    int inc2 = v;
    #pragma unroll
    for (int o = 1; o < 16; o <<= 1) {
      const int y = __shfl_up(inc2, o, 64);
      if (lane >= o) inc2 += y;
    }
    wtot[lane] = inc2 - v;  // exclusive
  }
  __syncthreads();
  const int pre = wtot[wid] + (inc - sum);
  #pragma unroll
  for (int i = 0; i < SCAN_CHUNK; ++i) {
    const int idx = base + i;
    if (idx < N_NODES) off[idx] = pre + local[i];
  }
  if (t == 1023) off[N_NODES] = E_TOT;
}

__global__ __launch_bounds__(256) void fill_kernel(const int* __restrict__ ei,
    const int* __restrict__ flag, const int* __restrict__ off,
    int* __restrict__ fillc, int* __restrict__ csr_src, int* __restrict__ csr_eid) {
  const int e = blockIdx.x * 256 + threadIdx.x;
  if (e >= E_TOT) return;
  const int wide = *flag;
  int s, d;
  if (e < E_RAW_N) { s = edge_src(ei, wide, e); d = edge_dst(ei, wide, e); }
  else { s = e - E_RAW_N; d = s; }
  const int p = off[d] + atomicAdd(&fillc[d], 1);
  csr_src[p] = s;
  csr_eid[p] = e;
}

// ---------------- fused per-node segment-softmax + aggregation ---------------
template<int DO_LN>
__global__ __launch_bounds__(256) void node_kernel(
    const int* __restrict__ off_, const int* __restrict__ csr_src, const int* __restrict__ csr_eid,
    const unsigned short* __restrict__ xlh,
    const float* __restrict__ a_s, const float* __restrict__ a_d,
    float* __restrict__ alpha_out,
    const float* __restrict__ bias,
    const float* __restrict__ gamma_, const float* __restrict__ beta_,
    unsigned short* __restrict__ hout)
{
  __shared__ int   srcS[4][64];
  __shared__ float alS[4][64][6];   // 5 alphas, stride 6 floats (24B)

  const int w = threadIdx.x >> 6;
  const int l = threadIdx.x & 63;
  const int n = blockIdx.x * 4 + w;
  if (n >= N_NODES) return;
  const int off = off_[n];
  const int deg = off_[n + 1] - off;

  const float ad0 = a_d[n*5+0], ad1 = a_d[n*5+1], ad2 = a_d[n*5+2], ad3 = a_d[n*5+3], ad4 = a_d[n*5+4];
  const int hA = l >> 4;  // head for cols 2l, 2l+1
  float accx = 0.f, accy = 0.f, accz = 0.f;

  if (deg <= 64) {
    // ---- register softmax: one lane per edge ----
    int src = 0, eid = 0;
    float v0 = -1e30f, v1 = -1e30f, v2 = -1e30f, v3 = -1e30f, v4 = -1e30f;
    if (l < deg) {
      src = csr_src[off + l];
      eid = csr_eid[off + l];
      const float* ap = a_s + src * 5;
      v0 = lrelu2(ap[0] + ad0);
      v1 = lrelu2(ap[1] + ad1);
      v2 = lrelu2(ap[2] + ad2);
      v3 = lrelu2(ap[3] + ad3);
      v4 = lrelu2(ap[4] + ad4);
    }
    const float m0 = wmax(v0), m1 = wmax(v1), m2 = wmax(v2), m3 = wmax(v3), m4 = wmax(v4);
    float e0 = 0.f, e1 = 0.f, e2 = 0.f, e3 = 0.f, e4 = 0.f;
    if (l < deg) {
      e0 = __expf(v0 - m0); e1 = __expf(v1 - m1); e2 = __expf(v2 - m2);
      e3 = __expf(v3 - m3); e4 = __expf(v4 - m4);
    }
    const float i0 = 1.f / (wsum(e0) + 1e-16f), i1 = 1.f / (wsum(e1) + 1e-16f),
                i2 = 1.f / (wsum(e2) + 1e-16f), i3 = 1.f / (wsum(e3) + 1e-16f),
                i4 = 1.f / (wsum(e4) + 1e-16f);
    const float a0 = e0 * i0, a1 = e1 * i1, a2 = e2 * i2, a3 = e3 * i3, a4 = e4 * i4;
    if (l < deg) {
      float* aw = alpha_out + (long)eid * 5;
      aw[0] = a0; aw[1] = a1; aw[2] = a2; aw[3] = a3; aw[4] = a4;
    }
    // ---- dump edge table to LDS (zeros beyond deg) ----
    srcS[w][l] = src;
    alS[w][l][0] = a0; alS[w][l][1] = a1; alS[w][l][2] = a2;
    alS[w][l][3] = a3; alS[w][l][4] = a4;

    const int degR = (deg + 7) & ~7;
    const unsigned cx = 2 * l, cz = 128 + l;
    for (int s0 = 0; s0 < degR; s0 += 8) {
      int sr[8]; float aA[8], aB[8];
      #pragma unroll
      for (int j = 0; j < 8; ++j) {
        sr[j] = srcS[w][s0 + j];
        aA[j] = alS[w][s0 + j][hA];
        aB[j] = alS[w][s0 + j][4];
      }
      ushort2 u2[8]; unsigned short z[8];
      #pragma unroll
      for (int j = 0; j < 8; ++j) {
        const unsigned xb = (unsigned)sr[j] * HID;
        u2[j] = *(const ushort2*)(xlh + xb + cx);
        if (l < 32) z[j] = xlh[xb + cz];
      }
      #pragma unroll
      for (int j = 0; j < 8; ++j) {
        accx += b2f(u2[j].x) * aA[j];
        accy += b2f(u2[j].y) * aA[j];
        if (l < 32) accz += b2f(z[j]) * aB[j];
      }
    }
  } else {
    // ---- slow path (rare): 3-pass over segment ----
    float m0 = -1e30f, m1 = -1e30f, m2 = -1e30f, m3 = -1e30f, m4 = -1e30f;
    for (int s = l; s < deg; s += 64) {
      const float* ap = a_s + csr_src[off + s] * 5;
      m0 = fmaxf(m0, lrelu2(ap[0] + ad0));
      m1 = fmaxf(m1, lrelu2(ap[1] + ad1));
      m2 = fmaxf(m2, lrelu2(ap[2] + ad2));
      m3 = fmaxf(m3, lrelu2(ap[3] + ad3));
      m4 = fmaxf(m4, lrelu2(ap[4] + ad4));
    }
    m0 = wmax(m0); m1 = wmax(m1); m2 = wmax(m2); m3 = wmax(m3); m4 = wmax(m4);
    float s0 = 0.f, s1 = 0.f, s2 = 0.f, s3 = 0.f, s4 = 0.f;
    for (int s = l; s < deg; s += 64) {
      const float* ap = a_s + csr_src[off + s] * 5;
      s0 += __expf(lrelu2(ap[0] + ad0) - m0);
      s1 += __expf(lrelu2(ap[1] + ad1) - m1);
      s2 += __expf(lrelu2(ap[2] + ad2) - m2);
      s3 += __expf(lrelu2(ap[3] + ad3) - m3);
      s4 += __expf(lrelu2(ap[4] + ad4) - m4);
    }
    const float i0 = 1.f / (wsum(s0) + 1e-16f), i1 = 1.f / (wsum(s1) + 1e-16f),
                i2 = 1.f / (wsum(s2) + 1e-16f), i3 = 1.f / (wsum(s3) + 1e-16f),
                i4 = 1.f / (wsum(s4) + 1e-16f);
    const float adA = hA == 0 ? ad0 : hA == 1 ? ad1 : hA == 2 ? ad2 : ad3;
    const float mA  = hA == 0 ? m0  : hA == 1 ? m1  : hA == 2 ? m2  : m3;
    const float iA  = hA == 0 ? i0  : hA == 1 ? i1  : hA == 2 ? i2  : i3;
    float adw = 0.f, mw = 0.f, iw = 0.f;
    if (l < 5) {
      adw = l == 0 ? ad0 : l == 1 ? ad1 : l == 2 ? ad2 : l == 3 ? ad3 : ad4;
      mw  = l == 0 ? m0  : l == 1 ? m1  : l == 2 ? m2  : l == 3 ? m3  : m4;
      iw  = l == 0 ? i0  : l == 1 ? i1  : l == 2 ? i2  : l == 3 ? i3  : i4;
    }
    for (int s = 0; s < deg; ++s) {
      const int p = off + s;
      const int srcs = csr_src[p];
      const float* ap = a_s + srcs * 5;
      const float aA = __expf(lrelu2(ap[hA] + adA) - mA) * iA;
      const long xb = (long)srcs * HID;
      const ushort2 u2 = *(const ushort2*)(xlh + xb + 2 * l);
      accx += b2f(u2.x) * aA;
      accy += b2f(u2.y) * aA;
      if (l < 32) {
        const float aC = __expf(lrelu2(ap[4] + ad4) - m4) * i4;
        accz += b2f(xlh[xb + 128 + l]) * aC;
      }
      if (l < 5) {
        alpha_out[(long)csr_eid[p] * 5 + l] = __expf(lrelu2(ap[l] + adw) - mw) * iw;
      }
    }
  }

  // epilogue (bf16 store — identical to downstream GEMM's A rounding)
  const int c0 = 2 * l, c2 = 128 + l;
  float v0 = accx + bias[c0];     v0 = v0 > 0.f ? v0 : 0.01f * v0;
  float v1 = accy + bias[c0 + 1]; v1 = v1 > 0.f ? v1 : 0.01f * v1;
  float v2 = 0.f;
  if (l < 32) { v2 = accz + bias[c2]; v2 = v2 > 0.f ? v2 : 0.01f * v2; }

  const long hb = (long)n * HID;
  if (DO_LN) {
    const float tot = wsum(v0 + v1 + v2);
    const float mean = tot * (1.f / 160.f);
    const float d0 = v0 - mean, d1 = v1 - mean;
    float sq = d0 * d0 + d1 * d1;
    float d2 = 0.f;
    if (l < 32) { d2 = v2 - mean; sq += d2 * d2; }
    const float var = wsum(sq) * (1.f / 160.f);
    const float rstd = rsqrtf(var + 1e-5f);
    hout[hb + c0]     = f2b(d0 * rstd * gamma_[c0]     + beta_[c0]);
    hout[hb + c0 + 1] = f2b(d1 * rstd * gamma_[c0 + 1] + beta_[c0 + 1]);
    if (l < 32) hout[hb + c2] = f2b(d2 * rstd * gamma_[c2] + beta_[c2]);
  } else {
    hout[hb + c0]     = f2b(v0);
    hout[hb + c0 + 1] = f2b(v1);
    if (l < 32) hout[hb + c2] = f2b(v2);
  }
}

extern "C" void kernel_launch(void* const* d_in, const int* in_sizes, int n_in,
                              void* d_out, int out_size, void* d_ws, size_t ws_size,
                              hipStream_t stream)
{
  const float* x     = (const float*)d_in[0];
  const int*   ei    = (const int*)d_in[1];
  const float* W1    = (const float*)d_in[2];
  const float* att1s = (const float*)d_in[3];
  const float* att1d = (const float*)d_in[4];
  const float* b1    = (const float*)d_in[5];
  const float* g1    = (const float*)d_in[6];
  const float* be1   = (const float*)d_in[7];
  const float* W2    = (const float*)d_in[8];
  const float* att2s = (const float*)d_in[9];
  const float* att2d = (const float*)d_in[10];
  const float* b2    = (const float*)d_in[11];
  const float* Wm    = (const float*)d_in[12];
  const float* bm    = (const float*)d_in[13];

  float* out    = (float*)d_out;                      // [N,160]
  float* alpha1 = out + (long)N_NODES * HID;          // [E,5]
  float* alpha2 = alpha1 + (long)E_TOT * 5;           // [E,5]

  char* p = (char*)d_ws;
  auto alloc = [&](size_t bytes) { void* r = (void*)p; p += (bytes + 255) & ~(size_t)255; return r; };
  unsigned short* hb16 = (unsigned short*)alloc((size_t)N_NODES * HID * 2);
  unsigned short* xlh  = (unsigned short*)alloc((size_t)N_NODES * HID * 2);
  float* as_  = (float*)alloc((size_t)N_NODES * 5 * 4);
  float* ad_  = (float*)alloc((size_t)N_NODES * 5 * 4);
  int* deg    = (int*)alloc((size_t)N_NODES * 4);
  int* fillc  = (int*)alloc((size_t)N_NODES * 4);
  int* off    = (int*)alloc((size_t)(N_NODES + 1) * 4);
  int* csrS   = (int*)alloc((size_t)E_TOT * 4);
  int* csrE   = (int*)alloc((size_t)E_TOT * 4);
  int* flag   = (int*)alloc(256);
  unsigned short* Bt1 = (unsigned short*)alloc((size_t)HID * 512 * 2);
  unsigned short* Bt2 = (unsigned short*)alloc((size_t)HID * 192 * 2);
  unsigned short* Btm = (unsigned short*)alloc((size_t)HID * 192 * 2);

  hipMemsetAsync(deg, 0, (size_t)N_NODES * 4, stream);
  hipMemsetAsync(fillc, 0, (size_t)N_NODES * 4, stream);

  detect_kernel<<<1, 64, 0, stream>>>(ei, flag);
  const int EB = (E_TOT + 255) / 256;
  count_kernel<<<EB, 256, 0, stream>>>(ei, flag, deg);
  scan_kernel<<<1, 1024, 0, stream>>>(deg, off);
  fill_kernel<<<EB, 256, 0, stream>>>(ei, flag, off, fillc, csrS, csrE);

  convert_all<<<(HID * 512 + 255) / 256, 256, 0, stream>>>(W1, W2, Wm, Bt1, Bt2, Btm);

  const int GB = (N_NODES + 63) / 64;

  // layer 1: bf16 pipelined LDS-GEMM (BK=64) + fused attention dots
  gemm_lds<float, F_IN_K, 512, 64, 2><<<GB, 256, 0, stream>>>(x, Bt1, nullptr, xlh, nullptr, att1s, att1d, as_, ad_);
  node_kernel<1><<<N_NODES / 4, 256, 0, stream>>>(off, csrS, csrE, xlh, as_, ad_, alpha1, b1, g1, be1, hb16);

  // layer 2: bf16-A GEMM
  gemm_lds<unsigned short, HID, 192, 64, 2><<<GB, 256, 0, stream>>>(hb16, Bt2, nullptr, xlh, nullptr, att2s, att2d, as_, ad_);
  node_kernel<0><<<N_NODES / 4, 256, 0, stream>>>(off, csrS, csrE, xlh, as_, ad_, alpha2, b2, nullptr, nullptr, hb16);

  // final MLP: out = leaky(h2 @ Wm + bm)
  gemm_lds<unsigned short, HID, 192, 64, 1><<<GB, 256, 0, stream>>>(hb16, Btm, out, nullptr, bm, nullptr, nullptr, nullptr, nullptr);
}

// Round 13
// 398.839 us; speedup vs baseline: 2.5219x; 1.0146x over previous
//
#include <hip/hip_runtime.h>

#define N_NODES 50000
#define E_RAW_N 800000
#define E_TOT   850000
#define F_IN_K  500
#define HID     160
#define XSTR    184   // packed row: 160 bf16 cols + 5 f32 a_s (+pad), 16B-aligned

using short8 = __attribute__((ext_vector_type(8))) short;
using f32x4  = __attribute__((ext_vector_type(4))) float;

__device__ __forceinline__ float b2f(unsigned short u) {
  union { unsigned int i; float f; } v; v.i = ((unsigned int)u) << 16; return v.f;
}
__device__ __forceinline__ unsigned short f2b(float f) {
  union { float f; unsigned int i; } v; v.f = f;
  unsigned int i = v.i;
  unsigned int lsb = (i >> 16) & 1u;
  i += 0x7fffu + lsb;
  return (unsigned short)(i >> 16);
}

__device__ __forceinline__ float wsum(float x) {
  #pragma unroll
  for (int o = 32; o; o >>= 1) x += __shfl_xor(x, o, 64);
  return x;
}
__device__ __forceinline__ float wmax(float x) {
  #pragma unroll
  for (int o = 32; o; o >>= 1) x = fmaxf(x, __shfl_xor(x, o, 64));
  return x;
}
__device__ __forceinline__ float lrelu2(float x) { return x > 0.f ? x : 0.2f * x; }

// ---------------- edge dtype detection (int64 vs int32 hedge) ----------------
__global__ void detect_kernel(const int* __restrict__ ei, int* __restrict__ flag) {
  if (threadIdx.x == 0 && blockIdx.x == 0) {
    int allz = 1;
    for (int i = 1; i < 128; i += 2) if (ei[i] != 0) { allz = 0; break; }
    *flag = allz;  // 1 => int64 layout
  }
}
__device__ __forceinline__ int edge_src(const int* ei, int wide, int e) {
  return wide ? ei[2 * e] : ei[e];
}
__device__ __forceinline__ int edge_dst(const int* ei, int wide, int e) {
  return wide ? ei[2 * (E_RAW_N + e)] : ei[E_RAW_N + e];
}

// ------- weight pre-convert (all 3 weights in one launch): f32 -> bf16 -------
__global__ __launch_bounds__(256) void convert_all(
    const float* __restrict__ W1, const float* __restrict__ W2, const float* __restrict__ Wm,
    unsigned short* __restrict__ Bt1, unsigned short* __restrict__ Bt2,
    unsigned short* __restrict__ Btm)
{
  const int i = blockIdx.x * 256 + threadIdx.x;
  if (i < HID * 512) {
    const int c = i / 512, k = i % 512;
    Bt1[i] = f2b((k < F_IN_K) ? W1[(long)k * HID + c] : 0.f);
  }
  if (i < HID * 192) {
    const int c = i / 192, k = i % 192;
    Bt2[i] = f2b((k < HID) ? W2[(long)k * HID + c] : 0.f);
    Btm[i] = f2b((k < HID) ? Wm[(long)k * HID + c] : 0.f);
  }
}

// ---------------- GEMM: [M,160] = A[M,K] @ B, LDS-staged B, pipelined --------
// block = 2 waves (128 thr), BM=32; wave = 16 rows x 160 cols, 16x16x32 MFMA.
// AT=float: A converted to bf16 in-register. AT=ushort: direct short8 loads.
// MODE 1: +bias, leaky(0.01), C f32 (stride 160).
// MODE 2: packed row out (stride XSTR): bf16 cols + fused att-dot a_s; a_d arr.
template<typename AT, int K, int KPAD, int BK, int MODE>
__global__ __launch_bounds__(128) void gemm_lds(
    const AT* __restrict__ A, const unsigned short* __restrict__ Bt,
    float* __restrict__ C, unsigned short* __restrict__ Ch,
    const float* __restrict__ bias,
    const float* __restrict__ att_s, const float* __restrict__ att_d,
    float* __restrict__ a_d)
{
  constexpr bool AB16 = (sizeof(AT) == 2);
  constexpr int LSTR = BK + 8;
  constexpr int CHUNKS = KPAD / BK;
  constexpr int KSC = BK / 32;
  constexpr int ROWU = BK / 8;
  constexpr int UNITS = HID * ROWU;
  static_assert(UNITS % 128 == 0, "units must tile threads");
  constexpr int UPT = UNITS / 128;
  __shared__ __align__(16) unsigned short Bs[HID][LSTR];

  const int t = threadIdx.x;
  const int l = t & 63;
  const int w = t >> 6;
  const int m = l & 15;
  const int kgrp = (l >> 4) * 8;
  const int rbase = blockIdx.x * 32 + w * 16;
  const int arow = (rbase + m < N_NODES) ? rbase + m : N_NODES - 1;
  const AT* Arow = A + (long)arow * K;

  f32x4 acc[10];
  #pragma unroll
  for (int i = 0; i < 10; ++i) acc[i] = (f32x4){0.f, 0.f, 0.f, 0.f};

  short8 rb[UPT];
  float  arF[KSC][8], arF2[KSC][8];
  short8 arS[KSC], arS2[KSC];

  auto loadB = [&](int cc, short8* dst) {
    #pragma unroll
    for (int i = 0; i < UPT; ++i) {
      const int u = i * 128 + t;
      const int c = u / ROWU;
      const int k8 = u % ROWU;
      dst[i] = *(const short8*)(Bt + (long)c * KPAD + cc * BK + k8 * 8);
    }
  };
  auto loadA = [&](int cc, float aF[KSC][8], short8* aS) {
    #pragma unroll
    for (int ks = 0; ks < KSC; ++ks) {
      const int kb = cc * BK + ks * 32 + kgrp;
      if constexpr (AB16) {
        short8 v = (short8){0,0,0,0,0,0,0,0};
        if (kb + 8 <= K) v = *(const short8*)(Arow + kb);
        else if (kb < K) {
          #pragma unroll
          for (int j = 0; j < 8; ++j) v[j] = (kb + j < K) ? (short)Arow[kb + j] : (short)0;
        }
        aS[ks] = v;
      } else {
        if (kb + 8 <= K) {
          const float4 a0 = *(const float4*)(Arow + kb);
          const float4 a1 = *(const float4*)(Arow + kb + 4);
          aF[ks][0]=a0.x; aF[ks][1]=a0.y; aF[ks][2]=a0.z; aF[ks][3]=a0.w;
          aF[ks][4]=a1.x; aF[ks][5]=a1.y; aF[ks][6]=a1.z; aF[ks][7]=a1.w;
        } else {
          #pragma unroll
          for (int j = 0; j < 8; ++j) aF[ks][j] = (kb + j < K) ? (float)Arow[kb + j] : 0.f;
        }
      }
    }
  };

  loadB(0, rb);
  loadA(0, arF, arS);

  for (int cc = 0; cc < CHUNKS; ++cc) {
    __syncthreads();
    #pragma unroll
    for (int i = 0; i < UPT; ++i) {
      const int u = i * 128 + t;
      const int c = u / ROWU;
      const int k8 = u % ROWU;
      *(short8*)&Bs[c][k8 * 8] = rb[i];
    }
    __syncthreads();
    if (cc + 1 < CHUNKS) {
      loadB(cc + 1, rb);
      loadA(cc + 1, arF2, arS2);
      __builtin_amdgcn_sched_barrier(0);
    }
    __builtin_amdgcn_s_setprio(1);
    #pragma unroll
    for (int ks = 0; ks < KSC; ++ks) {
      short8 ah;
      if constexpr (AB16) {
        ah = arS[ks];
      } else {
        #pragma unroll
        for (int j = 0; j < 8; ++j) ah[j] = (short)f2b(arF[ks][j]);
      }
      #pragma unroll
      for (int ct = 0; ct < 10; ++ct) {
        const short8 bh = *(const short8*)&Bs[ct * 16 + m][ks * 32 + kgrp];
        acc[ct] = __builtin_amdgcn_mfma_f32_16x16x32_bf16(ah, bh, acc[ct], 0, 0, 0);
      }
    }
    __builtin_amdgcn_s_setprio(0);
    if (cc + 1 < CHUNKS) {
      #pragma unroll
      for (int ks = 0; ks < KSC; ++ks) {
        if constexpr (AB16) arS[ks] = arS2[ks];
        else {
          #pragma unroll
          for (int j = 0; j < 8; ++j) arF[ks][j] = arF2[ks][j];
        }
      }
    }
  }

  const int crow0 = rbase + (l >> 4) * 4;

  if (MODE == 2) {
    // fused attention dots; a_s packed into row tail, a_d to its own array
    #pragma unroll
    for (int r = 0; r < 4; ++r) {
      float ps[5], pd[5];
      #pragma unroll
      for (int h = 0; h < 5; ++h) {
        float s = acc[2*h][r]     * att_s[(2*h) * 16 + m]
                + acc[2*h + 1][r] * att_s[(2*h + 1) * 16 + m];
        float d = acc[2*h][r]     * att_d[(2*h) * 16 + m]
                + acc[2*h + 1][r] * att_d[(2*h + 1) * 16 + m];
        #pragma unroll
        for (int o = 1; o < 16; o <<= 1) {
          s += __shfl_xor(s, o, 64);
          d += __shfl_xor(d, o, 64);
        }
        ps[h] = s; pd[h] = d;
      }
      const int crow = crow0 + r;
      if (crow < N_NODES && m < 5) {
        const float vs = m == 0 ? ps[0] : m == 1 ? ps[1] : m == 2 ? ps[2] : m == 3 ? ps[3] : ps[4];
        const float vd = m == 0 ? pd[0] : m == 1 ? pd[1] : m == 2 ? pd[2] : m == 3 ? pd[3] : pd[4];
        ((float*)(Ch + (long)crow * XSTR + 160))[m] = vs;
        a_d[crow * 5 + m] = vd;
      }
    }
  }

  #pragma unroll
  for (int r = 0; r < 4; ++r) {
    const int crow = crow0 + r;
    if (crow < N_NODES) {
      #pragma unroll
      for (int ct = 0; ct < 10; ++ct) {
        const int col = ct * 16 + m;
        float v = acc[ct][r];
        if (MODE == 1) { v += bias[col]; v = v > 0.f ? v : 0.01f * v; }
        if (MODE == 2) Ch[(long)crow * XSTR + col] = f2b(v);
        else           C[(long)crow * HID + col] = v;
      }
    }
  }
}

// ---------------- CSR build ---------------------------------------------------
__global__ __launch_bounds__(256) void count_kernel(const int* __restrict__ ei,
    const int* __restrict__ flag, int* __restrict__ deg) {
  const int e = blockIdx.x * 256 + threadIdx.x;
  if (e >= E_TOT) return;
  const int wide = *flag;
  const int d = (e < E_RAW_N) ? edge_dst(ei, wide, e) : (e - E_RAW_N);
  atomicAdd(&deg[d], 1);
}

#define SCAN_CHUNK 49  // 1024*49 = 50176 >= 50000
__global__ __launch_bounds__(1024) void scan_kernel(const int* __restrict__ deg, int* __restrict__ off) {
  __shared__ int wtot[16];
  const int t = threadIdx.x;
  const int lane = t & 63, wid = t >> 6;
  const int base = t * SCAN_CHUNK;
  int local[SCAN_CHUNK];
  int sum = 0;
  #pragma unroll
  for (int i = 0; i < SCAN_CHUNK; ++i) {
    const int idx = base + i;
    const int v = (idx < N_NODES) ? deg[idx] : 0;
    local[i] = sum;
    sum += v;
  }
  int inc = sum;
  #pragma unroll
  for (int o = 1; o < 64; o <<= 1) {
    const int y = __shfl_up(inc, o, 64);
    if (lane >= o) inc += y;
  }
  if (lane == 63) wtot[wid] = inc;
  __syncthreads();
  if (wid == 0 && lane < 16) {
    const int v = wtot[lane];
    int inc2 = v;
    #pragma unroll
    for (int o = 1; o < 16; o <<= 1) {
      const int y = __shfl_up(inc2, o, 64);
      if (lane >= o) inc2 += y;
    }
    wtot[lane] = inc2 - v;  // exclusive
  }
  __syncthreads();
  const int pre = wtot[wid] + (inc - sum);
  #pragma unroll
  for (int i = 0; i < SCAN_CHUNK; ++i) {
    const int idx = base + i;
    if (idx < N_NODES) off[idx] = pre + local[i];
  }
  if (t == 1023) off[N_NODES] = E_TOT;
}

__global__ __launch_bounds__(256) void fill_kernel(const int* __restrict__ ei,
    const int* __restrict__ flag, const int* __restrict__ off,
    int* __restrict__ fillc, int* __restrict__ csr_src, int* __restrict__ csr_eid) {
  const int e = blockIdx.x * 256 + threadIdx.x;
  if (e >= E_TOT) return;
  const int wide = *flag;
  int s, d;
  if (e < E_RAW_N) { s = edge_src(ei, wide, e); d = edge_dst(ei, wide, e); }
  else { s = e - E_RAW_N; d = s; }
  const int p = off[d] + atomicAdd(&fillc[d], 1);
  csr_src[p] = s;
  csr_eid[p] = e;
}

// ---------------- fused per-node segment-softmax + aggregation ---------------
// xlh rows are packed (XSTR): cols bf16 [0..160) + a_s f32 [160..170).
// Fast path (deg<=64): register softmax, NO max pass (logits ~N(0,2.3), exp
// cannot overflow f32); edge table in LDS; unroll-8 gather.
template<int DO_LN>
__global__ __launch_bounds__(256) void node_kernel(
    const int* __restrict__ off_, const int* __restrict__ csr_src, const int* __restrict__ csr_eid,
    const unsigned short* __restrict__ xlh,
    const float* __restrict__ a_d,
    float* __restrict__ alpha_out,
    const float* __restrict__ bias,
    const float* __restrict__ gamma_, const float* __restrict__ beta_,
    unsigned short* __restrict__ hout)
{
  __shared__ int   srcS[4][64];
  __shared__ float alS[4][64][6];

  const int w = threadIdx.x >> 6;
  const int l = threadIdx.x & 63;
  const int n = blockIdx.x * 4 + w;
  if (n >= N_NODES) return;
  const int off = off_[n];
  const int deg = off_[n + 1] - off;

  const float ad0 = a_d[n*5+0], ad1 = a_d[n*5+1], ad2 = a_d[n*5+2], ad3 = a_d[n*5+3], ad4 = a_d[n*5+4];
  const int hA = l >> 4;  // head for cols 2l, 2l+1
  float accx = 0.f, accy = 0.f, accz = 0.f;

  if (deg <= 64) {
    // ---- register softmax (no max pass): one lane per edge ----
    int src = 0, eid = 0;
    float e0 = 0.f, e1 = 0.f, e2 = 0.f, e3 = 0.f, e4 = 0.f;
    if (l < deg) {
      src = csr_src[off + l];
      eid = csr_eid[off + l];
      const float* ap = (const float*)(xlh + (unsigned)src * XSTR + 160);
      e0 = __expf(lrelu2(ap[0] + ad0));
      e1 = __expf(lrelu2(ap[1] + ad1));
      e2 = __expf(lrelu2(ap[2] + ad2));
      e3 = __expf(lrelu2(ap[3] + ad3));
      e4 = __expf(lrelu2(ap[4] + ad4));
    }
    const float i0 = 1.f / (wsum(e0) + 1e-16f), i1 = 1.f / (wsum(e1) + 1e-16f),
                i2 = 1.f / (wsum(e2) + 1e-16f), i3 = 1.f / (wsum(e3) + 1e-16f),
                i4 = 1.f / (wsum(e4) + 1e-16f);
    const float a0 = e0 * i0, a1 = e1 * i1, a2 = e2 * i2, a3 = e3 * i3, a4 = e4 * i4;
    if (l < deg) {
      float* aw = alpha_out + (long)eid * 5;
      aw[0] = a0; aw[1] = a1; aw[2] = a2; aw[3] = a3; aw[4] = a4;
    }
    srcS[w][l] = src;
    alS[w][l][0] = a0; alS[w][l][1] = a1; alS[w][l][2] = a2;
    alS[w][l][3] = a3; alS[w][l][4] = a4;

    const int degR = (deg + 7) & ~7;
    const unsigned cx = 2 * l, cz = 128 + l;
    for (int s0 = 0; s0 < degR; s0 += 8) {
      int sr[8]; float aA[8], aB[8];
      #pragma unroll
      for (int j = 0; j < 8; ++j) {
        sr[j] = srcS[w][s0 + j];
        aA[j] = alS[w][s0 + j][hA];
        aB[j] = alS[w][s0 + j][4];
      }
      ushort2 u2[8]; unsigned short z[8];
      #pragma unroll
      for (int j = 0; j < 8; ++j) {
        const unsigned xb = (unsigned)sr[j] * XSTR;
        u2[j] = *(const ushort2*)(xlh + xb + cx);
        if (l < 32) z[j] = xlh[xb + cz];
      }
      #pragma unroll
      for (int j = 0; j < 8; ++j) {
        accx += b2f(u2[j].x) * aA[j];
        accy += b2f(u2[j].y) * aA[j];
        if (l < 32) accz += b2f(z[j]) * aB[j];
      }
    }
  } else {
    // ---- slow path (rare): 3-pass over segment ----
    float m0 = -1e30f, m1 = -1e30f, m2 = -1e30f, m3 = -1e30f, m4 = -1e30f;
    for (int s = l; s < deg; s += 64) {
      const float* ap = (const float*)(xlh + (unsigned)csr_src[off + s] * XSTR + 160);
      m0 = fmaxf(m0, lrelu2(ap[0] + ad0));
      m1 = fmaxf(m1, lrelu2(ap[1] + ad1));
      m2 = fmaxf(m2, lrelu2(ap[2] + ad2));
      m3 = fmaxf(m3, lrelu2(ap[3] + ad3));
      m4 = fmaxf(m4, lrelu2(ap[4] + ad4));
    }
    m0 = wmax(m0); m1 = wmax(m1); m2 = wmax(m2); m3 = wmax(m3); m4 = wmax(m4);
    float s0 = 0.f, s1 = 0.f, s2 = 0.f, s3 = 0.f, s4 = 0.f;
    for (int s = l; s < deg; s += 64) {
      const float* ap = (const float*)(xlh + (unsigned)csr_src[off + s] * XSTR + 160);
      s0 += __expf(lrelu2(ap[0] + ad0) - m0);
      s1 += __expf(lrelu2(ap[1] + ad1) - m1);
      s2 += __expf(lrelu2(ap[2] + ad2) - m2);
      s3 += __expf(lrelu2(ap[3] + ad3) - m3);
      s4 += __expf(lrelu2(ap[4] + ad4) - m4);
    }
    const float i0 = 1.f / (wsum(s0) + 1e-16f), i1 = 1.f / (wsum(s1) + 1e-16f),
                i2 = 1.f / (wsum(s2) + 1e-16f), i3 = 1.f / (wsum(s3) + 1e-16f),
                i4 = 1.f / (wsum(s4) + 1e-16f);
    const float adA = hA == 0 ? ad0 : hA == 1 ? ad1 : hA == 2 ? ad2 : ad3;
    const float mA  = hA == 0 ? m0  : hA == 1 ? m1  : hA == 2 ? m2  : m3;
    const float iA  = hA == 0 ? i0  : hA == 1 ? i1  : hA == 2 ? i2  : i3;
    float adw = 0.f, mw = 0.f, iw = 0.f;
    if (l < 5) {
      adw = l == 0 ? ad0 : l == 1 ? ad1 : l == 2 ? ad2 : l == 3 ? ad3 : ad4;
      mw  = l == 0 ? m0  : l == 1 ? m1  : l == 2 ? m2  : l == 3 ? m3  : m4;
      iw  = l == 0 ? i0  : l == 1 ? i1  : l == 2 ? i2  : l == 3 ? i3  : i4;
    }
    for (int s = 0; s < deg; ++s) {
      const int p = off + s;
      const int srcs = csr_src[p];
      const unsigned xb = (unsigned)srcs * XSTR;
      const float* ap = (const float*)(xlh + xb + 160);
      const float aA = __expf(lrelu2(ap[hA] + adA) - mA) * iA;
      const ushort2 u2 = *(const ushort2*)(xlh + xb + 2 * l);
      accx += b2f(u2.x) * aA;
      accy += b2f(u2.y) * aA;
      if (l < 32) {
        const float aC = __expf(lrelu2(ap[4] + ad4) - m4) * i4;
        accz += b2f(xlh[xb + 128 + l]) * aC;
      }
      if (l < 5) {
        alpha_out[(long)csr_eid[p] * 5 + l] = __expf(lrelu2(ap[l] + adw) - mw) * iw;
      }
    }
  }

  // epilogue (bf16 store)
  const int c0 = 2 * l, c2 = 128 + l;
  float v0 = accx + bias[c0];     v0 = v0 > 0.f ? v0 : 0.01f * v0;
  float v1 = accy + bias[c0 + 1]; v1 = v1 > 0.f ? v1 : 0.01f * v1;
  float v2 = 0.f;
  if (l < 32) { v2 = accz + bias[c2]; v2 = v2 > 0.f ? v2 : 0.01f * v2; }

  const long hb = (long)n * HID;
  if (DO_LN) {
    const float tot = wsum(v0 + v1 + v2);
    const float mean = tot * (1.f / 160.f);
    const float d0 = v0 - mean, d1 = v1 - mean;
    float sq = d0 * d0 + d1 * d1;
    float d2 = 0.f;
    if (l < 32) { d2 = v2 - mean; sq += d2 * d2; }
    const float var = wsum(sq) * (1.f / 160.f);
    const float rstd = rsqrtf(var + 1e-5f);
    hout[hb + c0]     = f2b(d0 * rstd * gamma_[c0]     + beta_[c0]);
    hout[hb + c0 + 1] = f2b(d1 * rstd * gamma_[c0 + 1] + beta_[c0 + 1]);
    if (l < 32) hout[hb + c2] = f2b(d2 * rstd * gamma_[c2] + beta_[c2]);
  } else {
    hout[hb + c0]     = f2b(v0);
    hout[hb + c0 + 1] = f2b(v1);
    if (l < 32) hout[hb + c2] = f2b(v2);
  }
}

extern "C" void kernel_launch(void* const* d_in, const int* in_sizes, int n_in,
                              void* d_out, int out_size, void* d_ws, size_t ws_size,
                              hipStream_t stream)
{
  const float* x     = (const float*)d_in[0];
  const int*   ei    = (const int*)d_in[1];
  const float* W1    = (const float*)d_in[2];
  const float* att1s = (const float*)d_in[3];
  const float* att1d = (const float*)d_in[4];
  const float* b1    = (const float*)d_in[5];
  const float* g1    = (const float*)d_in[6];
  const float* be1   = (const float*)d_in[7];
  const float* W2    = (const float*)d_in[8];
  const float* att2s = (const float*)d_in[9];
  const float* att2d = (const float*)d_in[10];
  const float* b2    = (const float*)d_in[11];
  const float* Wm    = (const float*)d_in[12];
  const float* bm    = (const float*)d_in[13];

  float* out    = (float*)d_out;                      // [N,160]
  float* alpha1 = out + (long)N_NODES * HID;          // [E,5]
  float* alpha2 = alpha1 + (long)E_TOT * 5;           // [E,5]

  char* p = (char*)d_ws;
  auto alloc = [&](size_t bytes) { void* r = (void*)p; p += (bytes + 255) & ~(size_t)255; return r; };
  unsigned short* hb16 = (unsigned short*)alloc((size_t)N_NODES * HID * 2);
  unsigned short* xlh  = (unsigned short*)alloc((size_t)N_NODES * XSTR * 2);
  float* ad_  = (float*)alloc((size_t)N_NODES * 5 * 4);
  int* deg    = (int*)alloc((size_t)N_NODES * 4);
  int* fillc  = (int*)alloc((size_t)N_NODES * 4);
  int* off    = (int*)alloc((size_t)(N_NODES + 1) * 4);
  int* csrS   = (int*)alloc((size_t)E_TOT * 4);
  int* csrE   = (int*)alloc((size_t)E_TOT * 4);
  int* flag   = (int*)alloc(256);
  unsigned short* Bt1 = (unsigned short*)alloc((size_t)HID * 512 * 2);
  unsigned short* Bt2 = (unsigned short*)alloc((size_t)HID * 192 * 2);
  unsigned short* Btm = (unsigned short*)alloc((size_t)HID * 192 * 2);

  hipMemsetAsync(deg, 0, (size_t)N_NODES * 4, stream);
  hipMemsetAsync(fillc, 0, (size_t)N_NODES * 4, stream);

  detect_kernel<<<1, 64, 0, stream>>>(ei, flag);
  const int EB = (E_TOT + 255) / 256;
  count_kernel<<<EB, 256, 0, stream>>>(ei, flag, deg);
  scan_kernel<<<1, 1024, 0, stream>>>(deg, off);
  fill_kernel<<<EB, 256, 0, stream>>>(ei, flag, off, fillc, csrS, csrE);

  convert_all<<<(HID * 512 + 255) / 256, 256, 0, stream>>>(W1, W2, Wm, Bt1, Bt2, Btm);

  const int GB = (N_NODES + 31) / 32;

  // layer 1: bf16 pipelined LDS-GEMM (BM=32) + fused attention dots -> packed rows
  gemm_lds<float, F_IN_K, 512, 64, 2><<<GB, 128, 0, stream>>>(x, Bt1, nullptr, xlh, nullptr, att1s, att1d, ad_);
  node_kernel<1><<<N_NODES / 4, 256, 0, stream>>>(off, csrS, csrE, xlh, ad_, alpha1, b1, g1, be1, hb16);

  // layer 2
  gemm_lds<unsigned short, HID, 192, 64, 2><<<GB, 128, 0, stream>>>(hb16, Bt2, nullptr, xlh, nullptr, att2s, att2d, ad_);
  node_kernel<0><<<N_NODES / 4, 256, 0, stream>>>(off, csrS, csrE, xlh, ad_, alpha2, b2, nullptr, nullptr, hb16);

  // final MLP: out = leaky(h2 @ Wm + bm)
  gemm_lds<unsigned short, HID, 192, 64, 1><<<GB, 128, 0, stream>>>(hb16, Btm, out, nullptr, bm, nullptr, nullptr, nullptr);
}